// Round 1
// baseline (7721.728 us; speedup 1.0000x reference)
//
#include <hip/hip_runtime.h>

#define BN_EPS 1e-5f

// ---------------------------------------------------------------------------
// Embed: h = relu(x @ W_embed + b_embed)   [N,512] @ [512,64] -> [N,64]
// Tile: 32 rows x 64 cols per block (256 thr), each thread 2 rows x 4 cols.
// ---------------------------------------------------------------------------
__global__ __launch_bounds__(256) void embed_kernel(
    const float* __restrict__ x, const float* __restrict__ W,
    const float* __restrict__ b, float* __restrict__ h, int N) {
  __shared__ __align__(16) float xs[32][65];
  __shared__ __align__(16) float ws[64][64];
  const int tid  = threadIdx.x;
  const int cgrp = tid & 15;   // 16 col-groups of 4
  const int rgrp = tid >> 4;   // 16 row-groups of 2
  const int row0 = blockIdx.x * 32;

  float acc[2][4] = {{0.f, 0.f, 0.f, 0.f}, {0.f, 0.f, 0.f, 0.f}};

  for (int k0 = 0; k0 < 512; k0 += 64) {
    for (int idx = tid; idx < 32 * 64; idx += 256) {
      int r = idx >> 6, kk = idx & 63;
      int gr = row0 + r;
      xs[r][kk] = (gr < N) ? x[(size_t)gr * 512 + k0 + kk] : 0.f;
    }
    for (int idx = tid; idx < 64 * 64; idx += 256) {
      int kk = idx >> 6, c = idx & 63;
      ws[kk][c] = W[(size_t)(k0 + kk) * 64 + c];
    }
    __syncthreads();
#pragma unroll
    for (int kk = 0; kk < 64; ++kk) {
      float x0 = xs[rgrp * 2 + 0][kk];
      float x1 = xs[rgrp * 2 + 1][kk];
      float4 wv = *reinterpret_cast<const float4*>(&ws[kk][cgrp * 4]);
      acc[0][0] += x0 * wv.x; acc[0][1] += x0 * wv.y;
      acc[0][2] += x0 * wv.z; acc[0][3] += x0 * wv.w;
      acc[1][0] += x1 * wv.x; acc[1][1] += x1 * wv.y;
      acc[1][2] += x1 * wv.z; acc[1][3] += x1 * wv.w;
    }
    __syncthreads();
  }

  float4 bv = *reinterpret_cast<const float4*>(&b[cgrp * 4]);
#pragma unroll
  for (int i = 0; i < 2; ++i) {
    int gr = row0 + rgrp * 2 + i;
    if (gr < N) {
      float4 o;
      o.x = fmaxf(acc[i][0] + bv.x, 0.f);
      o.y = fmaxf(acc[i][1] + bv.y, 0.f);
      o.z = fmaxf(acc[i][2] + bv.z, 0.f);
      o.w = fmaxf(acc[i][3] + bv.w, 0.f);
      *reinterpret_cast<float4*>(&h[(size_t)gr * 64 + cgrp * 4]) = o;
    }
  }
}

// ---------------------------------------------------------------------------
// COO SpMM via HW float atomics: dst[row[e], off:off+W] += val[e]*src[col[e],:]
// W/4 threads per edge, each handling a float4 of features.
// ---------------------------------------------------------------------------
template <int W>
__global__ __launch_bounds__(256) void spmm_atomic(
    const int* __restrict__ rows, const int* __restrict__ cols,
    const float* __restrict__ vals, const float* __restrict__ src,
    float* __restrict__ dst, int E, int dstStride, int dstOff) {
  constexpr int TPE = W / 4;
  long long t = (long long)blockIdx.x * blockDim.x + threadIdx.x;
  int e = (int)(t / TPE);
  if (e >= E) return;
  int f = (int)(t % TPE);

  int r = rows[e];
  int c = cols[e];
  float v = vals[e];

  float4 s = *reinterpret_cast<const float4*>(src + (size_t)c * W + f * 4);
  float* p = dst + (size_t)r * dstStride + dstOff + f * 4;
  unsafeAtomicAdd(p + 0, s.x * v);
  unsafeAtomicAdd(p + 1, s.y * v);
  unsafeAtomicAdd(p + 2, s.z * v);
  unsafeAtomicAdd(p + 3, s.w * v);
}

// ---------------------------------------------------------------------------
// BatchNorm (eval) in place on h1: (v - mean) * rsqrt(var+eps) * gamma + beta
// ---------------------------------------------------------------------------
__global__ __launch_bounds__(256) void bn_kernel(
    float* __restrict__ h1, const float* __restrict__ gamma,
    const float* __restrict__ beta, const float* __restrict__ mean,
    const float* __restrict__ var, int n4) {
  int i = blockIdx.x * blockDim.x + threadIdx.x;
  if (i >= n4) return;
  float4 v = reinterpret_cast<float4*>(h1)[i];
  int c = (i * 4) & 127;
  float in[4] = {v.x, v.y, v.z, v.w};
  float o[4];
#pragma unroll
  for (int j = 0; j < 4; ++j) {
    float s = gamma[c + j] * rsqrtf(var[c + j] + BN_EPS);
    o[j] = (in[j] - mean[c + j]) * s + beta[c + j];
  }
  reinterpret_cast<float4*>(h1)[i] = make_float4(o[0], o[1], o[2], o[3]);
}

// ---------------------------------------------------------------------------
// Final: out = [h | h1 | h2] @ W_final + b_final   [N,448] @ [448,40]
// Tile: 64 rows x 40 cols per block (320 thr), each thread 2 rows x 4 cols.
// K chunks of 64: chunk0 from h, chunks1-2 from h1, chunks3-6 from h2.
// ---------------------------------------------------------------------------
__global__ __launch_bounds__(320) void final_kernel(
    const float* __restrict__ h, const float* __restrict__ h1,
    const float* __restrict__ h2, const float* __restrict__ Wf,
    const float* __restrict__ bf, float* __restrict__ out, int N) {
  __shared__ __align__(16) float js[64][65];
  __shared__ __align__(16) float wfs[64][40];
  const int tid  = threadIdx.x;
  const int cgrp = tid % 10;   // 10 col-groups of 4
  const int rgrp = tid / 10;   // 32 row-groups of 2
  const int row0 = blockIdx.x * 64;

  float acc[2][4] = {{0.f, 0.f, 0.f, 0.f}, {0.f, 0.f, 0.f, 0.f}};

  for (int ch = 0; ch < 7; ++ch) {
    const float* src;
    int stride, kloc;
    if (ch == 0)      { src = h;  stride = 64;  kloc = 0; }
    else if (ch <= 2) { src = h1; stride = 128; kloc = (ch - 1) * 64; }
    else              { src = h2; stride = 256; kloc = (ch - 3) * 64; }

    for (int idx = tid; idx < 64 * 64; idx += 320) {
      int r = idx >> 6, kk = idx & 63;
      int gr = row0 + r;
      js[r][kk] = (gr < N) ? src[(size_t)gr * stride + kloc + kk] : 0.f;
    }
    for (int idx = tid; idx < 64 * 40; idx += 320) {
      int kk = idx / 40, c = idx % 40;
      wfs[kk][c] = Wf[(size_t)(ch * 64 + kk) * 40 + c];
    }
    __syncthreads();
#pragma unroll
    for (int kk = 0; kk < 64; ++kk) {
      float x0 = js[rgrp * 2 + 0][kk];
      float x1 = js[rgrp * 2 + 1][kk];
      float4 wv = *reinterpret_cast<const float4*>(&wfs[kk][cgrp * 4]);
      acc[0][0] += x0 * wv.x; acc[0][1] += x0 * wv.y;
      acc[0][2] += x0 * wv.z; acc[0][3] += x0 * wv.w;
      acc[1][0] += x1 * wv.x; acc[1][1] += x1 * wv.y;
      acc[1][2] += x1 * wv.z; acc[1][3] += x1 * wv.w;
    }
    __syncthreads();
  }

  float4 bv = *reinterpret_cast<const float4*>(&bf[cgrp * 4]);
#pragma unroll
  for (int i = 0; i < 2; ++i) {
    int gr = row0 + rgrp * 2 + i;
    if (gr < N) {
      float4 o;
      o.x = acc[i][0] + bv.x;
      o.y = acc[i][1] + bv.y;
      o.z = acc[i][2] + bv.z;
      o.w = acc[i][3] + bv.w;
      *reinterpret_cast<float4*>(&out[(size_t)gr * 40 + cgrp * 4]) = o;
    }
  }
}

// ---------------------------------------------------------------------------
extern "C" void kernel_launch(void* const* d_in, const int* in_sizes, int n_in,
                              void* d_out, int out_size, void* d_ws, size_t ws_size,
                              hipStream_t stream) {
  const float* x     = (const float*)d_in[0];
  const int*   a1r   = (const int*)d_in[1];
  const int*   a1c   = (const int*)d_in[2];
  const float* a1v   = (const float*)d_in[3];
  const int*   a2r   = (const int*)d_in[4];
  const int*   a2c   = (const int*)d_in[5];
  const float* a2v   = (const float*)d_in[6];
  const float* We    = (const float*)d_in[7];
  const float* be    = (const float*)d_in[8];
  const float* gamma = (const float*)d_in[9];
  const float* beta  = (const float*)d_in[10];
  const float* mean  = (const float*)d_in[11];
  const float* var   = (const float*)d_in[12];
  const float* Wf    = (const float*)d_in[13];
  const float* bf    = (const float*)d_in[14];
  float* out = (float*)d_out;

  const int N  = in_sizes[0] / 512;
  const int E1 = in_sizes[1];
  const int E2 = in_sizes[4];

  float* h  = (float*)d_ws;                   // [N,64]
  float* h1 = h  + (size_t)N * 64;            // [N,128]
  float* h2 = h1 + (size_t)N * 128;           // [N,256]

  // zero the accumulation buffers (h fully written by embed)
  hipMemsetAsync(h1, 0, (size_t)N * (128 + 256) * sizeof(float), stream);

  embed_kernel<<<(N + 31) / 32, 256, 0, stream>>>(x, We, be, h, N);

  {
    long long t1 = (long long)E1 * 16;
    spmm_atomic<64><<<(int)((t1 + 255) / 256), 256, 0, stream>>>(
        a1r, a1c, a1v, h, h1, E1, 128, 0);
    long long t2 = (long long)E2 * 16;
    spmm_atomic<64><<<(int)((t2 + 255) / 256), 256, 0, stream>>>(
        a2r, a2c, a2v, h, h1, E2, 128, 64);
  }

  int n4 = N * 128 / 4;
  bn_kernel<<<(n4 + 255) / 256, 256, 0, stream>>>(h1, gamma, beta, mean, var, n4);

  {
    long long t1 = (long long)E1 * 32;
    spmm_atomic<128><<<(int)((t1 + 255) / 256), 256, 0, stream>>>(
        a1r, a1c, a1v, h1, h2, E1, 256, 0);
    long long t2 = (long long)E2 * 32;
    spmm_atomic<128><<<(int)((t2 + 255) / 256), 256, 0, stream>>>(
        a2r, a2c, a2v, h1, h2, E2, 256, 128);
  }

  final_kernel<<<(N + 63) / 64, 320, 0, stream>>>(h, h1, h2, Wf, bf, out, N);
}

// Round 2
// 1159.002 us; speedup vs baseline: 6.6624x; 6.6624x over previous
//
#include <hip/hip_runtime.h>

#define BN_EPS 1e-5f

// ---------------------------------------------------------------------------
// Embed: h = relu(x @ W_embed + b_embed)   [N,512] @ [512,64] -> [N,64]
// ---------------------------------------------------------------------------
__global__ __launch_bounds__(256) void embed_kernel(
    const float* __restrict__ x, const float* __restrict__ W,
    const float* __restrict__ b, float* __restrict__ h, int N) {
  __shared__ __align__(16) float xs[32][65];
  __shared__ __align__(16) float ws[64][64];
  const int tid  = threadIdx.x;
  const int cgrp = tid & 15;   // 16 col-groups of 4
  const int rgrp = tid >> 4;   // 16 row-groups of 2
  const int row0 = blockIdx.x * 32;

  float acc[2][4] = {{0.f, 0.f, 0.f, 0.f}, {0.f, 0.f, 0.f, 0.f}};

  for (int k0 = 0; k0 < 512; k0 += 64) {
    for (int idx = tid; idx < 32 * 64; idx += 256) {
      int r = idx >> 6, kk = idx & 63;
      int gr = row0 + r;
      xs[r][kk] = (gr < N) ? x[(size_t)gr * 512 + k0 + kk] : 0.f;
    }
    for (int idx = tid; idx < 64 * 64; idx += 256) {
      int kk = idx >> 6, c = idx & 63;
      ws[kk][c] = W[(size_t)(k0 + kk) * 64 + c];
    }
    __syncthreads();
#pragma unroll
    for (int kk = 0; kk < 64; ++kk) {
      float x0 = xs[rgrp * 2 + 0][kk];
      float x1 = xs[rgrp * 2 + 1][kk];
      float4 wv = *reinterpret_cast<const float4*>(&ws[kk][cgrp * 4]);
      acc[0][0] += x0 * wv.x; acc[0][1] += x0 * wv.y;
      acc[0][2] += x0 * wv.z; acc[0][3] += x0 * wv.w;
      acc[1][0] += x1 * wv.x; acc[1][1] += x1 * wv.y;
      acc[1][2] += x1 * wv.z; acc[1][3] += x1 * wv.w;
    }
    __syncthreads();
  }

  float4 bv = *reinterpret_cast<const float4*>(&b[cgrp * 4]);
#pragma unroll
  for (int i = 0; i < 2; ++i) {
    int gr = row0 + rgrp * 2 + i;
    if (gr < N) {
      float4 o;
      o.x = fmaxf(acc[i][0] + bv.x, 0.f);
      o.y = fmaxf(acc[i][1] + bv.y, 0.f);
      o.z = fmaxf(acc[i][2] + bv.z, 0.f);
      o.w = fmaxf(acc[i][3] + bv.w, 0.f);
      *reinterpret_cast<float4*>(&h[(size_t)gr * 64 + cgrp * 4]) = o;
    }
  }
}

// ---------------------------------------------------------------------------
// CSR build: histogram -> scan (rowptr + cursor) -> scatter (col,val sorted)
// ---------------------------------------------------------------------------
__global__ __launch_bounds__(256) void hist_kernel(
    const int* __restrict__ rows, int* __restrict__ cnt, int E) {
  int i = blockIdx.x * blockDim.x + threadIdx.x;
  if (i < E) atomicAdd(&cnt[rows[i]], 1);
}

__global__ __launch_bounds__(1024) void scan_kernel(
    const int* __restrict__ cnt, int* __restrict__ rowptr,
    int* __restrict__ cur, int N) {
  __shared__ int wsum[16];
  __shared__ int sbase;
  const int tid  = threadIdx.x;
  const int lane = tid & 63;
  const int w    = tid >> 6;
  if (tid == 0) { sbase = 0; rowptr[0] = 0; }
  __syncthreads();
  for (int t0 = 0; t0 < N; t0 += 1024) {
    int i = t0 + tid;
    int x = (i < N) ? cnt[i] : 0;
    int incl = x;
#pragma unroll
    for (int off = 1; off < 64; off <<= 1) {
      int y = __shfl_up(incl, off);
      if (lane >= off) incl += y;
    }
    if (lane == 63) wsum[w] = incl;
    __syncthreads();
    if (w == 0) {
      int v = (lane < 16) ? wsum[lane] : 0;
#pragma unroll
      for (int off = 1; off < 16; off <<= 1) {
        int y = __shfl_up(v, off);
        if (lane >= off) v += y;
      }
      if (lane < 16) wsum[lane] = v;
    }
    __syncthreads();
    int base = sbase + ((w > 0) ? wsum[w - 1] : 0);
    if (i < N) {
      rowptr[i + 1] = base + incl;
      cur[i]        = base + incl - x;
    }
    __syncthreads();
    if (tid == 1023) sbase += wsum[15];
    __syncthreads();
  }
}

__global__ __launch_bounds__(256) void scatter_kernel(
    const int* __restrict__ rows, const int* __restrict__ cols,
    const float* __restrict__ vals, int* __restrict__ cur,
    int* __restrict__ cs, float* __restrict__ vs, int E) {
  int i = blockIdx.x * blockDim.x + threadIdx.x;
  if (i >= E) return;
  int pos = atomicAdd(&cur[rows[i]], 1);
  cs[pos] = cols[i];
  vs[pos] = vals[i];
}

// ---------------------------------------------------------------------------
// Conv1 gather + fused BN: one wave per row.
//   h1[r,0:64]   = BN( sum_{adj1} v*h[c,:] )
//   h1[r,64:128] = BN( sum_{adj2} v*h[c,:] )
// ---------------------------------------------------------------------------
__global__ __launch_bounds__(256) void conv1_gather(
    const float* __restrict__ h,
    const int* __restrict__ rp1, const int* __restrict__ c1, const float* __restrict__ v1,
    const int* __restrict__ rp2, const int* __restrict__ c2, const float* __restrict__ v2,
    const float* __restrict__ gamma, const float* __restrict__ beta,
    const float* __restrict__ mean, const float* __restrict__ var,
    float* __restrict__ h1, int N) {
  int r    = (blockIdx.x * 256 + threadIdx.x) >> 6;
  int lane = threadIdx.x & 63;
  if (r >= N) return;
  float acc1 = 0.f, acc2 = 0.f;
  int s = rp1[r], e = rp1[r + 1];
  for (int j = s; j < e; ++j) {
    int c = c1[j]; float v = v1[j];
    acc1 += v * h[(size_t)c * 64 + lane];
  }
  s = rp2[r]; e = rp2[r + 1];
  for (int j = s; j < e; ++j) {
    int c = c2[j]; float v = v2[j];
    acc2 += v * h[(size_t)c * 64 + lane];
  }
  float sc1 = gamma[lane]      * rsqrtf(var[lane]      + BN_EPS);
  float sc2 = gamma[64 + lane] * rsqrtf(var[64 + lane] + BN_EPS);
  h1[(size_t)r * 128 + lane]      = (acc1 - mean[lane])      * sc1 + beta[lane];
  h1[(size_t)r * 128 + 64 + lane] = (acc2 - mean[64 + lane]) * sc2 + beta[64 + lane];
}

// ---------------------------------------------------------------------------
// g = h1 @ [Wf2a | Wf2b]   [N,128] @ [128,80] -> [N,80]
//   Wf2a = W_final rows 192..320, Wf2b = rows 320..448 (the h2 part of jk)
// ---------------------------------------------------------------------------
__global__ __launch_bounds__(320) void g_kernel(
    const float* __restrict__ h1, const float* __restrict__ Wf,
    float* __restrict__ g, int N) {
  __shared__ __align__(16) float hs[64][65];
  __shared__ __align__(16) float ws[64][80];
  const int tid  = threadIdx.x;
  const int cgrp = tid % 20;   // 20 col-groups of 4
  const int rgrp = tid / 20;   // 16 row-groups of 4
  const int row0 = blockIdx.x * 64;
  float acc[4][4] = {};

  for (int k0 = 0; k0 < 128; k0 += 64) {
    for (int idx = tid; idx < 64 * 64; idx += 320) {
      int r = idx >> 6, kk = idx & 63;
      int gr = row0 + r;
      hs[r][kk] = (gr < N) ? h1[(size_t)gr * 128 + k0 + kk] : 0.f;
    }
    for (int idx = tid; idx < 64 * 80; idx += 320) {
      int kk = idx / 80, j = idx % 80;
      int kr = k0 + kk;
      ws[kk][j] = (j < 40) ? Wf[(size_t)(192 + kr) * 40 + j]
                           : Wf[(size_t)(320 + kr) * 40 + (j - 40)];
    }
    __syncthreads();
#pragma unroll
    for (int kk = 0; kk < 64; ++kk) {
      float4 wv = *reinterpret_cast<const float4*>(&ws[kk][cgrp * 4]);
#pragma unroll
      for (int i = 0; i < 4; ++i) {
        float xv = hs[rgrp * 4 + i][kk];
        acc[i][0] += xv * wv.x; acc[i][1] += xv * wv.y;
        acc[i][2] += xv * wv.z; acc[i][3] += xv * wv.w;
      }
    }
    __syncthreads();
  }
#pragma unroll
  for (int i = 0; i < 4; ++i) {
    int gr = row0 + rgrp * 4 + i;
    if (gr < N) {
      *reinterpret_cast<float4*>(&g[(size_t)gr * 80 + cgrp * 4]) =
          make_float4(acc[i][0], acc[i][1], acc[i][2], acc[i][3]);
    }
  }
}

// ---------------------------------------------------------------------------
// Base final: out = [h | h1] @ Wf[0:192] + b_final   (h2 part added later)
// ---------------------------------------------------------------------------
__global__ __launch_bounds__(320) void final_base_kernel(
    const float* __restrict__ h, const float* __restrict__ h1,
    const float* __restrict__ Wf, const float* __restrict__ bf,
    float* __restrict__ out, int N) {
  __shared__ __align__(16) float js[64][65];
  __shared__ __align__(16) float wfs[64][40];
  const int tid  = threadIdx.x;
  const int cgrp = tid % 10;   // 10 col-groups of 4
  const int rgrp = tid / 10;   // 32 row-groups of 2
  const int row0 = blockIdx.x * 64;
  float acc[2][4] = {{0.f, 0.f, 0.f, 0.f}, {0.f, 0.f, 0.f, 0.f}};

  for (int ch = 0; ch < 3; ++ch) {
    const float* src;
    int stride, kloc;
    if (ch == 0) { src = h;  stride = 64;  kloc = 0; }
    else         { src = h1; stride = 128; kloc = (ch - 1) * 64; }

    for (int idx = tid; idx < 64 * 64; idx += 320) {
      int r = idx >> 6, kk = idx & 63;
      int gr = row0 + r;
      js[r][kk] = (gr < N) ? src[(size_t)gr * stride + kloc + kk] : 0.f;
    }
    for (int idx = tid; idx < 64 * 40; idx += 320) {
      int kk = idx / 40, c = idx % 40;
      wfs[kk][c] = Wf[(size_t)(ch * 64 + kk) * 40 + c];
    }
    __syncthreads();
#pragma unroll
    for (int kk = 0; kk < 64; ++kk) {
      float x0 = js[rgrp * 2 + 0][kk];
      float x1 = js[rgrp * 2 + 1][kk];
      float4 wv = *reinterpret_cast<const float4*>(&wfs[kk][cgrp * 4]);
      acc[0][0] += x0 * wv.x; acc[0][1] += x0 * wv.y;
      acc[0][2] += x0 * wv.z; acc[0][3] += x0 * wv.w;
      acc[1][0] += x1 * wv.x; acc[1][1] += x1 * wv.y;
      acc[1][2] += x1 * wv.z; acc[1][3] += x1 * wv.w;
    }
    __syncthreads();
  }

  float4 bv = *reinterpret_cast<const float4*>(&bf[cgrp * 4]);
#pragma unroll
  for (int i = 0; i < 2; ++i) {
    int gr = row0 + rgrp * 2 + i;
    if (gr < N) {
      float4 o;
      o.x = acc[i][0] + bv.x;
      o.y = acc[i][1] + bv.y;
      o.z = acc[i][2] + bv.z;
      o.w = acc[i][3] + bv.w;
      *reinterpret_cast<float4*>(&out[(size_t)gr * 40 + cgrp * 4]) = o;
    }
  }
}

// ---------------------------------------------------------------------------
// Final add: out[r,:] += sum_{adj1} v*g1[c,:] + sum_{adj2} v*g2[c,:]
// One wave per row, lanes 0..39 active.
// ---------------------------------------------------------------------------
__global__ __launch_bounds__(256) void final_add_kernel(
    const float* __restrict__ g,
    const int* __restrict__ rp1, const int* __restrict__ c1, const float* __restrict__ v1,
    const int* __restrict__ rp2, const int* __restrict__ c2, const float* __restrict__ v2,
    float* __restrict__ out, int N) {
  int r    = (blockIdx.x * 256 + threadIdx.x) >> 6;
  int lane = threadIdx.x & 63;
  if (r >= N || lane >= 40) return;
  float acc = 0.f;
  int s = rp1[r], e = rp1[r + 1];
  for (int j = s; j < e; ++j)
    acc += v1[j] * g[(size_t)c1[j] * 80 + lane];
  s = rp2[r]; e = rp2[r + 1];
  for (int j = s; j < e; ++j)
    acc += v2[j] * g[(size_t)c2[j] * 80 + 40 + lane];
  out[(size_t)r * 40 + lane] += acc;
}

// ---------------------------------------------------------------------------
extern "C" void kernel_launch(void* const* d_in, const int* in_sizes, int n_in,
                              void* d_out, int out_size, void* d_ws, size_t ws_size,
                              hipStream_t stream) {
  const float* x     = (const float*)d_in[0];
  const int*   a1r   = (const int*)d_in[1];
  const int*   a1c   = (const int*)d_in[2];
  const float* a1v   = (const float*)d_in[3];
  const int*   a2r   = (const int*)d_in[4];
  const int*   a2c   = (const int*)d_in[5];
  const float* a2v   = (const float*)d_in[6];
  const float* We    = (const float*)d_in[7];
  const float* be    = (const float*)d_in[8];
  const float* gamma = (const float*)d_in[9];
  const float* beta  = (const float*)d_in[10];
  const float* mean  = (const float*)d_in[11];
  const float* var   = (const float*)d_in[12];
  const float* Wf    = (const float*)d_in[13];
  const float* bf    = (const float*)d_in[14];
  float* out = (float*)d_out;

  const int N  = in_sizes[0] / 512;
  const int E1 = in_sizes[1];
  const int E2 = in_sizes[4];

  char* p = (char*)d_ws;
  auto alloc = [&](size_t bytes) { char* q = p; p += bytes; return q; };
  float* h    = (float*)alloc((size_t)N * 64  * 4);
  float* h1   = (float*)alloc((size_t)N * 128 * 4);
  float* g    = (float*)alloc((size_t)N * 80  * 4);
  int*   rp1  = (int*)  alloc(((size_t)N + 1) * 4);
  int*   rp2  = (int*)  alloc(((size_t)N + 1) * 4);
  int*   cur1 = (int*)  alloc((size_t)N * 4);
  int*   cur2 = (int*)  alloc((size_t)N * 4);
  int*   cnt1 = (int*)  alloc((size_t)N * 4);
  int*   cnt2 = (int*)  alloc((size_t)N * 4);   // adjacent to cnt1
  int*   c1s  = (int*)  alloc((size_t)E1 * 4);
  float* v1s  = (float*)alloc((size_t)E1 * 4);
  int*   c2s  = (int*)  alloc((size_t)E2 * 4);
  float* v2s  = (float*)alloc((size_t)E2 * 4);

  // --- CSR build (both graphs; each CSR used by conv1 and the final add) ---
  hipMemsetAsync(cnt1, 0, (size_t)2 * N * 4, stream);
  hist_kernel<<<(E1 + 255) / 256, 256, 0, stream>>>(a1r, cnt1, E1);
  hist_kernel<<<(E2 + 255) / 256, 256, 0, stream>>>(a2r, cnt2, E2);
  scan_kernel<<<1, 1024, 0, stream>>>(cnt1, rp1, cur1, N);
  scan_kernel<<<1, 1024, 0, stream>>>(cnt2, rp2, cur2, N);
  scatter_kernel<<<(E1 + 255) / 256, 256, 0, stream>>>(a1r, a1c, a1v, cur1, c1s, v1s, E1);
  scatter_kernel<<<(E2 + 255) / 256, 256, 0, stream>>>(a2r, a2c, a2v, cur2, c2s, v2s, E2);

  // --- embed ---
  embed_kernel<<<(N + 31) / 32, 256, 0, stream>>>(x, We, be, h, N);

  // --- conv1 (gather) + fused BN ---
  conv1_gather<<<(N * 64 + 255) / 256, 256, 0, stream>>>(
      h, rp1, c1s, v1s, rp2, c2s, v2s, gamma, beta, mean, var, h1, N);

  // --- g = h1 @ [Wf2a|Wf2b] ---
  g_kernel<<<(N + 63) / 64, 320, 0, stream>>>(h1, Wf, g, N);

  // --- out = [h|h1] @ Wf[0:192] + b ---
  final_base_kernel<<<(N + 63) / 64, 320, 0, stream>>>(h, h1, Wf, bf, out, N);

  // --- out += A1@g1 + A2@g2 ---
  final_add_kernel<<<(N * 64 + 255) / 256, 256, 0, stream>>>(
      g, rp1, c1s, v1s, rp2, c2s, v2s, out, N);
}

// Round 3
// 746.104 us; speedup vs baseline: 10.3494x; 1.5534x over previous
//
#include <hip/hip_runtime.h>

#define BN_EPS 1e-5f

__device__ __forceinline__ ushort f2bf(float f) {
  uint u = __float_as_uint(f);
  u += 0x7fffu + ((u >> 16) & 1u);
  return (ushort)(u >> 16);
}

// ---------------------------------------------------------------------------
// Embed: h = relu(x @ W_embed + b_embed)   [N,512] @ [512,64] -> [N,64]
// Writes both f32 h (for final_base) and bf16 h (for conv1 gather).
// ---------------------------------------------------------------------------
__global__ __launch_bounds__(256) void embed_kernel(
    const float* __restrict__ x, const float* __restrict__ W,
    const float* __restrict__ b, float* __restrict__ h,
    ushort* __restrict__ hb, int N) {
  __shared__ __align__(16) float xs[32][68];
  __shared__ __align__(16) float ws[64][64];
  const int tid  = threadIdx.x;
  const int cgrp = tid & 15;   // 16 col-groups of 4
  const int rgrp = tid >> 4;   // 16 row-groups of 2
  const int row0 = blockIdx.x * 32;

  float acc[2][4] = {{0.f, 0.f, 0.f, 0.f}, {0.f, 0.f, 0.f, 0.f}};

  for (int k0 = 0; k0 < 512; k0 += 64) {
    for (int idx = tid; idx < 32 * 16; idx += 256) {
      int r = idx >> 4, k4 = idx & 15;
      int gr = row0 + r;
      float4 xv = make_float4(0.f, 0.f, 0.f, 0.f);
      if (gr < N) xv = *reinterpret_cast<const float4*>(x + (size_t)gr * 512 + k0 + k4 * 4);
      *reinterpret_cast<float4*>(&xs[r][k4 * 4]) = xv;
    }
    for (int idx = tid; idx < 64 * 16; idx += 256) {
      int kk = idx >> 4, c4 = idx & 15;
      *reinterpret_cast<float4*>(&ws[kk][c4 * 4]) =
          *reinterpret_cast<const float4*>(W + (size_t)(k0 + kk) * 64 + c4 * 4);
    }
    __syncthreads();
#pragma unroll
    for (int kk = 0; kk < 64; ++kk) {
      float x0 = xs[rgrp * 2 + 0][kk];
      float x1 = xs[rgrp * 2 + 1][kk];
      float4 wv = *reinterpret_cast<const float4*>(&ws[kk][cgrp * 4]);
      acc[0][0] += x0 * wv.x; acc[0][1] += x0 * wv.y;
      acc[0][2] += x0 * wv.z; acc[0][3] += x0 * wv.w;
      acc[1][0] += x1 * wv.x; acc[1][1] += x1 * wv.y;
      acc[1][2] += x1 * wv.z; acc[1][3] += x1 * wv.w;
    }
    __syncthreads();
  }

  float4 bv = *reinterpret_cast<const float4*>(&b[cgrp * 4]);
#pragma unroll
  for (int i = 0; i < 2; ++i) {
    int gr = row0 + rgrp * 2 + i;
    if (gr < N) {
      float4 o;
      o.x = fmaxf(acc[i][0] + bv.x, 0.f);
      o.y = fmaxf(acc[i][1] + bv.y, 0.f);
      o.z = fmaxf(acc[i][2] + bv.z, 0.f);
      o.w = fmaxf(acc[i][3] + bv.w, 0.f);
      *reinterpret_cast<float4*>(&h[(size_t)gr * 64 + cgrp * 4]) = o;
      ushort4 ob;
      ob.x = f2bf(o.x); ob.y = f2bf(o.y); ob.z = f2bf(o.z); ob.w = f2bf(o.w);
      *reinterpret_cast<ushort4*>(&hb[(size_t)gr * 64 + cgrp * 4]) = ob;
    }
  }
}

// ---------------------------------------------------------------------------
// CSR build
// ---------------------------------------------------------------------------
__global__ __launch_bounds__(256) void hist_kernel(
    const int* __restrict__ rows, int* __restrict__ cnt, int E) {
  int i = blockIdx.x * blockDim.x + threadIdx.x;
  if (i < E) atomicAdd(&cnt[rows[i]], 1);
}

// 2 blocks: block 0 scans graph1 counts, block 1 graph2. 8 elems/thread.
__global__ __launch_bounds__(1024) void scan_kernel(
    int* __restrict__ cnt1, int* __restrict__ rp1, int* __restrict__ cur1,
    int* __restrict__ cnt2, int* __restrict__ rp2, int* __restrict__ cur2,
    int N) {
  int* cnt = blockIdx.x ? cnt2 : cnt1;
  int* rp  = blockIdx.x ? rp2  : rp1;
  int* cur = blockIdx.x ? cur2 : cur1;
  __shared__ int wsum[16];
  __shared__ int carry;
  const int tid  = threadIdx.x;
  const int lane = tid & 63;
  const int w    = tid >> 6;
  if (tid == 0) { carry = 0; rp[0] = 0; }
  __syncthreads();
  for (int t0 = 0; t0 < N; t0 += 8192) {
    int i0 = t0 + tid * 8;
    int v[8];
    if (i0 + 8 <= N) {
      int4 a = *reinterpret_cast<const int4*>(cnt + i0);
      int4 bq = *reinterpret_cast<const int4*>(cnt + i0 + 4);
      v[0] = a.x; v[1] = a.y; v[2] = a.z; v[3] = a.w;
      v[4] = bq.x; v[5] = bq.y; v[6] = bq.z; v[7] = bq.w;
    } else {
#pragma unroll
      for (int t = 0; t < 8; ++t) v[t] = (i0 + t < N) ? cnt[i0 + t] : 0;
    }
    int pre[8]; int run = 0;
#pragma unroll
    for (int t = 0; t < 8; ++t) { run += v[t]; pre[t] = run; }
    int incl = run;
#pragma unroll
    for (int off = 1; off < 64; off <<= 1) {
      int y = __shfl_up(incl, off);
      if (lane >= off) incl += y;
    }
    if (lane == 63) wsum[w] = incl;
    __syncthreads();
    if (w == 0) {
      int xv = (lane < 16) ? wsum[lane] : 0;
#pragma unroll
      for (int off = 1; off < 16; off <<= 1) {
        int y = __shfl_up(xv, off);
        if (lane >= off) xv += y;
      }
      if (lane < 16) wsum[lane] = xv;
    }
    __syncthreads();
    int tbase = carry + ((w > 0) ? wsum[w - 1] : 0) + (incl - run);
#pragma unroll
    for (int t = 0; t < 8; ++t) {
      int i = i0 + t;
      if (i < N) { rp[i + 1] = tbase + pre[t]; cur[i] = tbase + pre[t] - v[t]; }
    }
    __syncthreads();
    if (tid == 0) carry += wsum[15];
    __syncthreads();
  }
}

// Scatter (col, val) as packed int2 into row-sorted order.
__global__ __launch_bounds__(256) void scatter_kernel(
    const int* __restrict__ rows, const int* __restrict__ cols,
    const float* __restrict__ vals, int* __restrict__ cur,
    int2* __restrict__ E, int Ecnt) {
  int i = blockIdx.x * blockDim.x + threadIdx.x;
  if (i >= Ecnt) return;
  int pos = atomicAdd(&cur[rows[i]], 1);
  E[pos] = make_int2(cols[i], __float_as_int(vals[i]));
}

// ---------------------------------------------------------------------------
// Conv1 gather + fused BN. One wave per row (grid-stride).
// bf16 h rows are 128B = 8 lanes x 16B -> 8 edges per VMEM instruction.
// sub = lane>>3 (edge slot), q = lane&7 (feature block of 8).
// ---------------------------------------------------------------------------
__global__ __launch_bounds__(256) void conv1_gather(
    const ushort* __restrict__ hb,
    const int* __restrict__ rp1, const int2* __restrict__ E1,
    const int* __restrict__ rp2, const int2* __restrict__ E2,
    const float* __restrict__ gamma, const float* __restrict__ beta,
    const float* __restrict__ mean, const float* __restrict__ var,
    float* __restrict__ h1, int N, int nwaves) {
  const int wid  = (blockIdx.x * blockDim.x + threadIdx.x) >> 6;
  const int lane = threadIdx.x & 63;
  const int sub  = lane >> 3;
  const int q    = lane & 7;

  // Hoisted BN scale/shift for the 8 features lane<8 will store (x2 graphs).
  float sc1[8], sh1[8], sc2[8], sh2[8];
#pragma unroll
  for (int t4 = 0; t4 < 2; ++t4) {
    int f1 = q * 8 + t4 * 4;
    float4 gm = *reinterpret_cast<const float4*>(gamma + f1);
    float4 vr = *reinterpret_cast<const float4*>(var + f1);
    float4 mn = *reinterpret_cast<const float4*>(mean + f1);
    float4 bt = *reinterpret_cast<const float4*>(beta + f1);
    float s0 = gm.x * rsqrtf(vr.x + BN_EPS), s1 = gm.y * rsqrtf(vr.y + BN_EPS);
    float s2 = gm.z * rsqrtf(vr.z + BN_EPS), s3 = gm.w * rsqrtf(vr.w + BN_EPS);
    sc1[t4 * 4 + 0] = s0; sh1[t4 * 4 + 0] = bt.x - mn.x * s0;
    sc1[t4 * 4 + 1] = s1; sh1[t4 * 4 + 1] = bt.y - mn.y * s1;
    sc1[t4 * 4 + 2] = s2; sh1[t4 * 4 + 2] = bt.z - mn.z * s2;
    sc1[t4 * 4 + 3] = s3; sh1[t4 * 4 + 3] = bt.w - mn.w * s3;
    int f2 = 64 + f1;
    gm = *reinterpret_cast<const float4*>(gamma + f2);
    vr = *reinterpret_cast<const float4*>(var + f2);
    mn = *reinterpret_cast<const float4*>(mean + f2);
    bt = *reinterpret_cast<const float4*>(beta + f2);
    s0 = gm.x * rsqrtf(vr.x + BN_EPS); s1 = gm.y * rsqrtf(vr.y + BN_EPS);
    s2 = gm.z * rsqrtf(vr.z + BN_EPS); s3 = gm.w * rsqrtf(vr.w + BN_EPS);
    sc2[t4 * 4 + 0] = s0; sh2[t4 * 4 + 0] = bt.x - mn.x * s0;
    sc2[t4 * 4 + 1] = s1; sh2[t4 * 4 + 1] = bt.y - mn.y * s1;
    sc2[t4 * 4 + 2] = s2; sh2[t4 * 4 + 2] = bt.z - mn.z * s2;
    sc2[t4 * 4 + 3] = s3; sh2[t4 * 4 + 3] = bt.w - mn.w * s3;
  }

  for (int r = wid; r < N; r += nwaves) {
    float acc1[8] = {0, 0, 0, 0, 0, 0, 0, 0};
    float acc2[8] = {0, 0, 0, 0, 0, 0, 0, 0};
    {
      int s = rp1[r], e = rp1[r + 1];
      for (int j0 = s; j0 < e; j0 += 8) {
        int jj = j0 + sub;
        int2 m = (jj < e) ? E1[jj] : make_int2(0, 0);
        float v = __int_as_float(m.y);
        uint4 wv = *reinterpret_cast<const uint4*>(hb + (size_t)m.x * 64 + q * 8);
        acc1[0] += v * __uint_as_float(wv.x << 16);
        acc1[1] += v * __uint_as_float(wv.x & 0xffff0000u);
        acc1[2] += v * __uint_as_float(wv.y << 16);
        acc1[3] += v * __uint_as_float(wv.y & 0xffff0000u);
        acc1[4] += v * __uint_as_float(wv.z << 16);
        acc1[5] += v * __uint_as_float(wv.z & 0xffff0000u);
        acc1[6] += v * __uint_as_float(wv.w << 16);
        acc1[7] += v * __uint_as_float(wv.w & 0xffff0000u);
      }
    }
    {
      int s = rp2[r], e = rp2[r + 1];
      for (int j0 = s; j0 < e; j0 += 8) {
        int jj = j0 + sub;
        int2 m = (jj < e) ? E2[jj] : make_int2(0, 0);
        float v = __int_as_float(m.y);
        uint4 wv = *reinterpret_cast<const uint4*>(hb + (size_t)m.x * 64 + q * 8);
        acc2[0] += v * __uint_as_float(wv.x << 16);
        acc2[1] += v * __uint_as_float(wv.x & 0xffff0000u);
        acc2[2] += v * __uint_as_float(wv.y << 16);
        acc2[3] += v * __uint_as_float(wv.y & 0xffff0000u);
        acc2[4] += v * __uint_as_float(wv.z << 16);
        acc2[5] += v * __uint_as_float(wv.z & 0xffff0000u);
        acc2[6] += v * __uint_as_float(wv.w << 16);
        acc2[7] += v * __uint_as_float(wv.w & 0xffff0000u);
      }
    }
#pragma unroll
    for (int mask = 8; mask <= 32; mask <<= 1) {
#pragma unroll
      for (int t = 0; t < 8; ++t) {
        acc1[t] += __shfl_xor(acc1[t], mask);
        acc2[t] += __shfl_xor(acc2[t], mask);
      }
    }
    if (lane < 8) {
      float o1[8], o2[8];
#pragma unroll
      for (int t = 0; t < 8; ++t) {
        o1[t] = acc1[t] * sc1[t] + sh1[t];
        o2[t] = acc2[t] * sc2[t] + sh2[t];
      }
      float* dst = h1 + (size_t)r * 128 + q * 8;
      *reinterpret_cast<float4*>(dst)          = make_float4(o1[0], o1[1], o1[2], o1[3]);
      *reinterpret_cast<float4*>(dst + 4)      = make_float4(o1[4], o1[5], o1[6], o1[7]);
      *reinterpret_cast<float4*>(dst + 64)     = make_float4(o2[0], o2[1], o2[2], o2[3]);
      *reinterpret_cast<float4*>(dst + 68)     = make_float4(o2[4], o2[5], o2[6], o2[7]);
    }
  }
}

// ---------------------------------------------------------------------------
// g = h1 @ [Wf2a | Wf2b]   [N,128] @ [128,80] -> [N,80]
// ---------------------------------------------------------------------------
__global__ __launch_bounds__(320) void g_kernel(
    const float* __restrict__ h1, const float* __restrict__ Wf,
    float* __restrict__ g, int N) {
  __shared__ __align__(16) float hs[64][65];
  __shared__ __align__(16) float ws[64][80];
  const int tid  = threadIdx.x;
  const int cgrp = tid % 20;
  const int rgrp = tid / 20;
  const int row0 = blockIdx.x * 64;
  float acc[4][4] = {};

  for (int k0 = 0; k0 < 128; k0 += 64) {
    for (int idx = tid; idx < 64 * 64; idx += 320) {
      int r = idx >> 6, kk = idx & 63;
      int gr = row0 + r;
      hs[r][kk] = (gr < N) ? h1[(size_t)gr * 128 + k0 + kk] : 0.f;
    }
    for (int idx = tid; idx < 64 * 80; idx += 320) {
      int kk = idx / 80, j = idx % 80;
      int kr = k0 + kk;
      ws[kk][j] = (j < 40) ? Wf[(size_t)(192 + kr) * 40 + j]
                           : Wf[(size_t)(320 + kr) * 40 + (j - 40)];
    }
    __syncthreads();
#pragma unroll
    for (int kk = 0; kk < 64; ++kk) {
      float4 wv = *reinterpret_cast<const float4*>(&ws[kk][cgrp * 4]);
#pragma unroll
      for (int i = 0; i < 4; ++i) {
        float xv = hs[rgrp * 4 + i][kk];
        acc[i][0] += xv * wv.x; acc[i][1] += xv * wv.y;
        acc[i][2] += xv * wv.z; acc[i][3] += xv * wv.w;
      }
    }
    __syncthreads();
  }
#pragma unroll
  for (int i = 0; i < 4; ++i) {
    int gr = row0 + rgrp * 4 + i;
    if (gr < N) {
      *reinterpret_cast<float4*>(&g[(size_t)gr * 80 + cgrp * 4]) =
          make_float4(acc[i][0], acc[i][1], acc[i][2], acc[i][3]);
    }
  }
}

// ---------------------------------------------------------------------------
// Base final: out = [h | h1] @ Wf[0:192] + b_final
// ---------------------------------------------------------------------------
__global__ __launch_bounds__(320) void final_base_kernel(
    const float* __restrict__ h, const float* __restrict__ h1,
    const float* __restrict__ Wf, const float* __restrict__ bf,
    float* __restrict__ out, int N) {
  __shared__ __align__(16) float js[64][65];
  __shared__ __align__(16) float wfs[64][40];
  const int tid  = threadIdx.x;
  const int cgrp = tid % 10;
  const int rgrp = tid / 10;
  const int row0 = blockIdx.x * 64;
  float acc[2][4] = {{0.f, 0.f, 0.f, 0.f}, {0.f, 0.f, 0.f, 0.f}};

  for (int ch = 0; ch < 3; ++ch) {
    const float* src;
    int stride, kloc;
    if (ch == 0) { src = h;  stride = 64;  kloc = 0; }
    else         { src = h1; stride = 128; kloc = (ch - 1) * 64; }

    for (int idx = tid; idx < 64 * 64; idx += 320) {
      int r = idx >> 6, kk = idx & 63;
      int gr = row0 + r;
      js[r][kk] = (gr < N) ? src[(size_t)gr * stride + kloc + kk] : 0.f;
    }
    for (int idx = tid; idx < 64 * 40; idx += 320) {
      int kk = idx / 40, c = idx % 40;
      wfs[kk][c] = Wf[(size_t)(ch * 64 + kk) * 40 + c];
    }
    __syncthreads();
#pragma unroll
    for (int kk = 0; kk < 64; ++kk) {
      float x0 = js[rgrp * 2 + 0][kk];
      float x1 = js[rgrp * 2 + 1][kk];
      float4 wv = *reinterpret_cast<const float4*>(&wfs[kk][cgrp * 4]);
      acc[0][0] += x0 * wv.x; acc[0][1] += x0 * wv.y;
      acc[0][2] += x0 * wv.z; acc[0][3] += x0 * wv.w;
      acc[1][0] += x1 * wv.x; acc[1][1] += x1 * wv.y;
      acc[1][2] += x1 * wv.z; acc[1][3] += x1 * wv.w;
    }
    __syncthreads();
  }

  float4 bv = *reinterpret_cast<const float4*>(&bf[cgrp * 4]);
#pragma unroll
  for (int i = 0; i < 2; ++i) {
    int gr = row0 + rgrp * 2 + i;
    if (gr < N) {
      float4 o;
      o.x = acc[i][0] + bv.x;
      o.y = acc[i][1] + bv.y;
      o.z = acc[i][2] + bv.z;
      o.w = acc[i][3] + bv.w;
      *reinterpret_cast<float4*>(&out[(size_t)gr * 40 + cgrp * 4]) = o;
    }
  }
}

// ---------------------------------------------------------------------------
// Final add: out[r,:] += sum_{adj1} v*g[c,0:40] + sum_{adj2} v*g[c,40:80]
// One wave per row (grid-stride). sub = lane>>4 (4 edges/instr), q = lane&15,
// lanes q<10 carry real data; q>=10 compute garbage that is discarded.
// ---------------------------------------------------------------------------
__global__ __launch_bounds__(256) void final_add_kernel(
    const float* __restrict__ g,
    const int* __restrict__ rp1, const int2* __restrict__ E1,
    const int* __restrict__ rp2, const int2* __restrict__ E2,
    float* __restrict__ out, int N, int nwaves) {
  const int wid  = (blockIdx.x * blockDim.x + threadIdx.x) >> 6;
  const int lane = threadIdx.x & 63;
  const int sub  = lane >> 4;
  const int q    = lane & 15;
  const int off1 = (q < 10) ? q * 4 : 0;        // stay in-bounds for q>=10
  const int off2 = 40 + off1;

  for (int r = wid; r < N; r += nwaves) {
    float a1[4] = {0, 0, 0, 0}, a2[4] = {0, 0, 0, 0};
    {
      int s = rp1[r], e = rp1[r + 1];
      for (int j0 = s; j0 < e; j0 += 4) {
        int jj = j0 + sub;
        int2 m = (jj < e) ? E1[jj] : make_int2(0, 0);
        float v = __int_as_float(m.y);
        float4 gv = *reinterpret_cast<const float4*>(g + (size_t)m.x * 80 + off1);
        a1[0] += v * gv.x; a1[1] += v * gv.y; a1[2] += v * gv.z; a1[3] += v * gv.w;
      }
    }
    {
      int s = rp2[r], e = rp2[r + 1];
      for (int j0 = s; j0 < e; j0 += 4) {
        int jj = j0 + sub;
        int2 m = (jj < e) ? E2[jj] : make_int2(0, 0);
        float v = __int_as_float(m.y);
        float4 gv = *reinterpret_cast<const float4*>(g + (size_t)m.x * 80 + off2);
        a2[0] += v * gv.x; a2[1] += v * gv.y; a2[2] += v * gv.z; a2[3] += v * gv.w;
      }
    }
#pragma unroll
    for (int mask = 16; mask <= 32; mask <<= 1) {
#pragma unroll
      for (int t = 0; t < 4; ++t) {
        a1[t] += __shfl_xor(a1[t], mask);
        a2[t] += __shfl_xor(a2[t], mask);
      }
    }
    if (lane < 10) {
      float* p = out + (size_t)r * 40 + q * 4;
      float4 o = *reinterpret_cast<const float4*>(p);
      o.x += a1[0] + a2[0]; o.y += a1[1] + a2[1];
      o.z += a1[2] + a2[2]; o.w += a1[3] + a2[3];
      *reinterpret_cast<float4*>(p) = o;
    }
  }
}

// ---------------------------------------------------------------------------
extern "C" void kernel_launch(void* const* d_in, const int* in_sizes, int n_in,
                              void* d_out, int out_size, void* d_ws, size_t ws_size,
                              hipStream_t stream) {
  const float* x     = (const float*)d_in[0];
  const int*   a1r   = (const int*)d_in[1];
  const int*   a1c   = (const int*)d_in[2];
  const float* a1v   = (const float*)d_in[3];
  const int*   a2r   = (const int*)d_in[4];
  const int*   a2c   = (const int*)d_in[5];
  const float* a2v   = (const float*)d_in[6];
  const float* We    = (const float*)d_in[7];
  const float* be    = (const float*)d_in[8];
  const float* gamma = (const float*)d_in[9];
  const float* beta  = (const float*)d_in[10];
  const float* mean  = (const float*)d_in[11];
  const float* var   = (const float*)d_in[12];
  const float* Wf    = (const float*)d_in[13];
  const float* bf    = (const float*)d_in[14];
  float* out = (float*)d_out;

  const int N  = in_sizes[0] / 512;
  const int E1 = in_sizes[1];
  const int E2 = in_sizes[4];

  char* p = (char*)d_ws;
  auto alloc = [&](size_t bytes) {
    char* q = p; p += (bytes + 255) & ~(size_t)255; return q;
  };
  float*  h    = (float*) alloc((size_t)N * 64 * 4);
  ushort* hb   = (ushort*)alloc((size_t)N * 64 * 2);
  float*  h1   = (float*) alloc((size_t)N * 128 * 4);
  float*  g    = (float*) alloc((size_t)N * 80 * 4);
  int*    rp1  = (int*)   alloc(((size_t)N + 1) * 4);
  int*    rp2  = (int*)   alloc(((size_t)N + 1) * 4);
  int*    cur1 = (int*)   alloc((size_t)N * 4);
  int*    cur2 = (int*)   alloc((size_t)N * 4);
  int*    cnt  = (int*)   alloc((size_t)2 * N * 4);  // cnt1 | cnt2
  int2*   E1s  = (int2*)  alloc((size_t)E1 * 8);
  int2*   E2s  = (int2*)  alloc((size_t)E2 * 8);
  int* cnt1 = cnt;
  int* cnt2 = cnt + N;

  hipMemsetAsync(cnt, 0, (size_t)2 * N * 4, stream);

  // embed (independent of CSR build)
  embed_kernel<<<(N + 31) / 32, 256, 0, stream>>>(x, We, be, h, hb, N);

  // CSR build
  hist_kernel<<<(E1 + 255) / 256, 256, 0, stream>>>(a1r, cnt1, E1);
  hist_kernel<<<(E2 + 255) / 256, 256, 0, stream>>>(a2r, cnt2, E2);
  scan_kernel<<<2, 1024, 0, stream>>>(cnt1, rp1, cur1, cnt2, rp2, cur2, N);
  scatter_kernel<<<(E1 + 255) / 256, 256, 0, stream>>>(a1r, a1c, a1v, cur1, E1s, E1);
  scatter_kernel<<<(E2 + 255) / 256, 256, 0, stream>>>(a2r, a2c, a2v, cur2, E2s, E2);

  // conv1 (gather, 8 edges per VMEM) + fused BN
  const int NW = 2048 * 4;  // waves
  conv1_gather<<<2048, 256, 0, stream>>>(
      hb, rp1, E1s, rp2, E2s, gamma, beta, mean, var, h1, N, NW);

  // g = h1 @ [Wf2a|Wf2b]
  g_kernel<<<(N + 63) / 64, 320, 0, stream>>>(h1, Wf, g, N);

  // out = [h|h1] @ Wf[0:192] + b
  final_base_kernel<<<(N + 63) / 64, 320, 0, stream>>>(h, h1, Wf, bf, out, N);

  // out += A1@g1 + A2@g2 (4 edges per VMEM)
  final_add_kernel<<<2048, 256, 0, stream>>>(
      g, rp1, E1s, rp2, E2s, out, N, NW);
}

// Round 4
// 462.370 us; speedup vs baseline: 16.7003x; 1.6137x over previous
//
#include <hip/hip_runtime.h>

#define BN_EPS 1e-5f
#define MAXBINS 128   // bins of 512 rows; requires N <= 65536 (col packs in 16 bits)

__device__ __forceinline__ ushort f2bf(float f) {
  uint u = __float_as_uint(f);
  u += 0x7fffu + ((u >> 16) & 1u);
  return (ushort)(u >> 16);
}
__device__ __forceinline__ float bf2f(ushort u) {
  return __uint_as_float((uint)u << 16);
}

// ---------------------------------------------------------------------------
// Embed: hb = bf16( relu(x @ W_embed + b_embed) )   [N,512]@[512,64] -> [N,64]
// ---------------------------------------------------------------------------
__global__ __launch_bounds__(256) void embed_kernel(
    const float* __restrict__ x, const float* __restrict__ W,
    const float* __restrict__ b, ushort* __restrict__ hb, int N) {
  __shared__ __align__(16) float xs[32][68];
  __shared__ __align__(16) float ws[64][64];
  const int tid  = threadIdx.x;
  const int cgrp = tid & 15;   // 16 col-groups of 4
  const int rgrp = tid >> 4;   // 16 row-groups of 2
  const int row0 = blockIdx.x * 32;

  float acc[2][4] = {{0.f, 0.f, 0.f, 0.f}, {0.f, 0.f, 0.f, 0.f}};

  for (int k0 = 0; k0 < 512; k0 += 64) {
    for (int idx = tid; idx < 32 * 16; idx += 256) {
      int r = idx >> 4, k4 = idx & 15;
      int gr = row0 + r;
      float4 xv = make_float4(0.f, 0.f, 0.f, 0.f);
      if (gr < N) xv = *reinterpret_cast<const float4*>(x + (size_t)gr * 512 + k0 + k4 * 4);
      *reinterpret_cast<float4*>(&xs[r][k4 * 4]) = xv;
    }
    for (int idx = tid; idx < 64 * 16; idx += 256) {
      int kk = idx >> 4, c4 = idx & 15;
      *reinterpret_cast<float4*>(&ws[kk][c4 * 4]) =
          *reinterpret_cast<const float4*>(W + (size_t)(k0 + kk) * 64 + c4 * 4);
    }
    __syncthreads();
#pragma unroll
    for (int kk = 0; kk < 64; ++kk) {
      float x0 = xs[rgrp * 2 + 0][kk];
      float x1 = xs[rgrp * 2 + 1][kk];
      float4 wv = *reinterpret_cast<const float4*>(&ws[kk][cgrp * 4]);
      acc[0][0] += x0 * wv.x; acc[0][1] += x0 * wv.y;
      acc[0][2] += x0 * wv.z; acc[0][3] += x0 * wv.w;
      acc[1][0] += x1 * wv.x; acc[1][1] += x1 * wv.y;
      acc[1][2] += x1 * wv.z; acc[1][3] += x1 * wv.w;
    }
    __syncthreads();
  }

  float4 bv = *reinterpret_cast<const float4*>(&b[cgrp * 4]);
#pragma unroll
  for (int i = 0; i < 2; ++i) {
    int gr = row0 + rgrp * 2 + i;
    if (gr < N) {
      ushort4 ob;
      ob.x = f2bf(fmaxf(acc[i][0] + bv.x, 0.f));
      ob.y = f2bf(fmaxf(acc[i][1] + bv.y, 0.f));
      ob.z = f2bf(fmaxf(acc[i][2] + bv.z, 0.f));
      ob.w = f2bf(fmaxf(acc[i][3] + bv.w, 0.f));
      *reinterpret_cast<ushort4*>(&hb[(size_t)gr * 64 + cgrp * 4]) = ob;
    }
  }
}

// ---------------------------------------------------------------------------
// CSR build, two-level binned (bin = row>>9):
//   bin_hist -> bin_scan -> bin_scatter (staging, bin-grouped) -> csr_finalize
// ---------------------------------------------------------------------------
__global__ __launch_bounds__(256) void bin_hist(
    const int* __restrict__ rows, int* __restrict__ gbin, int E, int nbins) {
  __shared__ int lb[MAXBINS];
  const int tid = threadIdx.x;
  if (tid < nbins) lb[tid] = 0;
  __syncthreads();
  const int stride = gridDim.x * blockDim.x;
  for (int i = blockIdx.x * blockDim.x + tid; i < E; i += stride)
    atomicAdd(&lb[rows[i] >> 9], 1);
  __syncthreads();
  if (tid < nbins && lb[tid]) atomicAdd(&gbin[tid], lb[tid]);
}

__device__ __forceinline__ void scan_bins_dev(
    const int* gbin, int* gbase, int* gcur, int nbins, int lane) {
  int carry = 0;
  for (int ch = 0; ch * 64 < nbins; ++ch) {
    int idx = ch * 64 + lane;
    int v = (idx < nbins) ? gbin[idx] : 0;
    int inc = v;
#pragma unroll
    for (int off = 1; off < 64; off <<= 1) {
      int y = __shfl_up(inc, off);
      if (lane >= off) inc += y;
    }
    int ex = carry + inc - v;
    if (idx < nbins) { gbase[idx] = ex; gcur[idx] = ex; }
    carry += __shfl(inc, 63);
  }
}

__global__ __launch_bounds__(64) void bin_scan(
    const int* __restrict__ gbin1, int* __restrict__ gbase1, int* __restrict__ gcur1,
    const int* __restrict__ gbin2, int* __restrict__ gbase2, int* __restrict__ gcur2,
    int nbins) {
  int lane = threadIdx.x;
  scan_bins_dev(gbin1, gbase1, gcur1, nbins, lane);
  scan_bins_dev(gbin2, gbase2, gcur2, nbins, lane);
}

// Staging record: int2( col | (row&511)<<16 , val_bits ). Per 2048-edge chunk
// each block reserves contiguous per-bin ranges -> near-sequential writes.
__global__ __launch_bounds__(256) void bin_scatter(
    const int* __restrict__ rows, const int* __restrict__ cols,
    const float* __restrict__ vals, int E, int* __restrict__ gcur,
    int2* __restrict__ S, int nbins) {
  __shared__ int lcnt[MAXBINS];
  __shared__ int lcur[MAXBINS];
  const int tid = threadIdx.x;
  for (int e0 = blockIdx.x * 2048; e0 < E; e0 += gridDim.x * 2048) {
    int i0 = e0 + tid * 8;
    int r[8], c[8], vb[8];
    if (i0 + 8 <= E) {
      int4 a = *reinterpret_cast<const int4*>(rows + i0);
      int4 b = *reinterpret_cast<const int4*>(rows + i0 + 4);
      r[0]=a.x; r[1]=a.y; r[2]=a.z; r[3]=a.w; r[4]=b.x; r[5]=b.y; r[6]=b.z; r[7]=b.w;
      a = *reinterpret_cast<const int4*>(cols + i0);
      b = *reinterpret_cast<const int4*>(cols + i0 + 4);
      c[0]=a.x; c[1]=a.y; c[2]=a.z; c[3]=a.w; c[4]=b.x; c[5]=b.y; c[6]=b.z; c[7]=b.w;
      a = *reinterpret_cast<const int4*>(vals + i0);
      b = *reinterpret_cast<const int4*>(vals + i0 + 4);
      vb[0]=a.x; vb[1]=a.y; vb[2]=a.z; vb[3]=a.w; vb[4]=b.x; vb[5]=b.y; vb[6]=b.z; vb[7]=b.w;
    } else {
#pragma unroll
      for (int t = 0; t < 8; ++t) {
        int i = i0 + t;
        bool ok = i < E;
        r[t]  = ok ? rows[i] : -1;
        c[t]  = ok ? cols[i] : 0;
        vb[t] = ok ? __float_as_int(vals[i]) : 0;
      }
    }
    if (tid < nbins) lcnt[tid] = 0;
    __syncthreads();
#pragma unroll
    for (int t = 0; t < 8; ++t)
      if (r[t] >= 0) atomicAdd(&lcnt[r[t] >> 9], 1);
    __syncthreads();
    if (tid < nbins) {
      int n = lcnt[tid];
      lcur[tid] = n ? atomicAdd(&gcur[tid], n) : 0;
    }
    __syncthreads();
#pragma unroll
    for (int t = 0; t < 8; ++t) {
      if (r[t] >= 0) {
        int pos = atomicAdd(&lcur[r[t] >> 9], 1);
        S[pos] = make_int2(c[t] | ((r[t] & 511) << 16), vb[t]);
      }
    }
    __syncthreads();
  }
}

// One block per (graph, bin). LDS per-row counts -> scan -> rowptr + scatter
// into the block-exclusive final CSR region (L2-local, full-line writebacks).
__global__ __launch_bounds__(256) void csr_finalize(
    const int2* __restrict__ S1, const int* __restrict__ gbase1,
    int* __restrict__ rp1, int2* __restrict__ Eo1, int Etot1,
    const int2* __restrict__ S2, const int* __restrict__ gbase2,
    int* __restrict__ rp2, int2* __restrict__ Eo2, int Etot2,
    int N, int nbins) {
  __shared__ int cnt[512];
  __shared__ int cur[512];
  const int tid = threadIdx.x;
  const int b = blockIdx.x % nbins;
  const int g = blockIdx.x / nbins;
  const int2* S     = g ? S2 : S1;
  const int* gbase  = g ? gbase2 : gbase1;
  int* rp           = g ? rp2 : rp1;
  int2* Eo          = g ? Eo2 : Eo1;
  const int Etot    = g ? Etot2 : Etot1;

  const int base = gbase[b];
  const int end  = (b + 1 < nbins) ? gbase[b + 1] : Etot;
  const int r0   = b << 9;
  const int nrows = min(512, N - r0);

  for (int l = tid; l < 512; l += 256) cnt[l] = 0;
  __syncthreads();
  for (int j = base + tid; j < end; j += 256)
    atomicAdd(&cnt[S[j].x >> 16], 1);
  __syncthreads();
  if (tid < 64) {
    int carry = 0;
#pragma unroll
    for (int ch = 0; ch < 8; ++ch) {
      int v = cnt[ch * 64 + tid];
      int inc = v;
#pragma unroll
      for (int off = 1; off < 64; off <<= 1) {
        int y = __shfl_up(inc, off);
        if (tid >= off) inc += y;
      }
      inc += carry;
      cnt[ch * 64 + tid] = inc;
      carry = __shfl(inc, 63);
    }
  }
  __syncthreads();
  for (int l = tid; l < 512; l += 256)
    cur[l] = base + ((l > 0) ? cnt[l - 1] : 0);
  for (int l = tid; l < nrows; l += 256)
    rp[r0 + l + 1] = base + cnt[l];
  if (b == 0 && tid == 0) rp[0] = 0;
  __syncthreads();
  for (int j = base + tid; j < end; j += 256) {
    int2 m = S[j];
    int pos = atomicAdd(&cur[m.x >> 16], 1);
    Eo[pos] = make_int2(m.x & 0xffff, m.y);
  }
}

// ---------------------------------------------------------------------------
// Conv1 gather + fused BN. One wave per row (grid-stride).
// bf16 h rows are 128B = 8 lanes x 16B -> 8 edges per VMEM instruction.
// ---------------------------------------------------------------------------
__global__ __launch_bounds__(256) void conv1_gather(
    const ushort* __restrict__ hb,
    const int* __restrict__ rp1, const int2* __restrict__ E1,
    const int* __restrict__ rp2, const int2* __restrict__ E2,
    const float* __restrict__ gamma, const float* __restrict__ beta,
    const float* __restrict__ mean, const float* __restrict__ var,
    float* __restrict__ h1, int N, int nwaves) {
  const int wid  = (blockIdx.x * blockDim.x + threadIdx.x) >> 6;
  const int lane = threadIdx.x & 63;
  const int sub  = lane >> 3;
  const int q    = lane & 7;

  float sc1[8], sh1[8], sc2[8], sh2[8];
#pragma unroll
  for (int t4 = 0; t4 < 2; ++t4) {
    int f1 = q * 8 + t4 * 4;
    float4 gm = *reinterpret_cast<const float4*>(gamma + f1);
    float4 vr = *reinterpret_cast<const float4*>(var + f1);
    float4 mn = *reinterpret_cast<const float4*>(mean + f1);
    float4 bt = *reinterpret_cast<const float4*>(beta + f1);
    float s0 = gm.x * rsqrtf(vr.x + BN_EPS), s1 = gm.y * rsqrtf(vr.y + BN_EPS);
    float s2 = gm.z * rsqrtf(vr.z + BN_EPS), s3 = gm.w * rsqrtf(vr.w + BN_EPS);
    sc1[t4 * 4 + 0] = s0; sh1[t4 * 4 + 0] = bt.x - mn.x * s0;
    sc1[t4 * 4 + 1] = s1; sh1[t4 * 4 + 1] = bt.y - mn.y * s1;
    sc1[t4 * 4 + 2] = s2; sh1[t4 * 4 + 2] = bt.z - mn.z * s2;
    sc1[t4 * 4 + 3] = s3; sh1[t4 * 4 + 3] = bt.w - mn.w * s3;
    int f2 = 64 + f1;
    gm = *reinterpret_cast<const float4*>(gamma + f2);
    vr = *reinterpret_cast<const float4*>(var + f2);
    mn = *reinterpret_cast<const float4*>(mean + f2);
    bt = *reinterpret_cast<const float4*>(beta + f2);
    s0 = gm.x * rsqrtf(vr.x + BN_EPS); s1 = gm.y * rsqrtf(vr.y + BN_EPS);
    s2 = gm.z * rsqrtf(vr.z + BN_EPS); s3 = gm.w * rsqrtf(vr.w + BN_EPS);
    sc2[t4 * 4 + 0] = s0; sh2[t4 * 4 + 0] = bt.x - mn.x * s0;
    sc2[t4 * 4 + 1] = s1; sh2[t4 * 4 + 1] = bt.y - mn.y * s1;
    sc2[t4 * 4 + 2] = s2; sh2[t4 * 4 + 2] = bt.z - mn.z * s2;
    sc2[t4 * 4 + 3] = s3; sh2[t4 * 4 + 3] = bt.w - mn.w * s3;
  }

  for (int r = wid; r < N; r += nwaves) {
    float acc1[8] = {0, 0, 0, 0, 0, 0, 0, 0};
    float acc2[8] = {0, 0, 0, 0, 0, 0, 0, 0};
    {
      int s = rp1[r], e = rp1[r + 1];
      for (int j0 = s; j0 < e; j0 += 8) {
        int jj = j0 + sub;
        int2 m = (jj < e) ? E1[jj] : make_int2(0, 0);
        float v = __int_as_float(m.y);
        uint4 wv = *reinterpret_cast<const uint4*>(hb + (size_t)m.x * 64 + q * 8);
        acc1[0] += v * __uint_as_float(wv.x << 16);
        acc1[1] += v * __uint_as_float(wv.x & 0xffff0000u);
        acc1[2] += v * __uint_as_float(wv.y << 16);
        acc1[3] += v * __uint_as_float(wv.y & 0xffff0000u);
        acc1[4] += v * __uint_as_float(wv.z << 16);
        acc1[5] += v * __uint_as_float(wv.z & 0xffff0000u);
        acc1[6] += v * __uint_as_float(wv.w << 16);
        acc1[7] += v * __uint_as_float(wv.w & 0xffff0000u);
      }
    }
    {
      int s = rp2[r], e = rp2[r + 1];
      for (int j0 = s; j0 < e; j0 += 8) {
        int jj = j0 + sub;
        int2 m = (jj < e) ? E2[jj] : make_int2(0, 0);
        float v = __int_as_float(m.y);
        uint4 wv = *reinterpret_cast<const uint4*>(hb + (size_t)m.x * 64 + q * 8);
        acc2[0] += v * __uint_as_float(wv.x << 16);
        acc2[1] += v * __uint_as_float(wv.x & 0xffff0000u);
        acc2[2] += v * __uint_as_float(wv.y << 16);
        acc2[3] += v * __uint_as_float(wv.y & 0xffff0000u);
        acc2[4] += v * __uint_as_float(wv.z << 16);
        acc2[5] += v * __uint_as_float(wv.z & 0xffff0000u);
        acc2[6] += v * __uint_as_float(wv.w << 16);
        acc2[7] += v * __uint_as_float(wv.w & 0xffff0000u);
      }
    }
#pragma unroll
    for (int mask = 8; mask <= 32; mask <<= 1) {
#pragma unroll
      for (int t = 0; t < 8; ++t) {
        acc1[t] += __shfl_xor(acc1[t], mask);
        acc2[t] += __shfl_xor(acc2[t], mask);
      }
    }
    if (lane < 8) {
      float o1[8], o2[8];
#pragma unroll
      for (int t = 0; t < 8; ++t) {
        o1[t] = acc1[t] * sc1[t] + sh1[t];
        o2[t] = acc2[t] * sc2[t] + sh2[t];
      }
      float* dst = h1 + (size_t)r * 128 + q * 8;
      *reinterpret_cast<float4*>(dst)      = make_float4(o1[0], o1[1], o1[2], o1[3]);
      *reinterpret_cast<float4*>(dst + 4)  = make_float4(o1[4], o1[5], o1[6], o1[7]);
      *reinterpret_cast<float4*>(dst + 64) = make_float4(o2[0], o2[1], o2[2], o2[3]);
      *reinterpret_cast<float4*>(dst + 68) = make_float4(o2[4], o2[5], o2[6], o2[7]);
    }
  }
}

// ---------------------------------------------------------------------------
// g = h1 @ [Wf2a | Wf2b]   [N,128] @ [128,80] -> [N,80]
// ---------------------------------------------------------------------------
__global__ __launch_bounds__(320) void g_kernel(
    const float* __restrict__ h1, const float* __restrict__ Wf,
    float* __restrict__ g, int N) {
  __shared__ __align__(16) float hs[64][65];
  __shared__ __align__(16) float ws[64][80];
  const int tid  = threadIdx.x;
  const int cgrp = tid % 20;
  const int rgrp = tid / 20;
  const int row0 = blockIdx.x * 64;
  float acc[4][4] = {};

  for (int k0 = 0; k0 < 128; k0 += 64) {
    for (int idx = tid; idx < 64 * 64; idx += 320) {
      int r = idx >> 6, kk = idx & 63;
      int gr = row0 + r;
      hs[r][kk] = (gr < N) ? h1[(size_t)gr * 128 + k0 + kk] : 0.f;
    }
    for (int idx = tid; idx < 64 * 80; idx += 320) {
      int kk = idx / 80, j = idx % 80;
      int kr = k0 + kk;
      ws[kk][j] = (j < 40) ? Wf[(size_t)(192 + kr) * 40 + j]
                           : Wf[(size_t)(320 + kr) * 40 + (j - 40)];
    }
    __syncthreads();
#pragma unroll
    for (int kk = 0; kk < 64; ++kk) {
      float4 wv = *reinterpret_cast<const float4*>(&ws[kk][cgrp * 4]);
#pragma unroll
      for (int i = 0; i < 4; ++i) {
        float xv = hs[rgrp * 4 + i][kk];
        acc[i][0] += xv * wv.x; acc[i][1] += xv * wv.y;
        acc[i][2] += xv * wv.z; acc[i][3] += xv * wv.w;
      }
    }
    __syncthreads();
  }
#pragma unroll
  for (int i = 0; i < 4; ++i) {
    int gr = row0 + rgrp * 4 + i;
    if (gr < N) {
      *reinterpret_cast<float4*>(&g[(size_t)gr * 80 + cgrp * 4]) =
          make_float4(acc[i][0], acc[i][1], acc[i][2], acc[i][3]);
    }
  }
}

// ---------------------------------------------------------------------------
// Base final: out = [hb | h1] @ Wf[0:192] + b_final
// ---------------------------------------------------------------------------
__global__ __launch_bounds__(320) void final_base_kernel(
    const ushort* __restrict__ hb, const float* __restrict__ h1,
    const float* __restrict__ Wf, const float* __restrict__ bf,
    float* __restrict__ out, int N) {
  __shared__ __align__(16) float js[64][65];
  __shared__ __align__(16) float wfs[64][40];
  const int tid  = threadIdx.x;
  const int cgrp = tid % 10;
  const int rgrp = tid / 10;
  const int row0 = blockIdx.x * 64;
  float acc[2][4] = {{0.f, 0.f, 0.f, 0.f}, {0.f, 0.f, 0.f, 0.f}};

  for (int ch = 0; ch < 3; ++ch) {
    if (ch == 0) {
      for (int idx = tid; idx < 64 * 16; idx += 320) {
        int r = idx >> 4, q4 = idx & 15;
        int gr = row0 + r;
        ushort4 uv = make_ushort4(0, 0, 0, 0);
        if (gr < N) uv = *reinterpret_cast<const ushort4*>(hb + (size_t)gr * 64 + q4 * 4);
        js[r][q4 * 4 + 0] = bf2f(uv.x);
        js[r][q4 * 4 + 1] = bf2f(uv.y);
        js[r][q4 * 4 + 2] = bf2f(uv.z);
        js[r][q4 * 4 + 3] = bf2f(uv.w);
      }
    } else {
      int kloc = (ch - 1) * 64;
      for (int idx = tid; idx < 64 * 64; idx += 320) {
        int r = idx >> 6, kk = idx & 63;
        int gr = row0 + r;
        js[r][kk] = (gr < N) ? h1[(size_t)gr * 128 + kloc + kk] : 0.f;
      }
    }
    for (int idx = tid; idx < 64 * 40; idx += 320) {
      int kk = idx / 40, c = idx % 40;
      wfs[kk][c] = Wf[(size_t)(ch * 64 + kk) * 40 + c];
    }
    __syncthreads();
#pragma unroll
    for (int kk = 0; kk < 64; ++kk) {
      float x0 = js[rgrp * 2 + 0][kk];
      float x1 = js[rgrp * 2 + 1][kk];
      float4 wv = *reinterpret_cast<const float4*>(&wfs[kk][cgrp * 4]);
      acc[0][0] += x0 * wv.x; acc[0][1] += x0 * wv.y;
      acc[0][2] += x0 * wv.z; acc[0][3] += x0 * wv.w;
      acc[1][0] += x1 * wv.x; acc[1][1] += x1 * wv.y;
      acc[1][2] += x1 * wv.z; acc[1][3] += x1 * wv.w;
    }
    __syncthreads();
  }

  float4 bv = *reinterpret_cast<const float4*>(&bf[cgrp * 4]);
#pragma unroll
  for (int i = 0; i < 2; ++i) {
    int gr = row0 + rgrp * 2 + i;
    if (gr < N) {
      float4 o;
      o.x = acc[i][0] + bv.x;
      o.y = acc[i][1] + bv.y;
      o.z = acc[i][2] + bv.z;
      o.w = acc[i][3] + bv.w;
      *reinterpret_cast<float4*>(&out[(size_t)gr * 40 + cgrp * 4]) = o;
    }
  }
}

// ---------------------------------------------------------------------------
// Final add: out[r,:] += sum_{adj1} v*g[c,0:40] + sum_{adj2} v*g[c,40:80]
// ---------------------------------------------------------------------------
__global__ __launch_bounds__(256) void final_add_kernel(
    const float* __restrict__ g,
    const int* __restrict__ rp1, const int2* __restrict__ E1,
    const int* __restrict__ rp2, const int2* __restrict__ E2,
    float* __restrict__ out, int N, int nwaves) {
  const int wid  = (blockIdx.x * blockDim.x + threadIdx.x) >> 6;
  const int lane = threadIdx.x & 63;
  const int sub  = lane >> 4;
  const int q    = lane & 15;
  const int off1 = (q < 10) ? q * 4 : 0;
  const int off2 = 40 + off1;

  for (int r = wid; r < N; r += nwaves) {
    float a1[4] = {0, 0, 0, 0}, a2[4] = {0, 0, 0, 0};
    {
      int s = rp1[r], e = rp1[r + 1];
      for (int j0 = s; j0 < e; j0 += 4) {
        int jj = j0 + sub;
        int2 m = (jj < e) ? E1[jj] : make_int2(0, 0);
        float v = __int_as_float(m.y);
        float4 gv = *reinterpret_cast<const float4*>(g + (size_t)m.x * 80 + off1);
        a1[0] += v * gv.x; a1[1] += v * gv.y; a1[2] += v * gv.z; a1[3] += v * gv.w;
      }
    }
    {
      int s = rp2[r], e = rp2[r + 1];
      for (int j0 = s; j0 < e; j0 += 4) {
        int jj = j0 + sub;
        int2 m = (jj < e) ? E2[jj] : make_int2(0, 0);
        float v = __int_as_float(m.y);
        float4 gv = *reinterpret_cast<const float4*>(g + (size_t)m.x * 80 + off2);
        a2[0] += v * gv.x; a2[1] += v * gv.y; a2[2] += v * gv.z; a2[3] += v * gv.w;
      }
    }
#pragma unroll
    for (int mask = 16; mask <= 32; mask <<= 1) {
#pragma unroll
      for (int t = 0; t < 4; ++t) {
        a1[t] += __shfl_xor(a1[t], mask);
        a2[t] += __shfl_xor(a2[t], mask);
      }
    }
    if (lane < 10) {
      float* p = out + (size_t)r * 40 + q * 4;
      float4 o = *reinterpret_cast<const float4*>(p);
      o.x += a1[0] + a2[0]; o.y += a1[1] + a2[1];
      o.z += a1[2] + a2[2]; o.w += a1[3] + a2[3];
      *reinterpret_cast<float4*>(p) = o;
    }
  }
}

// ---------------------------------------------------------------------------
extern "C" void kernel_launch(void* const* d_in, const int* in_sizes, int n_in,
                              void* d_out, int out_size, void* d_ws, size_t ws_size,
                              hipStream_t stream) {
  const float* x     = (const float*)d_in[0];
  const int*   a1r   = (const int*)d_in[1];
  const int*   a1c   = (const int*)d_in[2];
  const float* a1v   = (const float*)d_in[3];
  const int*   a2r   = (const int*)d_in[4];
  const int*   a2c   = (const int*)d_in[5];
  const float* a2v   = (const float*)d_in[6];
  const float* We    = (const float*)d_in[7];
  const float* be    = (const float*)d_in[8];
  const float* gamma = (const float*)d_in[9];
  const float* beta  = (const float*)d_in[10];
  const float* mean  = (const float*)d_in[11];
  const float* var   = (const float*)d_in[12];
  const float* Wf    = (const float*)d_in[13];
  const float* bf    = (const float*)d_in[14];
  float* out = (float*)d_out;

  const int N  = in_sizes[0] / 512;
  const int E1 = in_sizes[1];
  const int E2 = in_sizes[4];
  const int nbins = (N + 511) >> 9;   // requires N <= 65536

  char* p = (char*)d_ws;
  auto alloc = [&](size_t bytes) {
    char* q = p; p += (bytes + 255) & ~(size_t)255; return q;
  };
  ushort* hb   = (ushort*)alloc((size_t)N * 64 * 2);
  float*  h1   = (float*) alloc((size_t)N * 128 * 4);
  int*    rp1  = (int*)   alloc(((size_t)N + 1) * 4);
  int*    rp2  = (int*)   alloc(((size_t)N + 1) * 4);
  int2*   E1s  = (int2*)  alloc((size_t)E1 * 8);
  int2*   E2s  = (int2*)  alloc((size_t)E2 * 8);
  int2*   S1   = (int2*)  alloc((size_t)E1 * 8);   // staging; g aliases S1|S2
  int2*   S2   = (int2*)  alloc((size_t)E2 * 8);
  int*    gbin1  = (int*) alloc(MAXBINS * 4);
  int*    gbin2  = (int*) alloc(MAXBINS * 4);      // contiguous after gbin1
  int*    gbase1 = (int*) alloc(MAXBINS * 4);
  int*    gbase2 = (int*) alloc(MAXBINS * 4);
  int*    gcur1  = (int*) alloc(MAXBINS * 4);
  int*    gcur2  = (int*) alloc(MAXBINS * 4);
  float*  g = (float*)S1;   // [N,80] = 16 MB <= 24 MB staging, dead by then

  hipMemsetAsync(gbin1, 0, (size_t)2 * MAXBINS * 4 + 256, stream);

  // embed (independent of CSR build)
  embed_kernel<<<(N + 31) / 32, 256, 0, stream>>>(x, We, be, hb, N);

  // binned CSR build
  bin_hist<<<256, 256, 0, stream>>>(a1r, gbin1, E1, nbins);
  bin_hist<<<256, 256, 0, stream>>>(a2r, gbin2, E2, nbins);
  bin_scan<<<1, 64, 0, stream>>>(gbin1, gbase1, gcur1, gbin2, gbase2, gcur2, nbins);
  bin_scatter<<<256, 256, 0, stream>>>(a1r, a1c, a1v, E1, gcur1, S1, nbins);
  bin_scatter<<<256, 256, 0, stream>>>(a2r, a2c, a2v, E2, gcur2, S2, nbins);
  csr_finalize<<<2 * nbins, 256, 0, stream>>>(
      S1, gbase1, rp1, E1s, E1, S2, gbase2, rp2, E2s, E2, N, nbins);

  // conv1 (gather, 8 edges per VMEM) + fused BN
  const int NW = 2048 * 4;
  conv1_gather<<<2048, 256, 0, stream>>>(
      hb, rp1, E1s, rp2, E2s, gamma, beta, mean, var, h1, N, NW);

  // g = h1 @ [Wf2a|Wf2b]   (g aliases staging, which is dead now)
  g_kernel<<<(N + 63) / 64, 320, 0, stream>>>(h1, Wf, g, N);

  // out = [hb|h1] @ Wf[0:192] + b
  final_base_kernel<<<(N + 63) / 64, 320, 0, stream>>>(hb, h1, Wf, bf, out, N);

  // out += A1@g1 + A2@g2 (4 edges per VMEM)
  final_add_kernel<<<2048, 256, 0, stream>>>(
      g, rp1, E1s, rp2, E2s, out, N, NW);
}

// Round 5
// 412.647 us; speedup vs baseline: 18.7127x; 1.1205x over previous
//
#include <hip/hip_runtime.h>

#define BN_EPS 1e-5f
#define MAXBINS 128   // bins of 512 rows; requires N <= 65536 (col packs in 16 bits)

__device__ __forceinline__ ushort f2bf(float f) {
  uint u = __float_as_uint(f);
  u += 0x7fffu + ((u >> 16) & 1u);
  return (ushort)(u >> 16);
}
__device__ __forceinline__ float bf2f(ushort u) {
  return __uint_as_float((uint)u << 16);
}

// ---------------------------------------------------------------------------
// Embed: hb = bf16( relu(x @ W_embed + b_embed) )   [N,512]@[512,64] -> [N,64]
// ---------------------------------------------------------------------------
__global__ __launch_bounds__(256) void embed_kernel(
    const float* __restrict__ x, const float* __restrict__ W,
    const float* __restrict__ b, ushort* __restrict__ hb, int N) {
  __shared__ __align__(16) float xs[32][68];
  __shared__ __align__(16) float ws[64][64];
  const int tid  = threadIdx.x;
  const int cgrp = tid & 15;   // 16 col-groups of 4
  const int rgrp = tid >> 4;   // 16 row-groups of 2
  const int row0 = blockIdx.x * 32;

  float acc[2][4] = {{0.f, 0.f, 0.f, 0.f}, {0.f, 0.f, 0.f, 0.f}};

  for (int k0 = 0; k0 < 512; k0 += 64) {
    for (int idx = tid; idx < 32 * 16; idx += 256) {
      int r = idx >> 4, k4 = idx & 15;
      int gr = row0 + r;
      float4 xv = make_float4(0.f, 0.f, 0.f, 0.f);
      if (gr < N) xv = *reinterpret_cast<const float4*>(x + (size_t)gr * 512 + k0 + k4 * 4);
      *reinterpret_cast<float4*>(&xs[r][k4 * 4]) = xv;
    }
    for (int idx = tid; idx < 64 * 16; idx += 256) {
      int kk = idx >> 4, c4 = idx & 15;
      *reinterpret_cast<float4*>(&ws[kk][c4 * 4]) =
          *reinterpret_cast<const float4*>(W + (size_t)(k0 + kk) * 64 + c4 * 4);
    }
    __syncthreads();
#pragma unroll
    for (int kk = 0; kk < 64; ++kk) {
      float x0 = xs[rgrp * 2 + 0][kk];
      float x1 = xs[rgrp * 2 + 1][kk];
      float4 wv = *reinterpret_cast<const float4*>(&ws[kk][cgrp * 4]);
      acc[0][0] += x0 * wv.x; acc[0][1] += x0 * wv.y;
      acc[0][2] += x0 * wv.z; acc[0][3] += x0 * wv.w;
      acc[1][0] += x1 * wv.x; acc[1][1] += x1 * wv.y;
      acc[1][2] += x1 * wv.z; acc[1][3] += x1 * wv.w;
    }
    __syncthreads();
  }

  float4 bv = *reinterpret_cast<const float4*>(&b[cgrp * 4]);
#pragma unroll
  for (int i = 0; i < 2; ++i) {
    int gr = row0 + rgrp * 2 + i;
    if (gr < N) {
      ushort4 ob;
      ob.x = f2bf(fmaxf(acc[i][0] + bv.x, 0.f));
      ob.y = f2bf(fmaxf(acc[i][1] + bv.y, 0.f));
      ob.z = f2bf(fmaxf(acc[i][2] + bv.z, 0.f));
      ob.w = f2bf(fmaxf(acc[i][3] + bv.w, 0.f));
      *reinterpret_cast<ushort4*>(&hb[(size_t)gr * 64 + cgrp * 4]) = ob;
    }
  }
}

// ---------------------------------------------------------------------------
// CSR build, two-level binned (bin = row>>9)
// ---------------------------------------------------------------------------
__global__ __launch_bounds__(256) void bin_hist(
    const int* __restrict__ rows, int* __restrict__ gbin, int E, int nbins) {
  __shared__ int lb[MAXBINS];
  const int tid = threadIdx.x;
  if (tid < nbins) lb[tid] = 0;
  __syncthreads();
  const int stride = gridDim.x * blockDim.x;
  for (int i = blockIdx.x * blockDim.x + tid; i < E; i += stride)
    atomicAdd(&lb[rows[i] >> 9], 1);
  __syncthreads();
  if (tid < nbins && lb[tid]) atomicAdd(&gbin[tid], lb[tid]);
}

__device__ __forceinline__ void scan_bins_dev(
    const int* gbin, int* gbase, int* gcur, int nbins, int lane) {
  int carry = 0;
  for (int ch = 0; ch * 64 < nbins; ++ch) {
    int idx = ch * 64 + lane;
    int v = (idx < nbins) ? gbin[idx] : 0;
    int inc = v;
#pragma unroll
    for (int off = 1; off < 64; off <<= 1) {
      int y = __shfl_up(inc, off);
      if (lane >= off) inc += y;
    }
    int ex = carry + inc - v;
    if (idx < nbins) { gbase[idx] = ex; gcur[idx] = ex; }
    carry += __shfl(inc, 63);
  }
}

__global__ __launch_bounds__(64) void bin_scan(
    const int* __restrict__ gbin1, int* __restrict__ gbase1, int* __restrict__ gcur1,
    const int* __restrict__ gbin2, int* __restrict__ gbase2, int* __restrict__ gcur2,
    int nbins) {
  int lane = threadIdx.x;
  scan_bins_dev(gbin1, gbase1, gcur1, nbins, lane);
  scan_bins_dev(gbin2, gbase2, gcur2, nbins, lane);
}

// Staging record: int2( col | (row&511)<<16 , val_bits_f32 ).
__global__ __launch_bounds__(256) void bin_scatter(
    const int* __restrict__ rows, const int* __restrict__ cols,
    const float* __restrict__ vals, int E, int* __restrict__ gcur,
    int2* __restrict__ S, int nbins) {
  __shared__ int lcnt[MAXBINS];
  __shared__ int lcur[MAXBINS];
  const int tid = threadIdx.x;
  for (int e0 = blockIdx.x * 2048; e0 < E; e0 += gridDim.x * 2048) {
    int i0 = e0 + tid * 8;
    int r[8], c[8], vb[8];
    if (i0 + 8 <= E) {
      int4 a = *reinterpret_cast<const int4*>(rows + i0);
      int4 b = *reinterpret_cast<const int4*>(rows + i0 + 4);
      r[0]=a.x; r[1]=a.y; r[2]=a.z; r[3]=a.w; r[4]=b.x; r[5]=b.y; r[6]=b.z; r[7]=b.w;
      a = *reinterpret_cast<const int4*>(cols + i0);
      b = *reinterpret_cast<const int4*>(cols + i0 + 4);
      c[0]=a.x; c[1]=a.y; c[2]=a.z; c[3]=a.w; c[4]=b.x; c[5]=b.y; c[6]=b.z; c[7]=b.w;
      a = *reinterpret_cast<const int4*>(vals + i0);
      b = *reinterpret_cast<const int4*>(vals + i0 + 4);
      vb[0]=a.x; vb[1]=a.y; vb[2]=a.z; vb[3]=a.w; vb[4]=b.x; vb[5]=b.y; vb[6]=b.z; vb[7]=b.w;
    } else {
#pragma unroll
      for (int t = 0; t < 8; ++t) {
        int i = i0 + t;
        bool ok = i < E;
        r[t]  = ok ? rows[i] : -1;
        c[t]  = ok ? cols[i] : 0;
        vb[t] = ok ? __float_as_int(vals[i]) : 0;
      }
    }
    if (tid < nbins) lcnt[tid] = 0;
    __syncthreads();
#pragma unroll
    for (int t = 0; t < 8; ++t)
      if (r[t] >= 0) atomicAdd(&lcnt[r[t] >> 9], 1);
    __syncthreads();
    if (tid < nbins) {
      int n = lcnt[tid];
      lcur[tid] = n ? atomicAdd(&gcur[tid], n) : 0;
    }
    __syncthreads();
#pragma unroll
    for (int t = 0; t < 8; ++t) {
      if (r[t] >= 0) {
        int pos = atomicAdd(&lcur[r[t] >> 9], 1);
        S[pos] = make_int2(c[t] | ((r[t] & 511) << 16), vb[t]);
      }
    }
    __syncthreads();
  }
}

// One block per (graph, bin). Final edge record: uint( col | bf16(val)<<16 ).
__global__ __launch_bounds__(256) void csr_finalize(
    const int2* __restrict__ S1, const int* __restrict__ gbase1,
    int* __restrict__ rp1, uint* __restrict__ Eo1, int Etot1,
    const int2* __restrict__ S2, const int* __restrict__ gbase2,
    int* __restrict__ rp2, uint* __restrict__ Eo2, int Etot2,
    int N, int nbins) {
  __shared__ int cnt[512];
  __shared__ int cur[512];
  const int tid = threadIdx.x;
  const int b = blockIdx.x % nbins;
  const int g = blockIdx.x / nbins;
  const int2* S     = g ? S2 : S1;
  const int* gbase  = g ? gbase2 : gbase1;
  int* rp           = g ? rp2 : rp1;
  uint* Eo          = g ? Eo2 : Eo1;
  const int Etot    = g ? Etot2 : Etot1;

  const int base = gbase[b];
  const int end  = (b + 1 < nbins) ? gbase[b + 1] : Etot;
  const int r0   = b << 9;
  const int nrows = min(512, N - r0);

  for (int l = tid; l < 512; l += 256) cnt[l] = 0;
  __syncthreads();
  for (int j = base + tid; j < end; j += 256)
    atomicAdd(&cnt[S[j].x >> 16], 1);
  __syncthreads();
  if (tid < 64) {
    int carry = 0;
#pragma unroll
    for (int ch = 0; ch < 8; ++ch) {
      int v = cnt[ch * 64 + tid];
      int inc = v;
#pragma unroll
      for (int off = 1; off < 64; off <<= 1) {
        int y = __shfl_up(inc, off);
        if (tid >= off) inc += y;
      }
      inc += carry;
      cnt[ch * 64 + tid] = inc;
      carry = __shfl(inc, 63);
    }
  }
  __syncthreads();
  for (int l = tid; l < 512; l += 256)
    cur[l] = base + ((l > 0) ? cnt[l - 1] : 0);
  for (int l = tid; l < nrows; l += 256)
    rp[r0 + l + 1] = base + cnt[l];
  if (b == 0 && tid == 0) rp[0] = 0;
  __syncthreads();
  for (int j = base + tid; j < end; j += 256) {
    int2 m = S[j];
    int pos = atomicAdd(&cur[m.x >> 16], 1);
    Eo[pos] = (uint)(m.x & 0xffff) | ((uint)f2bf(__int_as_float(m.y)) << 16);
  }
}

// ---------------------------------------------------------------------------
// Conv1 gather + fused BN. One wave per row (grid-stride).
// bf16 h rows are 128B = 8 lanes x 16B -> 8 edges per VMEM instruction.
// Edge record: col = m & 0xffff, val = bf16(m >> 16).
// ---------------------------------------------------------------------------
__global__ __launch_bounds__(256) void conv1_gather(
    const ushort* __restrict__ hb,
    const int* __restrict__ rp1, const uint* __restrict__ E1,
    const int* __restrict__ rp2, const uint* __restrict__ E2,
    const float* __restrict__ gamma, const float* __restrict__ beta,
    const float* __restrict__ mean, const float* __restrict__ var,
    float* __restrict__ h1, int N, int nwaves) {
  const int wid  = (blockIdx.x * blockDim.x + threadIdx.x) >> 6;
  const int lane = threadIdx.x & 63;
  const int sub  = lane >> 3;
  const int q    = lane & 7;

  float sc1[8], sh1[8], sc2[8], sh2[8];
#pragma unroll
  for (int t4 = 0; t4 < 2; ++t4) {
    int f1 = q * 8 + t4 * 4;
    float4 gm = *reinterpret_cast<const float4*>(gamma + f1);
    float4 vr = *reinterpret_cast<const float4*>(var + f1);
    float4 mn = *reinterpret_cast<const float4*>(mean + f1);
    float4 bt = *reinterpret_cast<const float4*>(beta + f1);
    float s0 = gm.x * rsqrtf(vr.x + BN_EPS), s1 = gm.y * rsqrtf(vr.y + BN_EPS);
    float s2 = gm.z * rsqrtf(vr.z + BN_EPS), s3 = gm.w * rsqrtf(vr.w + BN_EPS);
    sc1[t4 * 4 + 0] = s0; sh1[t4 * 4 + 0] = bt.x - mn.x * s0;
    sc1[t4 * 4 + 1] = s1; sh1[t4 * 4 + 1] = bt.y - mn.y * s1;
    sc1[t4 * 4 + 2] = s2; sh1[t4 * 4 + 2] = bt.z - mn.z * s2;
    sc1[t4 * 4 + 3] = s3; sh1[t4 * 4 + 3] = bt.w - mn.w * s3;
    int f2 = 64 + f1;
    gm = *reinterpret_cast<const float4*>(gamma + f2);
    vr = *reinterpret_cast<const float4*>(var + f2);
    mn = *reinterpret_cast<const float4*>(mean + f2);
    bt = *reinterpret_cast<const float4*>(beta + f2);
    s0 = gm.x * rsqrtf(vr.x + BN_EPS); s1 = gm.y * rsqrtf(vr.y + BN_EPS);
    s2 = gm.z * rsqrtf(vr.z + BN_EPS); s3 = gm.w * rsqrtf(vr.w + BN_EPS);
    sc2[t4 * 4 + 0] = s0; sh2[t4 * 4 + 0] = bt.x - mn.x * s0;
    sc2[t4 * 4 + 1] = s1; sh2[t4 * 4 + 1] = bt.y - mn.y * s1;
    sc2[t4 * 4 + 2] = s2; sh2[t4 * 4 + 2] = bt.z - mn.z * s2;
    sc2[t4 * 4 + 3] = s3; sh2[t4 * 4 + 3] = bt.w - mn.w * s3;
  }

  for (int r = wid; r < N; r += nwaves) {
    float acc1[8] = {0, 0, 0, 0, 0, 0, 0, 0};
    float acc2[8] = {0, 0, 0, 0, 0, 0, 0, 0};
    {
      int s = rp1[r], e = rp1[r + 1];
      for (int j0 = s; j0 < e; j0 += 8) {
        int jj = j0 + sub;
        uint m = (jj < e) ? E1[jj] : 0u;
        float v = bf2f((ushort)(m >> 16));
        uint4 wv = *reinterpret_cast<const uint4*>(hb + (size_t)(m & 0xffffu) * 64 + q * 8);
        acc1[0] += v * __uint_as_float(wv.x << 16);
        acc1[1] += v * __uint_as_float(wv.x & 0xffff0000u);
        acc1[2] += v * __uint_as_float(wv.y << 16);
        acc1[3] += v * __uint_as_float(wv.y & 0xffff0000u);
        acc1[4] += v * __uint_as_float(wv.z << 16);
        acc1[5] += v * __uint_as_float(wv.z & 0xffff0000u);
        acc1[6] += v * __uint_as_float(wv.w << 16);
        acc1[7] += v * __uint_as_float(wv.w & 0xffff0000u);
      }
    }
    {
      int s = rp2[r], e = rp2[r + 1];
      for (int j0 = s; j0 < e; j0 += 8) {
        int jj = j0 + sub;
        uint m = (jj < e) ? E2[jj] : 0u;
        float v = bf2f((ushort)(m >> 16));
        uint4 wv = *reinterpret_cast<const uint4*>(hb + (size_t)(m & 0xffffu) * 64 + q * 8);
        acc2[0] += v * __uint_as_float(wv.x << 16);
        acc2[1] += v * __uint_as_float(wv.x & 0xffff0000u);
        acc2[2] += v * __uint_as_float(wv.y << 16);
        acc2[3] += v * __uint_as_float(wv.y & 0xffff0000u);
        acc2[4] += v * __uint_as_float(wv.z << 16);
        acc2[5] += v * __uint_as_float(wv.z & 0xffff0000u);
        acc2[6] += v * __uint_as_float(wv.w << 16);
        acc2[7] += v * __uint_as_float(wv.w & 0xffff0000u);
      }
    }
#pragma unroll
    for (int mask = 8; mask <= 32; mask <<= 1) {
#pragma unroll
      for (int t = 0; t < 8; ++t) {
        acc1[t] += __shfl_xor(acc1[t], mask);
        acc2[t] += __shfl_xor(acc2[t], mask);
      }
    }
    if (lane < 8) {
      float o1[8], o2[8];
#pragma unroll
      for (int t = 0; t < 8; ++t) {
        o1[t] = acc1[t] * sc1[t] + sh1[t];
        o2[t] = acc2[t] * sc2[t] + sh2[t];
      }
      float* dst = h1 + (size_t)r * 128 + q * 8;
      *reinterpret_cast<float4*>(dst)      = make_float4(o1[0], o1[1], o1[2], o1[3]);
      *reinterpret_cast<float4*>(dst + 4)  = make_float4(o1[4], o1[5], o1[6], o1[7]);
      *reinterpret_cast<float4*>(dst + 64) = make_float4(o2[0], o2[1], o2[2], o2[3]);
      *reinterpret_cast<float4*>(dst + 68) = make_float4(o2[4], o2[5], o2[6], o2[7]);
    }
  }
}

// ---------------------------------------------------------------------------
// Fused dense tail:
//   out = [hb | h1] @ Wf[0:192] + b_final          (f32, written once)
//   g1b = bf16( h1 @ Wf[192:320] )  g2b = bf16( h1 @ Wf[320:448] )
// One pass over hb + h1. 64 rows/block, 320 threads: rgrp=tid/20 (4 rows),
// cgrp=tid%20 (2 out-cols + 4 g-cols each).
// ---------------------------------------------------------------------------
__global__ __launch_bounds__(320) void dense_tail_kernel(
    const ushort* __restrict__ hb, const float* __restrict__ h1,
    const float* __restrict__ Wf, const float* __restrict__ bfin,
    float* __restrict__ out, ushort* __restrict__ g1b, ushort* __restrict__ g2b,
    int N) {
  __shared__ __align__(16) float js[64][68];
  __shared__ __align__(16) float wg[64][80];
  __shared__ __align__(16) float wo[64][40];
  const int tid  = threadIdx.x;
  const int cgrp = tid % 20;
  const int rgrp = tid / 20;   // 0..15
  const int row0 = blockIdx.x * 64;
  float accg[4][4] = {};
  float acco[4][2] = {};

  for (int ch = 0; ch < 3; ++ch) {
    if (ch == 0) {
      for (int idx = tid; idx < 64 * 16; idx += 320) {
        int r = idx >> 4, q4 = idx & 15;
        int gr = row0 + r;
        ushort4 uv = make_ushort4(0, 0, 0, 0);
        if (gr < N) uv = *reinterpret_cast<const ushort4*>(hb + (size_t)gr * 64 + q4 * 4);
        *reinterpret_cast<float4*>(&js[r][q4 * 4]) =
            make_float4(bf2f(uv.x), bf2f(uv.y), bf2f(uv.z), bf2f(uv.w));
      }
    } else {
      int kloc = (ch - 1) * 64;
      for (int idx = tid; idx < 64 * 16; idx += 320) {
        int r = idx >> 4, k4 = idx & 15;
        int gr = row0 + r;
        float4 hv = make_float4(0.f, 0.f, 0.f, 0.f);
        if (gr < N) hv = *reinterpret_cast<const float4*>(h1 + (size_t)gr * 128 + kloc + k4 * 4);
        *reinterpret_cast<float4*>(&js[r][k4 * 4]) = hv;
      }
    }
    // out-weights rows ch*64 .. ch*64+63
    for (int idx = tid; idx < 64 * 10; idx += 320) {
      int kk = idx / 10, c4 = idx % 10;
      *reinterpret_cast<float4*>(&wo[kk][c4 * 4]) =
          *reinterpret_cast<const float4*>(Wf + (size_t)(ch * 64 + kk) * 40 + c4 * 4);
    }
    // g-weights rows (ch-1)*64 .. of Wf[192:320] | Wf[320:448]
    if (ch >= 1) {
      int kr0 = (ch - 1) * 64;
      for (int idx = tid; idx < 64 * 20; idx += 320) {
        int kk = idx / 20, c4 = idx % 20;
        const float* srcw = (c4 < 10)
            ? Wf + (size_t)(192 + kr0 + kk) * 40 + c4 * 4
            : Wf + (size_t)(320 + kr0 + kk) * 40 + (c4 - 10) * 4;
        *reinterpret_cast<float4*>(&wg[kk][c4 * 4]) =
            *reinterpret_cast<const float4*>(srcw);
      }
    }
    __syncthreads();
    if (ch == 0) {
#pragma unroll
      for (int kk = 0; kk < 64; ++kk) {
        float2 wov = *reinterpret_cast<const float2*>(&wo[kk][cgrp * 2]);
#pragma unroll
        for (int i = 0; i < 4; ++i) {
          float xv = js[rgrp * 4 + i][kk];
          acco[i][0] += xv * wov.x; acco[i][1] += xv * wov.y;
        }
      }
    } else {
#pragma unroll
      for (int kk = 0; kk < 64; ++kk) {
        float2 wov = *reinterpret_cast<const float2*>(&wo[kk][cgrp * 2]);
        float4 wgv = *reinterpret_cast<const float4*>(&wg[kk][cgrp * 4]);
#pragma unroll
        for (int i = 0; i < 4; ++i) {
          float xv = js[rgrp * 4 + i][kk];
          acco[i][0] += xv * wov.x; acco[i][1] += xv * wov.y;
          accg[i][0] += xv * wgv.x; accg[i][1] += xv * wgv.y;
          accg[i][2] += xv * wgv.z; accg[i][3] += xv * wgv.w;
        }
      }
    }
    __syncthreads();
  }

  float b0 = bfin[cgrp * 2], b1 = bfin[cgrp * 2 + 1];
#pragma unroll
  for (int i = 0; i < 4; ++i) {
    int gr = row0 + rgrp * 4 + i;
    if (gr < N) {
      *reinterpret_cast<float2*>(&out[(size_t)gr * 40 + cgrp * 2]) =
          make_float2(acco[i][0] + b0, acco[i][1] + b1);
      ushort4 ob;
      ob.x = f2bf(accg[i][0]); ob.y = f2bf(accg[i][1]);
      ob.z = f2bf(accg[i][2]); ob.w = f2bf(accg[i][3]);
      if (cgrp < 10)
        *reinterpret_cast<ushort4*>(&g1b[(size_t)gr * 40 + cgrp * 4]) = ob;
      else
        *reinterpret_cast<ushort4*>(&g2b[(size_t)gr * 40 + (cgrp - 10) * 4]) = ob;
    }
  }
}

// ---------------------------------------------------------------------------
// Final add: out[r,:] += sum_{adj1} v*g1b[c,:] + sum_{adj2} v*g2b[c,:]
// bf16 g rows are 80B; 8-lane subgroups (8 edges/VMEM), lanes q<5 carry data.
// ---------------------------------------------------------------------------
__global__ __launch_bounds__(256) void final_add_kernel(
    const ushort* __restrict__ g1b, const ushort* __restrict__ g2b,
    const int* __restrict__ rp1, const uint* __restrict__ E1,
    const int* __restrict__ rp2, const uint* __restrict__ E2,
    float* __restrict__ out, int N, int nwaves) {
  const int wid  = (blockIdx.x * blockDim.x + threadIdx.x) >> 6;
  const int lane = threadIdx.x & 63;
  const int sub  = lane >> 3;              // 8 edge slots
  const int q    = lane & 7;
  const int off  = (q < 5) ? q * 8 : 0;    // ushort offset within 40-wide row

  for (int r = wid; r < N; r += nwaves) {
    float a1[8] = {0, 0, 0, 0, 0, 0, 0, 0};
    float a2[8] = {0, 0, 0, 0, 0, 0, 0, 0};
    {
      int s = rp1[r], e = rp1[r + 1];
      for (int j0 = s; j0 < e; j0 += 8) {
        int jj = j0 + sub;
        uint m = (jj < e) ? E1[jj] : 0u;
        float v = bf2f((ushort)(m >> 16));
        uint4 gv = *reinterpret_cast<const uint4*>(g1b + (size_t)(m & 0xffffu) * 40 + off);
        a1[0] += v * __uint_as_float(gv.x << 16);
        a1[1] += v * __uint_as_float(gv.x & 0xffff0000u);
        a1[2] += v * __uint_as_float(gv.y << 16);
        a1[3] += v * __uint_as_float(gv.y & 0xffff0000u);
        a1[4] += v * __uint_as_float(gv.z << 16);
        a1[5] += v * __uint_as_float(gv.z & 0xffff0000u);
        a1[6] += v * __uint_as_float(gv.w << 16);
        a1[7] += v * __uint_as_float(gv.w & 0xffff0000u);
      }
    }
    {
      int s = rp2[r], e = rp2[r + 1];
      for (int j0 = s; j0 < e; j0 += 8) {
        int jj = j0 + sub;
        uint m = (jj < e) ? E2[jj] : 0u;
        float v = bf2f((ushort)(m >> 16));
        uint4 gv = *reinterpret_cast<const uint4*>(g2b + (size_t)(m & 0xffffu) * 40 + off);
        a2[0] += v * __uint_as_float(gv.x << 16);
        a2[1] += v * __uint_as_float(gv.x & 0xffff0000u);
        a2[2] += v * __uint_as_float(gv.y << 16);
        a2[3] += v * __uint_as_float(gv.y & 0xffff0000u);
        a2[4] += v * __uint_as_float(gv.z << 16);
        a2[5] += v * __uint_as_float(gv.z & 0xffff0000u);
        a2[6] += v * __uint_as_float(gv.w << 16);
        a2[7] += v * __uint_as_float(gv.w & 0xffff0000u);
      }
    }
#pragma unroll
    for (int mask = 8; mask <= 32; mask <<= 1) {
#pragma unroll
      for (int t = 0; t < 8; ++t) {
        a1[t] += __shfl_xor(a1[t], mask);
        a2[t] += __shfl_xor(a2[t], mask);
      }
    }
    if (lane < 5) {   // sub==0, q==lane: owns features lane*8 .. lane*8+7
      float* p = out + (size_t)r * 40 + lane * 8;
      float4 o0 = *reinterpret_cast<const float4*>(p);
      float4 o1 = *reinterpret_cast<const float4*>(p + 4);
      o0.x += a1[0] + a2[0]; o0.y += a1[1] + a2[1];
      o0.z += a1[2] + a2[2]; o0.w += a1[3] + a2[3];
      o1.x += a1[4] + a2[4]; o1.y += a1[5] + a2[5];
      o1.z += a1[6] + a2[6]; o1.w += a1[7] + a2[7];
      *reinterpret_cast<float4*>(p)     = o0;
      *reinterpret_cast<float4*>(p + 4) = o1;
    }
  }
}

// ---------------------------------------------------------------------------
extern "C" void kernel_launch(void* const* d_in, const int* in_sizes, int n_in,
                              void* d_out, int out_size, void* d_ws, size_t ws_size,
                              hipStream_t stream) {
  const float* x     = (const float*)d_in[0];
  const int*   a1r   = (const int*)d_in[1];
  const int*   a1c   = (const int*)d_in[2];
  const float* a1v   = (const float*)d_in[3];
  const int*   a2r   = (const int*)d_in[4];
  const int*   a2c   = (const int*)d_in[5];
  const float* a2v   = (const float*)d_in[6];
  const float* We    = (const float*)d_in[7];
  const float* be    = (const float*)d_in[8];
  const float* gamma = (const float*)d_in[9];
  const float* beta  = (const float*)d_in[10];
  const float* mean  = (const float*)d_in[11];
  const float* var   = (const float*)d_in[12];
  const float* Wf    = (const float*)d_in[13];
  const float* bf    = (const float*)d_in[14];
  float* out = (float*)d_out;

  const int N  = in_sizes[0] / 512;
  const int E1 = in_sizes[1];
  const int E2 = in_sizes[4];
  const int nbins = (N + 511) >> 9;   // requires N <= 65536

  char* p = (char*)d_ws;
  auto alloc = [&](size_t bytes) {
    char* q = p; p += (bytes + 255) & ~(size_t)255; return q;
  };
  ushort* hb   = (ushort*)alloc((size_t)N * 64 * 2);
  float*  h1   = (float*) alloc((size_t)N * 128 * 4);
  ushort* g1b  = (ushort*)alloc((size_t)N * 40 * 2);
  ushort* g2b  = (ushort*)alloc((size_t)N * 40 * 2);
  int*    rp1  = (int*)   alloc(((size_t)N + 1) * 4);
  int*    rp2  = (int*)   alloc(((size_t)N + 1) * 4);
  uint*   E1s  = (uint*)  alloc((size_t)E1 * 4);
  uint*   E2s  = (uint*)  alloc((size_t)E2 * 4);
  int2*   S1   = (int2*)  alloc((size_t)E1 * 8);
  int2*   S2   = (int2*)  alloc((size_t)E2 * 8);
  int*    gbin1  = (int*) alloc(MAXBINS * 4);
  int*    gbin2  = (int*) alloc(MAXBINS * 4);
  int*    gbase1 = (int*) alloc(MAXBINS * 4);
  int*    gbase2 = (int*) alloc(MAXBINS * 4);
  int*    gcur1  = (int*) alloc(MAXBINS * 4);
  int*    gcur2  = (int*) alloc(MAXBINS * 4);

  hipMemsetAsync(gbin1, 0, (size_t)2 * MAXBINS * 4 + 256, stream);

  // embed (independent of CSR build)
  embed_kernel<<<(N + 31) / 32, 256, 0, stream>>>(x, We, be, hb, N);

  // binned CSR build
  bin_hist<<<256, 256, 0, stream>>>(a1r, gbin1, E1, nbins);
  bin_hist<<<256, 256, 0, stream>>>(a2r, gbin2, E2, nbins);
  bin_scan<<<1, 64, 0, stream>>>(gbin1, gbase1, gcur1, gbin2, gbase2, gcur2, nbins);
  bin_scatter<<<256, 256, 0, stream>>>(a1r, a1c, a1v, E1, gcur1, S1, nbins);
  bin_scatter<<<256, 256, 0, stream>>>(a2r, a2c, a2v, E2, gcur2, S2, nbins);
  csr_finalize<<<2 * nbins, 256, 0, stream>>>(
      S1, gbase1, rp1, E1s, E1, S2, gbase2, rp2, E2s, E2, N, nbins);

  // conv1 (gather, 8 edges per VMEM) + fused BN
  const int NW = 2048 * 4;
  conv1_gather<<<2048, 256, 0, stream>>>(
      hb, rp1, E1s, rp2, E2s, gamma, beta, mean, var, h1, N, NW);

  // fused dense tail: out = [hb|h1]@Wf[0:192]+b ; g1b/g2b = bf16(h1@Wf[192:448])
  dense_tail_kernel<<<(N + 63) / 64, 320, 0, stream>>>(
      hb, h1, Wf, bf, out, g1b, g2b, N);

  // out += A1@g1 + A2@g2 (8 edges per VMEM, bf16 gather)
  final_add_kernel<<<2048, 256, 0, stream>>>(
      g1b, g2b, rp1, E1s, rp2, E2s, out, N, NW);
}

// Round 6
// 386.978 us; speedup vs baseline: 19.9539x; 1.0663x over previous
//
#include <hip/hip_runtime.h>

#define BN_EPS 1e-5f
#define MAXBINS 128   // bins of 512 rows; requires N <= 65536 (col packs in 16 bits)

typedef __attribute__((ext_vector_type(8))) short bf16x8;
typedef __attribute__((ext_vector_type(4))) float f32x4;

__device__ __forceinline__ ushort f2bf(float f) {
  uint u = __float_as_uint(f);
  u += 0x7fffu + ((u >> 16) & 1u);
  return (ushort)(u >> 16);
}
__device__ __forceinline__ float bf2f(ushort u) {
  return __uint_as_float((uint)u << 16);
}
__device__ __forceinline__ uint pack2bf(float a, float b) {
  return (uint)f2bf(a) | ((uint)f2bf(b) << 16);
}

// ---------------------------------------------------------------------------
// Embed: hb = bf16( relu(x @ W_embed + b_embed) )   [N,512]@[512,64] -> [N,64]
// ---------------------------------------------------------------------------
__global__ __launch_bounds__(256) void embed_kernel(
    const float* __restrict__ x, const float* __restrict__ W,
    const float* __restrict__ b, ushort* __restrict__ hb, int N) {
  __shared__ __align__(16) float xs[32][68];
  __shared__ __align__(16) float ws[64][64];
  const int tid  = threadIdx.x;
  const int cgrp = tid & 15;   // 16 col-groups of 4
  const int rgrp = tid >> 4;   // 16 row-groups of 2
  const int row0 = blockIdx.x * 32;

  float acc[2][4] = {{0.f, 0.f, 0.f, 0.f}, {0.f, 0.f, 0.f, 0.f}};

  for (int k0 = 0; k0 < 512; k0 += 64) {
    for (int idx = tid; idx < 32 * 16; idx += 256) {
      int r = idx >> 4, k4 = idx & 15;
      int gr = row0 + r;
      float4 xv = make_float4(0.f, 0.f, 0.f, 0.f);
      if (gr < N) xv = *reinterpret_cast<const float4*>(x + (size_t)gr * 512 + k0 + k4 * 4);
      *reinterpret_cast<float4*>(&xs[r][k4 * 4]) = xv;
    }
    for (int idx = tid; idx < 64 * 16; idx += 256) {
      int kk = idx >> 4, c4 = idx & 15;
      *reinterpret_cast<float4*>(&ws[kk][c4 * 4]) =
          *reinterpret_cast<const float4*>(W + (size_t)(k0 + kk) * 64 + c4 * 4);
    }
    __syncthreads();
#pragma unroll
    for (int kk = 0; kk < 64; ++kk) {
      float x0 = xs[rgrp * 2 + 0][kk];
      float x1 = xs[rgrp * 2 + 1][kk];
      float4 wv = *reinterpret_cast<const float4*>(&ws[kk][cgrp * 4]);
      acc[0][0] += x0 * wv.x; acc[0][1] += x0 * wv.y;
      acc[0][2] += x0 * wv.z; acc[0][3] += x0 * wv.w;
      acc[1][0] += x1 * wv.x; acc[1][1] += x1 * wv.y;
      acc[1][2] += x1 * wv.z; acc[1][3] += x1 * wv.w;
    }
    __syncthreads();
  }

  float4 bv = *reinterpret_cast<const float4*>(&b[cgrp * 4]);
#pragma unroll
  for (int i = 0; i < 2; ++i) {
    int gr = row0 + rgrp * 2 + i;
    if (gr < N) {
      ushort4 ob;
      ob.x = f2bf(fmaxf(acc[i][0] + bv.x, 0.f));
      ob.y = f2bf(fmaxf(acc[i][1] + bv.y, 0.f));
      ob.z = f2bf(fmaxf(acc[i][2] + bv.z, 0.f));
      ob.w = f2bf(fmaxf(acc[i][3] + bv.w, 0.f));
      *reinterpret_cast<ushort4*>(&hb[(size_t)gr * 64 + cgrp * 4]) = ob;
    }
  }
}

// ---------------------------------------------------------------------------
// CSR build, two-level binned (bin = row>>9)
// ---------------------------------------------------------------------------
__global__ __launch_bounds__(256) void bin_hist(
    const int* __restrict__ rows, int* __restrict__ gbin, int E, int nbins) {
  __shared__ int lb[MAXBINS];
  const int tid = threadIdx.x;
  if (tid < nbins) lb[tid] = 0;
  __syncthreads();
  const int stride = gridDim.x * blockDim.x;
  for (int i = blockIdx.x * blockDim.x + tid; i < E; i += stride)
    atomicAdd(&lb[rows[i] >> 9], 1);
  __syncthreads();
  if (tid < nbins && lb[tid]) atomicAdd(&gbin[tid], lb[tid]);
}

__device__ __forceinline__ void scan_bins_dev(
    const int* gbin, int* gbase, int* gcur, int nbins, int lane) {
  int carry = 0;
  for (int ch = 0; ch * 64 < nbins; ++ch) {
    int idx = ch * 64 + lane;
    int v = (idx < nbins) ? gbin[idx] : 0;
    int inc = v;
#pragma unroll
    for (int off = 1; off < 64; off <<= 1) {
      int y = __shfl_up(inc, off);
      if (lane >= off) inc += y;
    }
    int ex = carry + inc - v;
    if (idx < nbins) { gbase[idx] = ex; gcur[idx] = ex; }
    carry += __shfl(inc, 63);
  }
}

__global__ __launch_bounds__(64) void bin_scan(
    const int* __restrict__ gbin1, int* __restrict__ gbase1, int* __restrict__ gcur1,
    const int* __restrict__ gbin2, int* __restrict__ gbase2, int* __restrict__ gcur2,
    int nbins) {
  int lane = threadIdx.x;
  scan_bins_dev(gbin1, gbase1, gcur1, nbins, lane);
  scan_bins_dev(gbin2, gbase2, gcur2, nbins, lane);
}

// Staging record: int2( col | (row&511)<<16 , val_bits_f32 ).
__global__ __launch_bounds__(256) void bin_scatter(
    const int* __restrict__ rows, const int* __restrict__ cols,
    const float* __restrict__ vals, int E, int* __restrict__ gcur,
    int2* __restrict__ S, int nbins) {
  __shared__ int lcnt[MAXBINS];
  __shared__ int lcur[MAXBINS];
  const int tid = threadIdx.x;
  for (int e0 = blockIdx.x * 2048; e0 < E; e0 += gridDim.x * 2048) {
    int i0 = e0 + tid * 8;
    int r[8], c[8], vb[8];
    if (i0 + 8 <= E) {
      int4 a = *reinterpret_cast<const int4*>(rows + i0);
      int4 b = *reinterpret_cast<const int4*>(rows + i0 + 4);
      r[0]=a.x; r[1]=a.y; r[2]=a.z; r[3]=a.w; r[4]=b.x; r[5]=b.y; r[6]=b.z; r[7]=b.w;
      a = *reinterpret_cast<const int4*>(cols + i0);
      b = *reinterpret_cast<const int4*>(cols + i0 + 4);
      c[0]=a.x; c[1]=a.y; c[2]=a.z; c[3]=a.w; c[4]=b.x; c[5]=b.y; c[6]=b.z; c[7]=b.w;
      a = *reinterpret_cast<const int4*>(vals + i0);
      b = *reinterpret_cast<const int4*>(vals + i0 + 4);
      vb[0]=a.x; vb[1]=a.y; vb[2]=a.z; vb[3]=a.w; vb[4]=b.x; vb[5]=b.y; vb[6]=b.z; vb[7]=b.w;
    } else {
#pragma unroll
      for (int t = 0; t < 8; ++t) {
        int i = i0 + t;
        bool ok = i < E;
        r[t]  = ok ? rows[i] : -1;
        c[t]  = ok ? cols[i] : 0;
        vb[t] = ok ? __float_as_int(vals[i]) : 0;
      }
    }
    if (tid < nbins) lcnt[tid] = 0;
    __syncthreads();
#pragma unroll
    for (int t = 0; t < 8; ++t)
      if (r[t] >= 0) atomicAdd(&lcnt[r[t] >> 9], 1);
    __syncthreads();
    if (tid < nbins) {
      int n = lcnt[tid];
      lcur[tid] = n ? atomicAdd(&gcur[tid], n) : 0;
    }
    __syncthreads();
#pragma unroll
    for (int t = 0; t < 8; ++t) {
      if (r[t] >= 0) {
        int pos = atomicAdd(&lcur[r[t] >> 9], 1);
        S[pos] = make_int2(c[t] | ((r[t] & 511) << 16), vb[t]);
      }
    }
    __syncthreads();
  }
}

// One block per (graph, bin). Final edge record: uint( col | bf16(val)<<16 ).
__global__ __launch_bounds__(256) void csr_finalize(
    const int2* __restrict__ S1, const int* __restrict__ gbase1,
    int* __restrict__ rp1, uint* __restrict__ Eo1, int Etot1,
    const int2* __restrict__ S2, const int* __restrict__ gbase2,
    int* __restrict__ rp2, uint* __restrict__ Eo2, int Etot2,
    int N, int nbins) {
  __shared__ int cnt[512];
  __shared__ int cur[512];
  const int tid = threadIdx.x;
  const int b = blockIdx.x % nbins;
  const int g = blockIdx.x / nbins;
  const int2* S     = g ? S2 : S1;
  const int* gbase  = g ? gbase2 : gbase1;
  int* rp           = g ? rp2 : rp1;
  uint* Eo          = g ? Eo2 : Eo1;
  const int Etot    = g ? Etot2 : Etot1;

  const int base = gbase[b];
  const int end  = (b + 1 < nbins) ? gbase[b + 1] : Etot;
  const int r0   = b << 9;
  const int nrows = min(512, N - r0);

  for (int l = tid; l < 512; l += 256) cnt[l] = 0;
  __syncthreads();
  for (int j = base + tid; j < end; j += 256)
    atomicAdd(&cnt[S[j].x >> 16], 1);
  __syncthreads();
  if (tid < 64) {
    int carry = 0;
#pragma unroll
    for (int ch = 0; ch < 8; ++ch) {
      int v = cnt[ch * 64 + tid];
      int inc = v;
#pragma unroll
      for (int off = 1; off < 64; off <<= 1) {
        int y = __shfl_up(inc, off);
        if (tid >= off) inc += y;
      }
      inc += carry;
      cnt[ch * 64 + tid] = inc;
      carry = __shfl(inc, 63);
    }
  }
  __syncthreads();
  for (int l = tid; l < 512; l += 256)
    cur[l] = base + ((l > 0) ? cnt[l - 1] : 0);
  for (int l = tid; l < nrows; l += 256)
    rp[r0 + l + 1] = base + cnt[l];
  if (b == 0 && tid == 0) rp[0] = 0;
  __syncthreads();
  for (int j = base + tid; j < end; j += 256) {
    int2 m = S[j];
    int pos = atomicAdd(&cur[m.x >> 16], 1);
    Eo[pos] = (uint)(m.x & 0xffff) | ((uint)f2bf(__int_as_float(m.y)) << 16);
  }
}

// ---------------------------------------------------------------------------
// Conv1 gather + fused BN. One wave per row (grid-stride).
// Writes h1b as bf16 [N][128].
// ---------------------------------------------------------------------------
__global__ __launch_bounds__(256) void conv1_gather(
    const ushort* __restrict__ hb,
    const int* __restrict__ rp1, const uint* __restrict__ E1,
    const int* __restrict__ rp2, const uint* __restrict__ E2,
    const float* __restrict__ gamma, const float* __restrict__ beta,
    const float* __restrict__ mean, const float* __restrict__ var,
    ushort* __restrict__ h1b, int N, int nwaves) {
  const int wid  = (blockIdx.x * blockDim.x + threadIdx.x) >> 6;
  const int lane = threadIdx.x & 63;
  const int sub  = lane >> 3;
  const int q    = lane & 7;

  float sc1[8], sh1[8], sc2[8], sh2[8];
#pragma unroll
  for (int t4 = 0; t4 < 2; ++t4) {
    int f1 = q * 8 + t4 * 4;
    float4 gm = *reinterpret_cast<const float4*>(gamma + f1);
    float4 vr = *reinterpret_cast<const float4*>(var + f1);
    float4 mn = *reinterpret_cast<const float4*>(mean + f1);
    float4 bt = *reinterpret_cast<const float4*>(beta + f1);
    float s0 = gm.x * rsqrtf(vr.x + BN_EPS), s1 = gm.y * rsqrtf(vr.y + BN_EPS);
    float s2 = gm.z * rsqrtf(vr.z + BN_EPS), s3 = gm.w * rsqrtf(vr.w + BN_EPS);
    sc1[t4 * 4 + 0] = s0; sh1[t4 * 4 + 0] = bt.x - mn.x * s0;
    sc1[t4 * 4 + 1] = s1; sh1[t4 * 4 + 1] = bt.y - mn.y * s1;
    sc1[t4 * 4 + 2] = s2; sh1[t4 * 4 + 2] = bt.z - mn.z * s2;
    sc1[t4 * 4 + 3] = s3; sh1[t4 * 4 + 3] = bt.w - mn.w * s3;
    int f2 = 64 + f1;
    gm = *reinterpret_cast<const float4*>(gamma + f2);
    vr = *reinterpret_cast<const float4*>(var + f2);
    mn = *reinterpret_cast<const float4*>(mean + f2);
    bt = *reinterpret_cast<const float4*>(beta + f2);
    s0 = gm.x * rsqrtf(vr.x + BN_EPS); s1 = gm.y * rsqrtf(vr.y + BN_EPS);
    s2 = gm.z * rsqrtf(vr.z + BN_EPS); s3 = gm.w * rsqrtf(vr.w + BN_EPS);
    sc2[t4 * 4 + 0] = s0; sh2[t4 * 4 + 0] = bt.x - mn.x * s0;
    sc2[t4 * 4 + 1] = s1; sh2[t4 * 4 + 1] = bt.y - mn.y * s1;
    sc2[t4 * 4 + 2] = s2; sh2[t4 * 4 + 2] = bt.z - mn.z * s2;
    sc2[t4 * 4 + 3] = s3; sh2[t4 * 4 + 3] = bt.w - mn.w * s3;
  }

  for (int r = wid; r < N; r += nwaves) {
    float acc1[8] = {0, 0, 0, 0, 0, 0, 0, 0};
    float acc2[8] = {0, 0, 0, 0, 0, 0, 0, 0};
    {
      int s = rp1[r], e = rp1[r + 1];
      for (int j0 = s; j0 < e; j0 += 8) {
        int jj = j0 + sub;
        uint m = (jj < e) ? E1[jj] : 0u;
        float v = bf2f((ushort)(m >> 16));
        uint4 wv = *reinterpret_cast<const uint4*>(hb + (size_t)(m & 0xffffu) * 64 + q * 8);
        acc1[0] += v * __uint_as_float(wv.x << 16);
        acc1[1] += v * __uint_as_float(wv.x & 0xffff0000u);
        acc1[2] += v * __uint_as_float(wv.y << 16);
        acc1[3] += v * __uint_as_float(wv.y & 0xffff0000u);
        acc1[4] += v * __uint_as_float(wv.z << 16);
        acc1[5] += v * __uint_as_float(wv.z & 0xffff0000u);
        acc1[6] += v * __uint_as_float(wv.w << 16);
        acc1[7] += v * __uint_as_float(wv.w & 0xffff0000u);
      }
    }
    {
      int s = rp2[r], e = rp2[r + 1];
      for (int j0 = s; j0 < e; j0 += 8) {
        int jj = j0 + sub;
        uint m = (jj < e) ? E2[jj] : 0u;
        float v = bf2f((ushort)(m >> 16));
        uint4 wv = *reinterpret_cast<const uint4*>(hb + (size_t)(m & 0xffffu) * 64 + q * 8);
        acc2[0] += v * __uint_as_float(wv.x << 16);
        acc2[1] += v * __uint_as_float(wv.x & 0xffff0000u);
        acc2[2] += v * __uint_as_float(wv.y << 16);
        acc2[3] += v * __uint_as_float(wv.y & 0xffff0000u);
        acc2[4] += v * __uint_as_float(wv.z << 16);
        acc2[5] += v * __uint_as_float(wv.z & 0xffff0000u);
        acc2[6] += v * __uint_as_float(wv.w << 16);
        acc2[7] += v * __uint_as_float(wv.w & 0xffff0000u);
      }
    }
#pragma unroll
    for (int mask = 8; mask <= 32; mask <<= 1) {
#pragma unroll
      for (int t = 0; t < 8; ++t) {
        acc1[t] += __shfl_xor(acc1[t], mask);
        acc2[t] += __shfl_xor(acc2[t], mask);
      }
    }
    if (lane < 8) {
      uint4 p1, p2;
      p1.x = pack2bf(acc1[0] * sc1[0] + sh1[0], acc1[1] * sc1[1] + sh1[1]);
      p1.y = pack2bf(acc1[2] * sc1[2] + sh1[2], acc1[3] * sc1[3] + sh1[3]);
      p1.z = pack2bf(acc1[4] * sc1[4] + sh1[4], acc1[5] * sc1[5] + sh1[5]);
      p1.w = pack2bf(acc1[6] * sc1[6] + sh1[6], acc1[7] * sc1[7] + sh1[7]);
      p2.x = pack2bf(acc2[0] * sc2[0] + sh2[0], acc2[1] * sc2[1] + sh2[1]);
      p2.y = pack2bf(acc2[2] * sc2[2] + sh2[2], acc2[3] * sc2[3] + sh2[3]);
      p2.z = pack2bf(acc2[4] * sc2[4] + sh2[4], acc2[5] * sc2[5] + sh2[5]);
      p2.w = pack2bf(acc2[6] * sc2[6] + sh2[6], acc2[7] * sc2[7] + sh2[7]);
      ushort* dst = h1b + (size_t)r * 128 + q * 8;
      *reinterpret_cast<uint4*>(dst)      = p1;
      *reinterpret_cast<uint4*>(dst + 64) = p2;
    }
  }
}

// ---------------------------------------------------------------------------
// MFMA dense tail: A = [hb | h1b] (N x 192 bf16), Bt staged in LDS.
//   cols 0:40   -> out (f32, +bias)
//   cols 40:80  -> g1b = bf16( h1 @ Wf[192:320] )
//   cols 80:120 -> g2b = bf16( h1 @ Wf[320:448] )
// 256 thr = 4 waves; wave = 32 rows x 128 cols; block = 128 rows.
// mfma_f32_16x16x32_bf16: A row=lane&15, k=(lane>>4)*8+j (contig);
// B col=lane&15, same k; C/D col=lane&15, row=(lane>>4)*4+reg.
// ---------------------------------------------------------------------------
__global__ __launch_bounds__(256) void dense_tail_mfma(
    const ushort* __restrict__ hb, const ushort* __restrict__ h1b,
    const float* __restrict__ Wf, const float* __restrict__ bfin,
    float* __restrict__ out, ushort* __restrict__ g1b, ushort* __restrict__ g2b,
    int N) {
  __shared__ ushort Bt[128][200];   // [col][k], 400B row stride (16B aligned)
  const int tid  = threadIdx.x;
  const int wv   = tid >> 6;
  const int lane = tid & 63;
  const int m16  = lane & 15;
  const int kg   = lane >> 4;
  const int row0 = blockIdx.x * 128;

  // stage Wbig^T as bf16: Bt[col][k]
  for (int idx = tid; idx < 192 * 128; idx += 256) {
    int k = idx >> 7, col = idx & 127;
    float v = 0.f;
    if (col < 40)       v = Wf[(size_t)k * 40 + col];
    else if (col < 80)  { if (k >= 64) v = Wf[(size_t)(128 + k) * 40 + (col - 40)]; }
    else if (col < 120) { if (k >= 64) v = Wf[(size_t)(256 + k) * 40 + (col - 80)]; }
    Bt[col][k] = f2bf(v);
  }
  __syncthreads();

  f32x4 acc[2][8];
#pragma unroll
  for (int i = 0; i < 2; ++i)
#pragma unroll
    for (int t = 0; t < 8; ++t) acc[i][t] = (f32x4){0.f, 0.f, 0.f, 0.f};

#pragma unroll
  for (int ks = 0; ks < 6; ++ks) {
    const int kk = ks * 32 + kg * 8;
    bf16x8 afr[2];
#pragma unroll
    for (int i = 0; i < 2; ++i) {
      int grow = row0 + wv * 32 + i * 16 + m16;
      grow = (grow < N) ? grow : (N - 1);
      const ushort* ap = (kk < 64) ? hb + (size_t)grow * 64 + kk
                                   : h1b + (size_t)grow * 128 + (kk - 64);
      afr[i] = *reinterpret_cast<const bf16x8*>(ap);
    }
#pragma unroll
    for (int t = 0; t < 8; ++t) {
      bf16x8 bfr = *reinterpret_cast<const bf16x8*>(&Bt[t * 16 + m16][kk]);
      acc[0][t] = __builtin_amdgcn_mfma_f32_16x16x32_bf16(afr[0], bfr, acc[0][t], 0, 0, 0);
      acc[1][t] = __builtin_amdgcn_mfma_f32_16x16x32_bf16(afr[1], bfr, acc[1][t], 0, 0, 0);
    }
  }

  // epilogue
#pragma unroll
  for (int i = 0; i < 2; ++i) {
    const int rbase = row0 + wv * 32 + i * 16 + kg * 4;
#pragma unroll
    for (int t = 0; t < 8; ++t) {
      const int col = t * 16 + m16;
      if (col >= 120) continue;
      const float bias = (col < 40) ? bfin[col] : 0.f;
#pragma unroll
      for (int reg = 0; reg < 4; ++reg) {
        int gr = rbase + reg;
        if (gr < N) {
          float v = acc[i][t][reg];
          if (col < 40)       out[(size_t)gr * 40 + col] = v + bias;
          else if (col < 80)  g1b[(size_t)gr * 40 + (col - 40)] = f2bf(v);
          else                g2b[(size_t)gr * 40 + (col - 80)] = f2bf(v);
        }
      }
    }
  }
}

// ---------------------------------------------------------------------------
// Final add: out[r,:] += sum_{adj1} v*g1b[c,:] + sum_{adj2} v*g2b[c,:]
// bf16 g rows are 80B; 8-lane subgroups (8 edges/VMEM), lanes q<5 carry data.
// ---------------------------------------------------------------------------
__global__ __launch_bounds__(256) void final_add_kernel(
    const ushort* __restrict__ g1b, const ushort* __restrict__ g2b,
    const int* __restrict__ rp1, const uint* __restrict__ E1,
    const int* __restrict__ rp2, const uint* __restrict__ E2,
    float* __restrict__ out, int N, int nwaves) {
  const int wid  = (blockIdx.x * blockDim.x + threadIdx.x) >> 6;
  const int lane = threadIdx.x & 63;
  const int sub  = lane >> 3;              // 8 edge slots
  const int q    = lane & 7;
  const int off  = (q < 5) ? q * 8 : 0;    // ushort offset within 40-wide row

  for (int r = wid; r < N; r += nwaves) {
    float a1[8] = {0, 0, 0, 0, 0, 0, 0, 0};
    float a2[8] = {0, 0, 0, 0, 0, 0, 0, 0};
    {
      int s = rp1[r], e = rp1[r + 1];
      for (int j0 = s; j0 < e; j0 += 8) {
        int jj = j0 + sub;
        uint m = (jj < e) ? E1[jj] : 0u;
        float v = bf2f((ushort)(m >> 16));
        uint4 gv = *reinterpret_cast<const uint4*>(g1b + (size_t)(m & 0xffffu) * 40 + off);
        a1[0] += v * __uint_as_float(gv.x << 16);
        a1[1] += v * __uint_as_float(gv.x & 0xffff0000u);
        a1[2] += v * __uint_as_float(gv.y << 16);
        a1[3] += v * __uint_as_float(gv.y & 0xffff0000u);
        a1[4] += v * __uint_as_float(gv.z << 16);
        a1[5] += v * __uint_as_float(gv.z & 0xffff0000u);
        a1[6] += v * __uint_as_float(gv.w << 16);
        a1[7] += v * __uint_as_float(gv.w & 0xffff0000u);
      }
    }
    {
      int s = rp2[r], e = rp2[r + 1];
      for (int j0 = s; j0 < e; j0 += 8) {
        int jj = j0 + sub;
        uint m = (jj < e) ? E2[jj] : 0u;
        float v = bf2f((ushort)(m >> 16));
        uint4 gv = *reinterpret_cast<const uint4*>(g2b + (size_t)(m & 0xffffu) * 40 + off);
        a2[0] += v * __uint_as_float(gv.x << 16);
        a2[1] += v * __uint_as_float(gv.x & 0xffff0000u);
        a2[2] += v * __uint_as_float(gv.y << 16);
        a2[3] += v * __uint_as_float(gv.y & 0xffff0000u);
        a2[4] += v * __uint_as_float(gv.z << 16);
        a2[5] += v * __uint_as_float(gv.z & 0xffff0000u);
        a2[6] += v * __uint_as_float(gv.w << 16);
        a2[7] += v * __uint_as_float(gv.w & 0xffff0000u);
      }
    }
#pragma unroll
    for (int mask = 8; mask <= 32; mask <<= 1) {
#pragma unroll
      for (int t = 0; t < 8; ++t) {
        a1[t] += __shfl_xor(a1[t], mask);
        a2[t] += __shfl_xor(a2[t], mask);
      }
    }
    if (lane < 5) {   // sub==0, q==lane: owns features lane*8 .. lane*8+7
      float* p = out + (size_t)r * 40 + lane * 8;
      float4 o0 = *reinterpret_cast<const float4*>(p);
      float4 o1 = *reinterpret_cast<const float4*>(p + 4);
      o0.x += a1[0] + a2[0]; o0.y += a1[1] + a2[1];
      o0.z += a1[2] + a2[2]; o0.w += a1[3] + a2[3];
      o1.x += a1[4] + a2[4]; o1.y += a1[5] + a2[5];
      o1.z += a1[6] + a2[6]; o1.w += a1[7] + a2[7];
      *reinterpret_cast<float4*>(p)     = o0;
      *reinterpret_cast<float4*>(p + 4) = o1;
    }
  }
}

// ---------------------------------------------------------------------------
extern "C" void kernel_launch(void* const* d_in, const int* in_sizes, int n_in,
                              void* d_out, int out_size, void* d_ws, size_t ws_size,
                              hipStream_t stream) {
  const float* x     = (const float*)d_in[0];
  const int*   a1r   = (const int*)d_in[1];
  const int*   a1c   = (const int*)d_in[2];
  const float* a1v   = (const float*)d_in[3];
  const int*   a2r   = (const int*)d_in[4];
  const int*   a2c   = (const int*)d_in[5];
  const float* a2v   = (const float*)d_in[6];
  const float* We    = (const float*)d_in[7];
  const float* be    = (const float*)d_in[8];
  const float* gamma = (const float*)d_in[9];
  const float* beta  = (const float*)d_in[10];
  const float* mean  = (const float*)d_in[11];
  const float* var   = (const float*)d_in[12];
  const float* Wf    = (const float*)d_in[13];
  const float* bf    = (const float*)d_in[14];
  float* out = (float*)d_out;

  const int N  = in_sizes[0] / 512;
  const int E1 = in_sizes[1];
  const int E2 = in_sizes[4];
  const int nbins = (N + 511) >> 9;   // requires N <= 65536

  char* p = (char*)d_ws;
  auto alloc = [&](size_t bytes) {
    char* q = p; p += (bytes + 255) & ~(size_t)255; return q;
  };
  ushort* hb   = (ushort*)alloc((size_t)N * 64 * 2);
  ushort* h1b  = (ushort*)alloc((size_t)N * 128 * 2);
  ushort* g1b  = (ushort*)alloc((size_t)N * 40 * 2);
  ushort* g2b  = (ushort*)alloc((size_t)N * 40 * 2);
  int*    rp1  = (int*)   alloc(((size_t)N + 1) * 4);
  int*    rp2  = (int*)   alloc(((size_t)N + 1) * 4);
  uint*   E1s  = (uint*)  alloc((size_t)E1 * 4);
  uint*   E2s  = (uint*)  alloc((size_t)E2 * 4);
  int2*   S1   = (int2*)  alloc((size_t)E1 * 8);
  int2*   S2   = (int2*)  alloc((size_t)E2 * 8);
  int*    gbin1  = (int*) alloc(MAXBINS * 4);
  int*    gbin2  = (int*) alloc(MAXBINS * 4);
  int*    gbase1 = (int*) alloc(MAXBINS * 4);
  int*    gbase2 = (int*) alloc(MAXBINS * 4);
  int*    gcur1  = (int*) alloc(MAXBINS * 4);
  int*    gcur2  = (int*) alloc(MAXBINS * 4);

  hipMemsetAsync(gbin1, 0, (size_t)2 * MAXBINS * 4 + 256, stream);

  // embed (independent of CSR build)
  embed_kernel<<<(N + 31) / 32, 256, 0, stream>>>(x, We, be, hb, N);

  // binned CSR build
  bin_hist<<<256, 256, 0, stream>>>(a1r, gbin1, E1, nbins);
  bin_hist<<<256, 256, 0, stream>>>(a2r, gbin2, E2, nbins);
  bin_scan<<<1, 64, 0, stream>>>(gbin1, gbase1, gcur1, gbin2, gbase2, gcur2, nbins);
  bin_scatter<<<256, 256, 0, stream>>>(a1r, a1c, a1v, E1, gcur1, S1, nbins);
  bin_scatter<<<256, 256, 0, stream>>>(a2r, a2c, a2v, E2, gcur2, S2, nbins);
  csr_finalize<<<2 * nbins, 256, 0, stream>>>(
      S1, gbase1, rp1, E1s, E1, S2, gbase2, rp2, E2s, E2, N, nbins);

  // conv1 (gather, 8 edges per VMEM) + fused BN -> bf16 h1b
  const int NW = 2048 * 4;
  conv1_gather<<<2048, 256, 0, stream>>>(
      hb, rp1, E1s, rp2, E2s, gamma, beta, mean, var, h1b, N, NW);

  // MFMA dense tail: out base + g1b/g2b in one pass
  dense_tail_mfma<<<(N + 127) / 128, 256, 0, stream>>>(
      hb, h1b, Wf, bf, out, g1b, g2b, N);

  // out += A1@g1 + A2@g2 (8 edges per VMEM, bf16 gather)
  final_add_kernel<<<2048, 256, 0, stream>>>(
      g1b, g2b, rp1, E1s, rp2, E2s, out, N, NW);
}

// Round 7
// 359.887 us; speedup vs baseline: 21.4560x; 1.0753x over previous
//
#include <hip/hip_runtime.h>

#define BN_EPS 1e-5f
#define MAXBINS 128   // bins of 512 rows; requires N <= 65536 (col packs in 16 bits)

typedef __attribute__((ext_vector_type(8))) short bf16x8;
typedef __attribute__((ext_vector_type(4))) float f32x4;

__device__ __forceinline__ ushort f2bf(float f) {
  uint u = __float_as_uint(f);
  u += 0x7fffu + ((u >> 16) & 1u);
  return (ushort)(u >> 16);
}
__device__ __forceinline__ float bf2f(ushort u) {
  return __uint_as_float((uint)u << 16);
}
__device__ __forceinline__ uint pack2bf(float a, float b) {
  return (uint)f2bf(a) | ((uint)f2bf(b) << 16);
}
// acc[0..7] += v * bf16x8(wv)
__device__ __forceinline__ void fma8(float acc[8], uint4 wv, float v) {
  acc[0] += v * __uint_as_float(wv.x << 16);
  acc[1] += v * __uint_as_float(wv.x & 0xffff0000u);
  acc[2] += v * __uint_as_float(wv.y << 16);
  acc[3] += v * __uint_as_float(wv.y & 0xffff0000u);
  acc[4] += v * __uint_as_float(wv.z << 16);
  acc[5] += v * __uint_as_float(wv.z & 0xffff0000u);
  acc[6] += v * __uint_as_float(wv.w << 16);
  acc[7] += v * __uint_as_float(wv.w & 0xffff0000u);
}

// ---------------------------------------------------------------------------
// Embed: hb = bf16( relu(x @ W_embed + b_embed) )   [N,512]@[512,64] -> [N,64]
// ---------------------------------------------------------------------------
__global__ __launch_bounds__(256) void embed_kernel(
    const float* __restrict__ x, const float* __restrict__ W,
    const float* __restrict__ b, ushort* __restrict__ hb, int N) {
  __shared__ __align__(16) float xs[32][68];
  __shared__ __align__(16) float ws[64][64];
  const int tid  = threadIdx.x;
  const int cgrp = tid & 15;   // 16 col-groups of 4
  const int rgrp = tid >> 4;   // 16 row-groups of 2
  const int row0 = blockIdx.x * 32;

  float acc[2][4] = {{0.f, 0.f, 0.f, 0.f}, {0.f, 0.f, 0.f, 0.f}};

  for (int k0 = 0; k0 < 512; k0 += 64) {
    for (int idx = tid; idx < 32 * 16; idx += 256) {
      int r = idx >> 4, k4 = idx & 15;
      int gr = row0 + r;
      float4 xv = make_float4(0.f, 0.f, 0.f, 0.f);
      if (gr < N) xv = *reinterpret_cast<const float4*>(x + (size_t)gr * 512 + k0 + k4 * 4);
      *reinterpret_cast<float4*>(&xs[r][k4 * 4]) = xv;
    }
    for (int idx = tid; idx < 64 * 16; idx += 256) {
      int kk = idx >> 4, c4 = idx & 15;
      *reinterpret_cast<float4*>(&ws[kk][c4 * 4]) =
          *reinterpret_cast<const float4*>(W + (size_t)(k0 + kk) * 64 + c4 * 4);
    }
    __syncthreads();
#pragma unroll
    for (int kk = 0; kk < 64; ++kk) {
      float x0 = xs[rgrp * 2 + 0][kk];
      float x1 = xs[rgrp * 2 + 1][kk];
      float4 wv = *reinterpret_cast<const float4*>(&ws[kk][cgrp * 4]);
      acc[0][0] += x0 * wv.x; acc[0][1] += x0 * wv.y;
      acc[0][2] += x0 * wv.z; acc[0][3] += x0 * wv.w;
      acc[1][0] += x1 * wv.x; acc[1][1] += x1 * wv.y;
      acc[1][2] += x1 * wv.z; acc[1][3] += x1 * wv.w;
    }
    __syncthreads();
  }

  float4 bv = *reinterpret_cast<const float4*>(&b[cgrp * 4]);
#pragma unroll
  for (int i = 0; i < 2; ++i) {
    int gr = row0 + rgrp * 2 + i;
    if (gr < N) {
      ushort4 ob;
      ob.x = f2bf(fmaxf(acc[i][0] + bv.x, 0.f));
      ob.y = f2bf(fmaxf(acc[i][1] + bv.y, 0.f));
      ob.z = f2bf(fmaxf(acc[i][2] + bv.z, 0.f));
      ob.w = f2bf(fmaxf(acc[i][3] + bv.w, 0.f));
      *reinterpret_cast<ushort4*>(&hb[(size_t)gr * 64 + cgrp * 4]) = ob;
    }
  }
}

// ---------------------------------------------------------------------------
// CSR build, two-level binned (bin = row>>9)
// ---------------------------------------------------------------------------
__global__ __launch_bounds__(256) void bin_hist(
    const int* __restrict__ rows, int* __restrict__ gbin, int E, int nbins) {
  __shared__ int lb[MAXBINS];
  const int tid = threadIdx.x;
  if (tid < nbins) lb[tid] = 0;
  __syncthreads();
  const int stride = gridDim.x * blockDim.x;
  for (int i = blockIdx.x * blockDim.x + tid; i < E; i += stride)
    atomicAdd(&lb[rows[i] >> 9], 1);
  __syncthreads();
  if (tid < nbins && lb[tid]) atomicAdd(&gbin[tid], lb[tid]);
}

__device__ __forceinline__ void scan_bins_dev(
    const int* gbin, int* gbase, int* gcur, int nbins, int lane) {
  int carry = 0;
  for (int ch = 0; ch * 64 < nbins; ++ch) {
    int idx = ch * 64 + lane;
    int v = (idx < nbins) ? gbin[idx] : 0;
    int inc = v;
#pragma unroll
    for (int off = 1; off < 64; off <<= 1) {
      int y = __shfl_up(inc, off);
      if (lane >= off) inc += y;
    }
    int ex = carry + inc - v;
    if (idx < nbins) { gbase[idx] = ex; gcur[idx] = ex; }
    carry += __shfl(inc, 63);
  }
}

__global__ __launch_bounds__(64) void bin_scan(
    const int* __restrict__ gbin1, int* __restrict__ gbase1, int* __restrict__ gcur1,
    const int* __restrict__ gbin2, int* __restrict__ gbase2, int* __restrict__ gcur2,
    int nbins) {
  int lane = threadIdx.x;
  scan_bins_dev(gbin1, gbase1, gcur1, nbins, lane);
  scan_bins_dev(gbin2, gbase2, gcur2, nbins, lane);
}

// Staging record: int2( col | (row&511)<<16 , val_bits_f32 ).
__global__ __launch_bounds__(256) void bin_scatter(
    const int* __restrict__ rows, const int* __restrict__ cols,
    const float* __restrict__ vals, int E, int* __restrict__ gcur,
    int2* __restrict__ S, int nbins) {
  __shared__ int lcnt[MAXBINS];
  __shared__ int lcur[MAXBINS];
  const int tid = threadIdx.x;
  for (int e0 = blockIdx.x * 2048; e0 < E; e0 += gridDim.x * 2048) {
    int i0 = e0 + tid * 8;
    int r[8], c[8], vb[8];
    if (i0 + 8 <= E) {
      int4 a = *reinterpret_cast<const int4*>(rows + i0);
      int4 b = *reinterpret_cast<const int4*>(rows + i0 + 4);
      r[0]=a.x; r[1]=a.y; r[2]=a.z; r[3]=a.w; r[4]=b.x; r[5]=b.y; r[6]=b.z; r[7]=b.w;
      a = *reinterpret_cast<const int4*>(cols + i0);
      b = *reinterpret_cast<const int4*>(cols + i0 + 4);
      c[0]=a.x; c[1]=a.y; c[2]=a.z; c[3]=a.w; c[4]=b.x; c[5]=b.y; c[6]=b.z; c[7]=b.w;
      a = *reinterpret_cast<const int4*>(vals + i0);
      b = *reinterpret_cast<const int4*>(vals + i0 + 4);
      vb[0]=a.x; vb[1]=a.y; vb[2]=a.z; vb[3]=a.w; vb[4]=b.x; vb[5]=b.y; vb[6]=b.z; vb[7]=b.w;
    } else {
#pragma unroll
      for (int t = 0; t < 8; ++t) {
        int i = i0 + t;
        bool ok = i < E;
        r[t]  = ok ? rows[i] : -1;
        c[t]  = ok ? cols[i] : 0;
        vb[t] = ok ? __float_as_int(vals[i]) : 0;
      }
    }
    if (tid < nbins) lcnt[tid] = 0;
    __syncthreads();
#pragma unroll
    for (int t = 0; t < 8; ++t)
      if (r[t] >= 0) atomicAdd(&lcnt[r[t] >> 9], 1);
    __syncthreads();
    if (tid < nbins) {
      int n = lcnt[tid];
      lcur[tid] = n ? atomicAdd(&gcur[tid], n) : 0;
    }
    __syncthreads();
#pragma unroll
    for (int t = 0; t < 8; ++t) {
      if (r[t] >= 0) {
        int pos = atomicAdd(&lcur[r[t] >> 9], 1);
        S[pos] = make_int2(c[t] | ((r[t] & 511) << 16), vb[t]);
      }
    }
    __syncthreads();
  }
}

// One block per (graph, bin). Final edge record: uint( col | bf16(val)<<16 ).
__global__ __launch_bounds__(256) void csr_finalize(
    const int2* __restrict__ S1, const int* __restrict__ gbase1,
    int* __restrict__ rp1, uint* __restrict__ Eo1, int Etot1,
    const int2* __restrict__ S2, const int* __restrict__ gbase2,
    int* __restrict__ rp2, uint* __restrict__ Eo2, int Etot2,
    int N, int nbins) {
  __shared__ int cnt[512];
  __shared__ int cur[512];
  const int tid = threadIdx.x;
  const int b = blockIdx.x % nbins;
  const int g = blockIdx.x / nbins;
  const int2* S     = g ? S2 : S1;
  const int* gbase  = g ? gbase2 : gbase1;
  int* rp           = g ? rp2 : rp1;
  uint* Eo          = g ? Eo2 : Eo1;
  const int Etot    = g ? Etot2 : Etot1;

  const int base = gbase[b];
  const int end  = (b + 1 < nbins) ? gbase[b + 1] : Etot;
  const int r0   = b << 9;
  const int nrows = min(512, N - r0);

  for (int l = tid; l < 512; l += 256) cnt[l] = 0;
  __syncthreads();
  for (int j = base + tid; j < end; j += 256)
    atomicAdd(&cnt[S[j].x >> 16], 1);
  __syncthreads();
  if (tid < 64) {
    int carry = 0;
#pragma unroll
    for (int ch = 0; ch < 8; ++ch) {
      int v = cnt[ch * 64 + tid];
      int inc = v;
#pragma unroll
      for (int off = 1; off < 64; off <<= 1) {
        int y = __shfl_up(inc, off);
        if (tid >= off) inc += y;
      }
      inc += carry;
      cnt[ch * 64 + tid] = inc;
      carry = __shfl(inc, 63);
    }
  }
  __syncthreads();
  for (int l = tid; l < 512; l += 256)
    cur[l] = base + ((l > 0) ? cnt[l - 1] : 0);
  for (int l = tid; l < nrows; l += 256)
    rp[r0 + l + 1] = base + cnt[l];
  if (b == 0 && tid == 0) rp[0] = 0;
  __syncthreads();
  for (int j = base + tid; j < end; j += 256) {
    int2 m = S[j];
    int pos = atomicAdd(&cur[m.x >> 16], 1);
    Eo[pos] = (uint)(m.x & 0xffff) | ((uint)f2bf(__int_as_float(m.y)) << 16);
  }
}

// ---------------------------------------------------------------------------
// Conv1 gather + fused BN. One wave per row (grid-stride).
// 32-edge chunks: 4 independent masked meta loads + 4 independent gathers
// per iteration (MLP=4). Masked slots -> col 0 / val 0 (harmless, L2-hot).
// ---------------------------------------------------------------------------
__global__ __launch_bounds__(256) void conv1_gather(
    const ushort* __restrict__ hb,
    const int* __restrict__ rp1, const uint* __restrict__ E1,
    const int* __restrict__ rp2, const uint* __restrict__ E2,
    const float* __restrict__ gamma, const float* __restrict__ beta,
    const float* __restrict__ mean, const float* __restrict__ var,
    ushort* __restrict__ h1b, int N, int nwaves) {
  const int wid  = (blockIdx.x * blockDim.x + threadIdx.x) >> 6;
  const int lane = threadIdx.x & 63;
  const int sub  = lane >> 3;
  const int q    = lane & 7;

  float sc1[8], sh1[8], sc2[8], sh2[8];
#pragma unroll
  for (int t4 = 0; t4 < 2; ++t4) {
    int f1 = q * 8 + t4 * 4;
    float4 gm = *reinterpret_cast<const float4*>(gamma + f1);
    float4 vr = *reinterpret_cast<const float4*>(var + f1);
    float4 mn = *reinterpret_cast<const float4*>(mean + f1);
    float4 bt = *reinterpret_cast<const float4*>(beta + f1);
    float s0 = gm.x * rsqrtf(vr.x + BN_EPS), s1 = gm.y * rsqrtf(vr.y + BN_EPS);
    float s2 = gm.z * rsqrtf(vr.z + BN_EPS), s3 = gm.w * rsqrtf(vr.w + BN_EPS);
    sc1[t4 * 4 + 0] = s0; sh1[t4 * 4 + 0] = bt.x - mn.x * s0;
    sc1[t4 * 4 + 1] = s1; sh1[t4 * 4 + 1] = bt.y - mn.y * s1;
    sc1[t4 * 4 + 2] = s2; sh1[t4 * 4 + 2] = bt.z - mn.z * s2;
    sc1[t4 * 4 + 3] = s3; sh1[t4 * 4 + 3] = bt.w - mn.w * s3;
    int f2 = 64 + f1;
    gm = *reinterpret_cast<const float4*>(gamma + f2);
    vr = *reinterpret_cast<const float4*>(var + f2);
    mn = *reinterpret_cast<const float4*>(mean + f2);
    bt = *reinterpret_cast<const float4*>(beta + f2);
    s0 = gm.x * rsqrtf(vr.x + BN_EPS); s1 = gm.y * rsqrtf(vr.y + BN_EPS);
    s2 = gm.z * rsqrtf(vr.z + BN_EPS); s3 = gm.w * rsqrtf(vr.w + BN_EPS);
    sc2[t4 * 4 + 0] = s0; sh2[t4 * 4 + 0] = bt.x - mn.x * s0;
    sc2[t4 * 4 + 1] = s1; sh2[t4 * 4 + 1] = bt.y - mn.y * s1;
    sc2[t4 * 4 + 2] = s2; sh2[t4 * 4 + 2] = bt.z - mn.z * s2;
    sc2[t4 * 4 + 3] = s3; sh2[t4 * 4 + 3] = bt.w - mn.w * s3;
  }

  for (int r = wid; r < N; r += nwaves) {
    float acc1[8] = {0, 0, 0, 0, 0, 0, 0, 0};
    float acc2[8] = {0, 0, 0, 0, 0, 0, 0, 0};
    {
      int s = rp1[r], e = rp1[r + 1];
      for (int j0 = s; j0 < e; j0 += 32) {
        int j = j0 + sub;
        uint m0 = (j      < e) ? E1[j]      : 0u;
        uint m1 = (j + 8  < e) ? E1[j + 8]  : 0u;
        uint m2 = (j + 16 < e) ? E1[j + 16] : 0u;
        uint m3 = (j + 24 < e) ? E1[j + 24] : 0u;
        uint4 w0 = *reinterpret_cast<const uint4*>(hb + (size_t)(m0 & 0xffffu) * 64 + q * 8);
        uint4 w1 = *reinterpret_cast<const uint4*>(hb + (size_t)(m1 & 0xffffu) * 64 + q * 8);
        uint4 w2 = *reinterpret_cast<const uint4*>(hb + (size_t)(m2 & 0xffffu) * 64 + q * 8);
        uint4 w3 = *reinterpret_cast<const uint4*>(hb + (size_t)(m3 & 0xffffu) * 64 + q * 8);
        fma8(acc1, w0, bf2f((ushort)(m0 >> 16)));
        fma8(acc1, w1, bf2f((ushort)(m1 >> 16)));
        fma8(acc1, w2, bf2f((ushort)(m2 >> 16)));
        fma8(acc1, w3, bf2f((ushort)(m3 >> 16)));
      }
    }
    {
      int s = rp2[r], e = rp2[r + 1];
      for (int j0 = s; j0 < e; j0 += 32) {
        int j = j0 + sub;
        uint m0 = (j      < e) ? E2[j]      : 0u;
        uint m1 = (j + 8  < e) ? E2[j + 8]  : 0u;
        uint m2 = (j + 16 < e) ? E2[j + 16] : 0u;
        uint m3 = (j + 24 < e) ? E2[j + 24] : 0u;
        uint4 w0 = *reinterpret_cast<const uint4*>(hb + (size_t)(m0 & 0xffffu) * 64 + q * 8);
        uint4 w1 = *reinterpret_cast<const uint4*>(hb + (size_t)(m1 & 0xffffu) * 64 + q * 8);
        uint4 w2 = *reinterpret_cast<const uint4*>(hb + (size_t)(m2 & 0xffffu) * 64 + q * 8);
        uint4 w3 = *reinterpret_cast<const uint4*>(hb + (size_t)(m3 & 0xffffu) * 64 + q * 8);
        fma8(acc2, w0, bf2f((ushort)(m0 >> 16)));
        fma8(acc2, w1, bf2f((ushort)(m1 >> 16)));
        fma8(acc2, w2, bf2f((ushort)(m2 >> 16)));
        fma8(acc2, w3, bf2f((ushort)(m3 >> 16)));
      }
    }
#pragma unroll
    for (int mask = 8; mask <= 32; mask <<= 1) {
#pragma unroll
      for (int t = 0; t < 8; ++t) {
        acc1[t] += __shfl_xor(acc1[t], mask);
        acc2[t] += __shfl_xor(acc2[t], mask);
      }
    }
    if (lane < 8) {
      uint4 p1, p2;
      p1.x = pack2bf(acc1[0] * sc1[0] + sh1[0], acc1[1] * sc1[1] + sh1[1]);
      p1.y = pack2bf(acc1[2] * sc1[2] + sh1[2], acc1[3] * sc1[3] + sh1[3]);
      p1.z = pack2bf(acc1[4] * sc1[4] + sh1[4], acc1[5] * sc1[5] + sh1[5]);
      p1.w = pack2bf(acc1[6] * sc1[6] + sh1[6], acc1[7] * sc1[7] + sh1[7]);
      p2.x = pack2bf(acc2[0] * sc2[0] + sh2[0], acc2[1] * sc2[1] + sh2[1]);
      p2.y = pack2bf(acc2[2] * sc2[2] + sh2[2], acc2[3] * sc2[3] + sh2[3]);
      p2.z = pack2bf(acc2[4] * sc2[4] + sh2[4], acc2[5] * sc2[5] + sh2[5]);
      p2.w = pack2bf(acc2[6] * sc2[6] + sh2[6], acc2[7] * sc2[7] + sh2[7]);
      ushort* dst = h1b + (size_t)r * 128 + q * 8;
      *reinterpret_cast<uint4*>(dst)      = p1;
      *reinterpret_cast<uint4*>(dst + 64) = p2;
    }
  }
}

// ---------------------------------------------------------------------------
// MFMA dense tail: A = [hb | h1b] (N x 192 bf16), Bt staged in LDS.
//   cols 0:40 -> out (f32,+bias); 40:80 -> g1b; 80:120 -> g2b (bf16)
// ---------------------------------------------------------------------------
__global__ __launch_bounds__(256) void dense_tail_mfma(
    const ushort* __restrict__ hb, const ushort* __restrict__ h1b,
    const float* __restrict__ Wf, const float* __restrict__ bfin,
    float* __restrict__ out, ushort* __restrict__ g1b, ushort* __restrict__ g2b,
    int N) {
  __shared__ ushort Bt[128][200];   // [col][k], 400B row stride
  const int tid  = threadIdx.x;
  const int wv   = tid >> 6;
  const int lane = tid & 63;
  const int m16  = lane & 15;
  const int kg   = lane >> 4;
  const int row0 = blockIdx.x * 128;

  for (int idx = tid; idx < 192 * 128; idx += 256) {
    int k = idx >> 7, col = idx & 127;
    float v = 0.f;
    if (col < 40)       v = Wf[(size_t)k * 40 + col];
    else if (col < 80)  { if (k >= 64) v = Wf[(size_t)(128 + k) * 40 + (col - 40)]; }
    else if (col < 120) { if (k >= 64) v = Wf[(size_t)(256 + k) * 40 + (col - 80)]; }
    Bt[col][k] = f2bf(v);
  }
  __syncthreads();

  f32x4 acc[2][8];
#pragma unroll
  for (int i = 0; i < 2; ++i)
#pragma unroll
    for (int t = 0; t < 8; ++t) acc[i][t] = (f32x4){0.f, 0.f, 0.f, 0.f};

#pragma unroll
  for (int ks = 0; ks < 6; ++ks) {
    const int kk = ks * 32 + kg * 8;
    bf16x8 afr[2];
#pragma unroll
    for (int i = 0; i < 2; ++i) {
      int grow = row0 + wv * 32 + i * 16 + m16;
      grow = (grow < N) ? grow : (N - 1);
      const ushort* ap = (kk < 64) ? hb + (size_t)grow * 64 + kk
                                   : h1b + (size_t)grow * 128 + (kk - 64);
      afr[i] = *reinterpret_cast<const bf16x8*>(ap);
    }
#pragma unroll
    for (int t = 0; t < 8; ++t) {
      bf16x8 bfr = *reinterpret_cast<const bf16x8*>(&Bt[t * 16 + m16][kk]);
      acc[0][t] = __builtin_amdgcn_mfma_f32_16x16x32_bf16(afr[0], bfr, acc[0][t], 0, 0, 0);
      acc[1][t] = __builtin_amdgcn_mfma_f32_16x16x32_bf16(afr[1], bfr, acc[1][t], 0, 0, 0);
    }
  }

#pragma unroll
  for (int i = 0; i < 2; ++i) {
    const int rbase = row0 + wv * 32 + i * 16 + kg * 4;
#pragma unroll
    for (int t = 0; t < 8; ++t) {
      const int col = t * 16 + m16;
      if (col >= 120) continue;
      const float bias = (col < 40) ? bfin[col] : 0.f;
#pragma unroll
      for (int reg = 0; reg < 4; ++reg) {
        int gr = rbase + reg;
        if (gr < N) {
          float v = acc[i][t][reg];
          if (col < 40)       out[(size_t)gr * 40 + col] = v + bias;
          else if (col < 80)  g1b[(size_t)gr * 40 + (col - 40)] = f2bf(v);
          else                g2b[(size_t)gr * 40 + (col - 80)] = f2bf(v);
        }
      }
    }
  }
}

// ---------------------------------------------------------------------------
// Final add: out[r,:] += sum_{adj1} v*g1b[c,:] + sum_{adj2} v*g2b[c,:]
// 32-edge chunks, MLP=4, 8-lane subgroups; lanes q<5 carry real data.
// ---------------------------------------------------------------------------
__global__ __launch_bounds__(256) void final_add_kernel(
    const ushort* __restrict__ g1b, const ushort* __restrict__ g2b,
    const int* __restrict__ rp1, const uint* __restrict__ E1,
    const int* __restrict__ rp2, const uint* __restrict__ E2,
    float* __restrict__ out, int N, int nwaves) {
  const int wid  = (blockIdx.x * blockDim.x + threadIdx.x) >> 6;
  const int lane = threadIdx.x & 63;
  const int sub  = lane >> 3;
  const int q    = lane & 7;
  const int off  = (q < 5) ? q * 8 : 0;

  for (int r = wid; r < N; r += nwaves) {
    float a1[8] = {0, 0, 0, 0, 0, 0, 0, 0};
    float a2[8] = {0, 0, 0, 0, 0, 0, 0, 0};
    {
      int s = rp1[r], e = rp1[r + 1];
      for (int j0 = s; j0 < e; j0 += 32) {
        int j = j0 + sub;
        uint m0 = (j      < e) ? E1[j]      : 0u;
        uint m1 = (j + 8  < e) ? E1[j + 8]  : 0u;
        uint m2 = (j + 16 < e) ? E1[j + 16] : 0u;
        uint m3 = (j + 24 < e) ? E1[j + 24] : 0u;
        uint4 w0 = *reinterpret_cast<const uint4*>(g1b + (size_t)(m0 & 0xffffu) * 40 + off);
        uint4 w1 = *reinterpret_cast<const uint4*>(g1b + (size_t)(m1 & 0xffffu) * 40 + off);
        uint4 w2 = *reinterpret_cast<const uint4*>(g1b + (size_t)(m2 & 0xffffu) * 40 + off);
        uint4 w3 = *reinterpret_cast<const uint4*>(g1b + (size_t)(m3 & 0xffffu) * 40 + off);
        fma8(a1, w0, bf2f((ushort)(m0 >> 16)));
        fma8(a1, w1, bf2f((ushort)(m1 >> 16)));
        fma8(a1, w2, bf2f((ushort)(m2 >> 16)));
        fma8(a1, w3, bf2f((ushort)(m3 >> 16)));
      }
    }
    {
      int s = rp2[r], e = rp2[r + 1];
      for (int j0 = s; j0 < e; j0 += 32) {
        int j = j0 + sub;
        uint m0 = (j      < e) ? E2[j]      : 0u;
        uint m1 = (j + 8  < e) ? E2[j + 8]  : 0u;
        uint m2 = (j + 16 < e) ? E2[j + 16] : 0u;
        uint m3 = (j + 24 < e) ? E2[j + 24] : 0u;
        uint4 w0 = *reinterpret_cast<const uint4*>(g2b + (size_t)(m0 & 0xffffu) * 40 + off);
        uint4 w1 = *reinterpret_cast<const uint4*>(g2b + (size_t)(m1 & 0xffffu) * 40 + off);
        uint4 w2 = *reinterpret_cast<const uint4*>(g2b + (size_t)(m2 & 0xffffu) * 40 + off);
        uint4 w3 = *reinterpret_cast<const uint4*>(g2b + (size_t)(m3 & 0xffffu) * 40 + off);
        fma8(a2, w0, bf2f((ushort)(m0 >> 16)));
        fma8(a2, w1, bf2f((ushort)(m1 >> 16)));
        fma8(a2, w2, bf2f((ushort)(m2 >> 16)));
        fma8(a2, w3, bf2f((ushort)(m3 >> 16)));
      }
    }
#pragma unroll
    for (int mask = 8; mask <= 32; mask <<= 1) {
#pragma unroll
      for (int t = 0; t < 8; ++t) {
        a1[t] += __shfl_xor(a1[t], mask);
        a2[t] += __shfl_xor(a2[t], mask);
      }
    }
    if (lane < 5) {
      float* p = out + (size_t)r * 40 + lane * 8;
      float4 o0 = *reinterpret_cast<const float4*>(p);
      float4 o1 = *reinterpret_cast<const float4*>(p + 4);
      o0.x += a1[0] + a2[0]; o0.y += a1[1] + a2[1];
      o0.z += a1[2] + a2[2]; o0.w += a1[3] + a2[3];
      o1.x += a1[4] + a2[4]; o1.y += a1[5] + a2[5];
      o1.z += a1[6] + a2[6]; o1.w += a1[7] + a2[7];
      *reinterpret_cast<float4*>(p)     = o0;
      *reinterpret_cast<float4*>(p + 4) = o1;
    }
  }
}

// ---------------------------------------------------------------------------
extern "C" void kernel_launch(void* const* d_in, const int* in_sizes, int n_in,
                              void* d_out, int out_size, void* d_ws, size_t ws_size,
                              hipStream_t stream) {
  const float* x     = (const float*)d_in[0];
  const int*   a1r   = (const int*)d_in[1];
  const int*   a1c   = (const int*)d_in[2];
  const float* a1v   = (const float*)d_in[3];
  const int*   a2r   = (const int*)d_in[4];
  const int*   a2c   = (const int*)d_in[5];
  const float* a2v   = (const float*)d_in[6];
  const float* We    = (const float*)d_in[7];
  const float* be    = (const float*)d_in[8];
  const float* gamma = (const float*)d_in[9];
  const float* beta  = (const float*)d_in[10];
  const float* mean  = (const float*)d_in[11];
  const float* var   = (const float*)d_in[12];
  const float* Wf    = (const float*)d_in[13];
  const float* bf    = (const float*)d_in[14];
  float* out = (float*)d_out;

  const int N  = in_sizes[0] / 512;
  const int E1 = in_sizes[1];
  const int E2 = in_sizes[4];
  const int nbins = (N + 511) >> 9;   // requires N <= 65536

  char* p = (char*)d_ws;
  auto alloc = [&](size_t bytes) {
    char* q = p; p += (bytes + 255) & ~(size_t)255; return q;
  };
  ushort* hb   = (ushort*)alloc((size_t)N * 64 * 2);
  ushort* h1b  = (ushort*)alloc((size_t)N * 128 * 2);
  ushort* g1b  = (ushort*)alloc((size_t)N * 40 * 2);
  ushort* g2b  = (ushort*)alloc((size_t)N * 40 * 2);
  int*    rp1  = (int*)   alloc(((size_t)N + 1) * 4);
  int*    rp2  = (int*)   alloc(((size_t)N + 1) * 4);
  uint*   E1s  = (uint*)  alloc((size_t)E1 * 4);
  uint*   E2s  = (uint*)  alloc((size_t)E2 * 4);
  int2*   S1   = (int2*)  alloc((size_t)E1 * 8);
  int2*   S2   = (int2*)  alloc((size_t)E2 * 8);
  int*    gbin1  = (int*) alloc(MAXBINS * 4);
  int*    gbin2  = (int*) alloc(MAXBINS * 4);
  int*    gbase1 = (int*) alloc(MAXBINS * 4);
  int*    gbase2 = (int*) alloc(MAXBINS * 4);
  int*    gcur1  = (int*) alloc(MAXBINS * 4);
  int*    gcur2  = (int*) alloc(MAXBINS * 4);

  hipMemsetAsync(gbin1, 0, (size_t)2 * MAXBINS * 4 + 256, stream);

  // embed (independent of CSR build)
  embed_kernel<<<(N + 31) / 32, 256, 0, stream>>>(x, We, be, hb, N);

  // binned CSR build
  bin_hist<<<256, 256, 0, stream>>>(a1r, gbin1, E1, nbins);
  bin_hist<<<256, 256, 0, stream>>>(a2r, gbin2, E2, nbins);
  bin_scan<<<1, 64, 0, stream>>>(gbin1, gbase1, gcur1, gbin2, gbase2, gcur2, nbins);
  bin_scatter<<<256, 256, 0, stream>>>(a1r, a1c, a1v, E1, gcur1, S1, nbins);
  bin_scatter<<<256, 256, 0, stream>>>(a2r, a2c, a2v, E2, gcur2, S2, nbins);
  csr_finalize<<<2 * nbins, 256, 0, stream>>>(
      S1, gbase1, rp1, E1s, E1, S2, gbase2, rp2, E2s, E2, N, nbins);

  // conv1 (gather, MLP=4) + fused BN -> bf16 h1b
  const int NW = 2048 * 4;
  conv1_gather<<<2048, 256, 0, stream>>>(
      hb, rp1, E1s, rp2, E2s, gamma, beta, mean, var, h1b, N, NW);

  // MFMA dense tail: out base + g1b/g2b in one pass
  dense_tail_mfma<<<(N + 127) / 128, 256, 0, stream>>>(
      hb, h1b, Wf, bf, out, g1b, g2b, N);

  // out += A1@g1 + A2@g2 (MLP=4, bf16 gather)
  final_add_kernel<<<2048, 256, 0, stream>>>(
      g1b, g2b, rp1, E1s, rp2, E2s, out, N, NW);
}

// Round 8
// 323.418 us; speedup vs baseline: 23.8754x; 1.1128x over previous
//
#include <hip/hip_runtime.h>

#define BN_EPS 1e-5f
#define MAXBINS 128   // bins of 512 rows; requires N <= 65536 (col packs in 16 bits)

typedef __attribute__((ext_vector_type(8))) short bf16x8;
typedef __attribute__((ext_vector_type(4))) float f32x4;

__device__ __forceinline__ ushort f2bf(float f) {
  uint u = __float_as_uint(f);
  u += 0x7fffu + ((u >> 16) & 1u);
  return (ushort)(u >> 16);
}
__device__ __forceinline__ float bf2f(ushort u) {
  return __uint_as_float((uint)u << 16);
}
__device__ __forceinline__ uint pack2bf(float a, float b) {
  return (uint)f2bf(a) | ((uint)f2bf(b) << 16);
}
// acc[0..7] += v * bf16x8(wv)
__device__ __forceinline__ void fma8(float acc[8], uint4 wv, float v) {
  acc[0] += v * __uint_as_float(wv.x << 16);
  acc[1] += v * __uint_as_float(wv.x & 0xffff0000u);
  acc[2] += v * __uint_as_float(wv.y << 16);
  acc[3] += v * __uint_as_float(wv.y & 0xffff0000u);
  acc[4] += v * __uint_as_float(wv.z << 16);
  acc[5] += v * __uint_as_float(wv.z & 0xffff0000u);
  acc[6] += v * __uint_as_float(wv.w << 16);
  acc[7] += v * __uint_as_float(wv.w & 0xffff0000u);
}

// ---------------------------------------------------------------------------
// Embed via MFMA: hb = bf16( relu(x @ W_embed + b) )  [N,512]@[512,64]
// 256 thr = 4 waves; wave = 32 rows; block = 128 rows. W staged bf16 in LDS
// transposed (Bt[col][k]); A-fragments read from global x with in-reg cvt.
// mfma_f32_16x16x32_bf16: A row=lane&15, k=(lane>>4)*8+j; C/D col=lane&15,
// row=(lane>>4)*4+reg.  (layout verified end-to-end in round 6)
// ---------------------------------------------------------------------------
__global__ __launch_bounds__(256) void embed_mfma(
    const float* __restrict__ x, const float* __restrict__ W,
    const float* __restrict__ b, ushort* __restrict__ hb, int N) {
  __shared__ ushort Bt[64][520];   // [col][k], 1040B row stride (16B aligned)
  const int tid  = threadIdx.x;
  const int wv   = tid >> 6;
  const int lane = tid & 63;
  const int m16  = lane & 15;
  const int kg   = lane >> 4;
  const int row0 = blockIdx.x * 128 + wv * 32;

  // stage W^T bf16: consecutive tid -> consecutive col (coalesced f32 reads)
  for (int idx = tid; idx < 512 * 64; idx += 256) {
    int k = idx >> 6, col = idx & 63;
    Bt[col][k] = f2bf(W[(size_t)k * 64 + col]);
  }
  __syncthreads();

  f32x4 acc[2][4];
#pragma unroll
  for (int i = 0; i < 2; ++i)
#pragma unroll
    for (int t = 0; t < 4; ++t) acc[i][t] = (f32x4){0.f, 0.f, 0.f, 0.f};

#pragma unroll 4
  for (int ks = 0; ks < 16; ++ks) {
    const int kk = ks * 32 + kg * 8;
    bf16x8 afr[2];
#pragma unroll
    for (int i = 0; i < 2; ++i) {
      int grow = row0 + i * 16 + m16;
      grow = (grow < N) ? grow : (N - 1);
      const float* ap = x + (size_t)grow * 512 + kk;
      float4 lo = *reinterpret_cast<const float4*>(ap);
      float4 hi = *reinterpret_cast<const float4*>(ap + 4);
      uint4 pk;
      pk.x = pack2bf(lo.x, lo.y); pk.y = pack2bf(lo.z, lo.w);
      pk.z = pack2bf(hi.x, hi.y); pk.w = pack2bf(hi.z, hi.w);
      afr[i] = *reinterpret_cast<const bf16x8*>(&pk);
    }
#pragma unroll
    for (int t = 0; t < 4; ++t) {
      bf16x8 bfr = *reinterpret_cast<const bf16x8*>(&Bt[t * 16 + m16][kk]);
      acc[0][t] = __builtin_amdgcn_mfma_f32_16x16x32_bf16(afr[0], bfr, acc[0][t], 0, 0, 0);
      acc[1][t] = __builtin_amdgcn_mfma_f32_16x16x32_bf16(afr[1], bfr, acc[1][t], 0, 0, 0);
    }
  }

  // epilogue: bias + relu + bf16 store
#pragma unroll
  for (int i = 0; i < 2; ++i) {
    const int rbase = row0 + i * 16 + kg * 4;
#pragma unroll
    for (int t = 0; t < 4; ++t) {
      const int col = t * 16 + m16;
      const float bias = b[col];
#pragma unroll
      for (int reg = 0; reg < 4; ++reg) {
        int gr = rbase + reg;
        if (gr < N)
          hb[(size_t)gr * 64 + col] = f2bf(fmaxf(acc[i][t][reg] + bias, 0.f));
      }
    }
  }
}

// ---------------------------------------------------------------------------
// CSR build, two-level binned (bin = row>>9)
// ---------------------------------------------------------------------------
__global__ __launch_bounds__(256) void bin_hist(
    const int* __restrict__ rows, int* __restrict__ gbin, int E, int nbins) {
  __shared__ int lb[MAXBINS];
  const int tid = threadIdx.x;
  if (tid < nbins) lb[tid] = 0;
  __syncthreads();
  const int stride = gridDim.x * blockDim.x;
  for (int i = blockIdx.x * blockDim.x + tid; i < E; i += stride)
    atomicAdd(&lb[rows[i] >> 9], 1);
  __syncthreads();
  if (tid < nbins && lb[tid]) atomicAdd(&gbin[tid], lb[tid]);
}

__device__ __forceinline__ void scan_bins_dev(
    const int* gbin, int* gbase, int* gcur, int nbins, int lane) {
  int carry = 0;
  for (int ch = 0; ch * 64 < nbins; ++ch) {
    int idx = ch * 64 + lane;
    int v = (idx < nbins) ? gbin[idx] : 0;
    int inc = v;
#pragma unroll
    for (int off = 1; off < 64; off <<= 1) {
      int y = __shfl_up(inc, off);
      if (lane >= off) inc += y;
    }
    int ex = carry + inc - v;
    if (idx < nbins) { gbase[idx] = ex; gcur[idx] = ex; }
    carry += __shfl(inc, 63);
  }
}

__global__ __launch_bounds__(64) void bin_scan(
    const int* __restrict__ gbin1, int* __restrict__ gbase1, int* __restrict__ gcur1,
    const int* __restrict__ gbin2, int* __restrict__ gbase2, int* __restrict__ gcur2,
    int nbins) {
  int lane = threadIdx.x;
  scan_bins_dev(gbin1, gbase1, gcur1, nbins, lane);
  scan_bins_dev(gbin2, gbase2, gcur2, nbins, lane);
}

// Staging record: int2( col | (row&511)<<16 , val_bits_f32 ).
__global__ __launch_bounds__(256) void bin_scatter(
    const int* __restrict__ rows, const int* __restrict__ cols,
    const float* __restrict__ vals, int E, int* __restrict__ gcur,
    int2* __restrict__ S, int nbins) {
  __shared__ int lcnt[MAXBINS];
  __shared__ int lcur[MAXBINS];
  const int tid = threadIdx.x;
  for (int e0 = blockIdx.x * 2048; e0 < E; e0 += gridDim.x * 2048) {
    int i0 = e0 + tid * 8;
    int r[8], c[8], vb[8];
    if (i0 + 8 <= E) {
      int4 a = *reinterpret_cast<const int4*>(rows + i0);
      int4 b = *reinterpret_cast<const int4*>(rows + i0 + 4);
      r[0]=a.x; r[1]=a.y; r[2]=a.z; r[3]=a.w; r[4]=b.x; r[5]=b.y; r[6]=b.z; r[7]=b.w;
      a = *reinterpret_cast<const int4*>(cols + i0);
      b = *reinterpret_cast<const int4*>(cols + i0 + 4);
      c[0]=a.x; c[1]=a.y; c[2]=a.z; c[3]=a.w; c[4]=b.x; c[5]=b.y; c[6]=b.z; c[7]=b.w;
      a = *reinterpret_cast<const int4*>(vals + i0);
      b = *reinterpret_cast<const int4*>(vals + i0 + 4);
      vb[0]=a.x; vb[1]=a.y; vb[2]=a.z; vb[3]=a.w; vb[4]=b.x; vb[5]=b.y; vb[6]=b.z; vb[7]=b.w;
    } else {
#pragma unroll
      for (int t = 0; t < 8; ++t) {
        int i = i0 + t;
        bool ok = i < E;
        r[t]  = ok ? rows[i] : -1;
        c[t]  = ok ? cols[i] : 0;
        vb[t] = ok ? __float_as_int(vals[i]) : 0;
      }
    }
    if (tid < nbins) lcnt[tid] = 0;
    __syncthreads();
#pragma unroll
    for (int t = 0; t < 8; ++t)
      if (r[t] >= 0) atomicAdd(&lcnt[r[t] >> 9], 1);
    __syncthreads();
    if (tid < nbins) {
      int n = lcnt[tid];
      lcur[tid] = n ? atomicAdd(&gcur[tid], n) : 0;
    }
    __syncthreads();
#pragma unroll
    for (int t = 0; t < 8; ++t) {
      if (r[t] >= 0) {
        int pos = atomicAdd(&lcur[r[t] >> 9], 1);
        S[pos] = make_int2(c[t] | ((r[t] & 511) << 16), vb[t]);
      }
    }
    __syncthreads();
  }
}

// One block per (graph, bin). Final edge record: uint( col | bf16(val)<<16 ).
__global__ __launch_bounds__(256) void csr_finalize(
    const int2* __restrict__ S1, const int* __restrict__ gbase1,
    int* __restrict__ rp1, uint* __restrict__ Eo1, int Etot1,
    const int2* __restrict__ S2, const int* __restrict__ gbase2,
    int* __restrict__ rp2, uint* __restrict__ Eo2, int Etot2,
    int N, int nbins) {
  __shared__ int cnt[512];
  __shared__ int cur[512];
  const int tid = threadIdx.x;
  const int b = blockIdx.x % nbins;
  const int g = blockIdx.x / nbins;
  const int2* S     = g ? S2 : S1;
  const int* gbase  = g ? gbase2 : gbase1;
  int* rp           = g ? rp2 : rp1;
  uint* Eo          = g ? Eo2 : Eo1;
  const int Etot    = g ? Etot2 : Etot1;

  const int base = gbase[b];
  const int end  = (b + 1 < nbins) ? gbase[b + 1] : Etot;
  const int r0   = b << 9;
  const int nrows = min(512, N - r0);

  for (int l = tid; l < 512; l += 256) cnt[l] = 0;
  __syncthreads();
  for (int j = base + tid; j < end; j += 256)
    atomicAdd(&cnt[S[j].x >> 16], 1);
  __syncthreads();
  if (tid < 64) {
    int carry = 0;
#pragma unroll
    for (int ch = 0; ch < 8; ++ch) {
      int v = cnt[ch * 64 + tid];
      int inc = v;
#pragma unroll
      for (int off = 1; off < 64; off <<= 1) {
        int y = __shfl_up(inc, off);
        if (tid >= off) inc += y;
      }
      inc += carry;
      cnt[ch * 64 + tid] = inc;
      carry = __shfl(inc, 63);
    }
  }
  __syncthreads();
  for (int l = tid; l < 512; l += 256)
    cur[l] = base + ((l > 0) ? cnt[l - 1] : 0);
  for (int l = tid; l < nrows; l += 256)
    rp[r0 + l + 1] = base + cnt[l];
  if (b == 0 && tid == 0) rp[0] = 0;
  __syncthreads();
  for (int j = base + tid; j < end; j += 256) {
    int2 m = S[j];
    int pos = atomicAdd(&cur[m.x >> 16], 1);
    Eo[pos] = (uint)(m.x & 0xffff) | ((uint)f2bf(__int_as_float(m.y)) << 16);
  }
}

// ---------------------------------------------------------------------------
// Conv1 gather + fused BN. One wave per row (grid-stride), 32-edge chunks,
// MLP=4 (4 independent masked meta loads + 4 independent gathers).
// ---------------------------------------------------------------------------
__global__ __launch_bounds__(256) void conv1_gather(
    const ushort* __restrict__ hb,
    const int* __restrict__ rp1, const uint* __restrict__ E1,
    const int* __restrict__ rp2, const uint* __restrict__ E2,
    const float* __restrict__ gamma, const float* __restrict__ beta,
    const float* __restrict__ mean, const float* __restrict__ var,
    ushort* __restrict__ h1b, int N, int nwaves) {
  const int wid  = (blockIdx.x * blockDim.x + threadIdx.x) >> 6;
  const int lane = threadIdx.x & 63;
  const int sub  = lane >> 3;
  const int q    = lane & 7;

  float sc1[8], sh1[8], sc2[8], sh2[8];
#pragma unroll
  for (int t4 = 0; t4 < 2; ++t4) {
    int f1 = q * 8 + t4 * 4;
    float4 gm = *reinterpret_cast<const float4*>(gamma + f1);
    float4 vr = *reinterpret_cast<const float4*>(var + f1);
    float4 mn = *reinterpret_cast<const float4*>(mean + f1);
    float4 bt = *reinterpret_cast<const float4*>(beta + f1);
    float s0 = gm.x * rsqrtf(vr.x + BN_EPS), s1 = gm.y * rsqrtf(vr.y + BN_EPS);
    float s2 = gm.z * rsqrtf(vr.z + BN_EPS), s3 = gm.w * rsqrtf(vr.w + BN_EPS);
    sc1[t4 * 4 + 0] = s0; sh1[t4 * 4 + 0] = bt.x - mn.x * s0;
    sc1[t4 * 4 + 1] = s1; sh1[t4 * 4 + 1] = bt.y - mn.y * s1;
    sc1[t4 * 4 + 2] = s2; sh1[t4 * 4 + 2] = bt.z - mn.z * s2;
    sc1[t4 * 4 + 3] = s3; sh1[t4 * 4 + 3] = bt.w - mn.w * s3;
    int f2 = 64 + f1;
    gm = *reinterpret_cast<const float4*>(gamma + f2);
    vr = *reinterpret_cast<const float4*>(var + f2);
    mn = *reinterpret_cast<const float4*>(mean + f2);
    bt = *reinterpret_cast<const float4*>(beta + f2);
    s0 = gm.x * rsqrtf(vr.x + BN_EPS); s1 = gm.y * rsqrtf(vr.y + BN_EPS);
    s2 = gm.z * rsqrtf(vr.z + BN_EPS); s3 = gm.w * rsqrtf(vr.w + BN_EPS);
    sc2[t4 * 4 + 0] = s0; sh2[t4 * 4 + 0] = bt.x - mn.x * s0;
    sc2[t4 * 4 + 1] = s1; sh2[t4 * 4 + 1] = bt.y - mn.y * s1;
    sc2[t4 * 4 + 2] = s2; sh2[t4 * 4 + 2] = bt.z - mn.z * s2;
    sc2[t4 * 4 + 3] = s3; sh2[t4 * 4 + 3] = bt.w - mn.w * s3;
  }

  for (int r = wid; r < N; r += nwaves) {
    float acc1[8] = {0, 0, 0, 0, 0, 0, 0, 0};
    float acc2[8] = {0, 0, 0, 0, 0, 0, 0, 0};
    {
      int s = rp1[r], e = rp1[r + 1];
      for (int j0 = s; j0 < e; j0 += 32) {
        int j = j0 + sub;
        uint m0 = (j      < e) ? E1[j]      : 0u;
        uint m1 = (j + 8  < e) ? E1[j + 8]  : 0u;
        uint m2 = (j + 16 < e) ? E1[j + 16] : 0u;
        uint m3 = (j + 24 < e) ? E1[j + 24] : 0u;
        uint4 w0 = *reinterpret_cast<const uint4*>(hb + (size_t)(m0 & 0xffffu) * 64 + q * 8);
        uint4 w1 = *reinterpret_cast<const uint4*>(hb + (size_t)(m1 & 0xffffu) * 64 + q * 8);
        uint4 w2 = *reinterpret_cast<const uint4*>(hb + (size_t)(m2 & 0xffffu) * 64 + q * 8);
        uint4 w3 = *reinterpret_cast<const uint4*>(hb + (size_t)(m3 & 0xffffu) * 64 + q * 8);
        fma8(acc1, w0, bf2f((ushort)(m0 >> 16)));
        fma8(acc1, w1, bf2f((ushort)(m1 >> 16)));
        fma8(acc1, w2, bf2f((ushort)(m2 >> 16)));
        fma8(acc1, w3, bf2f((ushort)(m3 >> 16)));
      }
    }
    {
      int s = rp2[r], e = rp2[r + 1];
      for (int j0 = s; j0 < e; j0 += 32) {
        int j = j0 + sub;
        uint m0 = (j      < e) ? E2[j]      : 0u;
        uint m1 = (j + 8  < e) ? E2[j + 8]  : 0u;
        uint m2 = (j + 16 < e) ? E2[j + 16] : 0u;
        uint m3 = (j + 24 < e) ? E2[j + 24] : 0u;
        uint4 w0 = *reinterpret_cast<const uint4*>(hb + (size_t)(m0 & 0xffffu) * 64 + q * 8);
        uint4 w1 = *reinterpret_cast<const uint4*>(hb + (size_t)(m1 & 0xffffu) * 64 + q * 8);
        uint4 w2 = *reinterpret_cast<const uint4*>(hb + (size_t)(m2 & 0xffffu) * 64 + q * 8);
        uint4 w3 = *reinterpret_cast<const uint4*>(hb + (size_t)(m3 & 0xffffu) * 64 + q * 8);
        fma8(acc2, w0, bf2f((ushort)(m0 >> 16)));
        fma8(acc2, w1, bf2f((ushort)(m1 >> 16)));
        fma8(acc2, w2, bf2f((ushort)(m2 >> 16)));
        fma8(acc2, w3, bf2f((ushort)(m3 >> 16)));
      }
    }
#pragma unroll
    for (int mask = 8; mask <= 32; mask <<= 1) {
#pragma unroll
      for (int t = 0; t < 8; ++t) {
        acc1[t] += __shfl_xor(acc1[t], mask);
        acc2[t] += __shfl_xor(acc2[t], mask);
      }
    }
    if (lane < 8) {
      uint4 p1, p2;
      p1.x = pack2bf(acc1[0] * sc1[0] + sh1[0], acc1[1] * sc1[1] + sh1[1]);
      p1.y = pack2bf(acc1[2] * sc1[2] + sh1[2], acc1[3] * sc1[3] + sh1[3]);
      p1.z = pack2bf(acc1[4] * sc1[4] + sh1[4], acc1[5] * sc1[5] + sh1[5]);
      p1.w = pack2bf(acc1[6] * sc1[6] + sh1[6], acc1[7] * sc1[7] + sh1[7]);
      p2.x = pack2bf(acc2[0] * sc2[0] + sh2[0], acc2[1] * sc2[1] + sh2[1]);
      p2.y = pack2bf(acc2[2] * sc2[2] + sh2[2], acc2[3] * sc2[3] + sh2[3]);
      p2.z = pack2bf(acc2[4] * sc2[4] + sh2[4], acc2[5] * sc2[5] + sh2[5]);
      p2.w = pack2bf(acc2[6] * sc2[6] + sh2[6], acc2[7] * sc2[7] + sh2[7]);
      ushort* dst = h1b + (size_t)r * 128 + q * 8;
      *reinterpret_cast<uint4*>(dst)      = p1;
      *reinterpret_cast<uint4*>(dst + 64) = p2;
    }
  }
}

// ---------------------------------------------------------------------------
// MFMA dense tail: A = [hb | h1b] (N x 192 bf16), Bt staged in LDS.
//   cols 0:40 -> out (f32,+bias); 40:80 -> g1b; 80:120 -> g2b (bf16)
// ---------------------------------------------------------------------------
__global__ __launch_bounds__(256) void dense_tail_mfma(
    const ushort* __restrict__ hb, const ushort* __restrict__ h1b,
    const float* __restrict__ Wf, const float* __restrict__ bfin,
    float* __restrict__ out, ushort* __restrict__ g1b, ushort* __restrict__ g2b,
    int N) {
  __shared__ ushort Bt[128][200];   // [col][k], 400B row stride
  const int tid  = threadIdx.x;
  const int wv   = tid >> 6;
  const int lane = tid & 63;
  const int m16  = lane & 15;
  const int kg   = lane >> 4;
  const int row0 = blockIdx.x * 128;

  for (int idx = tid; idx < 192 * 128; idx += 256) {
    int k = idx >> 7, col = idx & 127;
    float v = 0.f;
    if (col < 40)       v = Wf[(size_t)k * 40 + col];
    else if (col < 80)  { if (k >= 64) v = Wf[(size_t)(128 + k) * 40 + (col - 40)]; }
    else if (col < 120) { if (k >= 64) v = Wf[(size_t)(256 + k) * 40 + (col - 80)]; }
    Bt[col][k] = f2bf(v);
  }
  __syncthreads();

  f32x4 acc[2][8];
#pragma unroll
  for (int i = 0; i < 2; ++i)
#pragma unroll
    for (int t = 0; t < 8; ++t) acc[i][t] = (f32x4){0.f, 0.f, 0.f, 0.f};

#pragma unroll
  for (int ks = 0; ks < 6; ++ks) {
    const int kk = ks * 32 + kg * 8;
    bf16x8 afr[2];
#pragma unroll
    for (int i = 0; i < 2; ++i) {
      int grow = row0 + wv * 32 + i * 16 + m16;
      grow = (grow < N) ? grow : (N - 1);
      const ushort* ap = (kk < 64) ? hb + (size_t)grow * 64 + kk
                                   : h1b + (size_t)grow * 128 + (kk - 64);
      afr[i] = *reinterpret_cast<const bf16x8*>(ap);
    }
#pragma unroll
    for (int t = 0; t < 8; ++t) {
      bf16x8 bfr = *reinterpret_cast<const bf16x8*>(&Bt[t * 16 + m16][kk]);
      acc[0][t] = __builtin_amdgcn_mfma_f32_16x16x32_bf16(afr[0], bfr, acc[0][t], 0, 0, 0);
      acc[1][t] = __builtin_amdgcn_mfma_f32_16x16x32_bf16(afr[1], bfr, acc[1][t], 0, 0, 0);
    }
  }

#pragma unroll
  for (int i = 0; i < 2; ++i) {
    const int rbase = row0 + wv * 32 + i * 16 + kg * 4;
#pragma unroll
    for (int t = 0; t < 8; ++t) {
      const int col = t * 16 + m16;
      if (col >= 120) continue;
      const float bias = (col < 40) ? bfin[col] : 0.f;
#pragma unroll
      for (int reg = 0; reg < 4; ++reg) {
        int gr = rbase + reg;
        if (gr < N) {
          float v = acc[i][t][reg];
          if (col < 40)       out[(size_t)gr * 40 + col] = v + bias;
          else if (col < 80)  g1b[(size_t)gr * 40 + (col - 40)] = f2bf(v);
          else                g2b[(size_t)gr * 40 + (col - 80)] = f2bf(v);
        }
      }
    }
  }
}

// ---------------------------------------------------------------------------
// Final add: out[r,:] += sum_{adj1} v*g1b[c,:] + sum_{adj2} v*g2b[c,:]
// 32-edge chunks, MLP=4, 8-lane subgroups; lanes q<5 carry real data.
// ---------------------------------------------------------------------------
__global__ __launch_bounds__(256) void final_add_kernel(
    const ushort* __restrict__ g1b, const ushort* __restrict__ g2b,
    const int* __restrict__ rp1, const uint* __restrict__ E1,
    const int* __restrict__ rp2, const uint* __restrict__ E2,
    float* __restrict__ out, int N, int nwaves) {
  const int wid  = (blockIdx.x * blockDim.x + threadIdx.x) >> 6;
  const int lane = threadIdx.x & 63;
  const int sub  = lane >> 3;
  const int q    = lane & 7;
  const int off  = (q < 5) ? q * 8 : 0;

  for (int r = wid; r < N; r += nwaves) {
    float a1[8] = {0, 0, 0, 0, 0, 0, 0, 0};
    float a2[8] = {0, 0, 0, 0, 0, 0, 0, 0};
    {
      int s = rp1[r], e = rp1[r + 1];
      for (int j0 = s; j0 < e; j0 += 32) {
        int j = j0 + sub;
        uint m0 = (j      < e) ? E1[j]      : 0u;
        uint m1 = (j + 8  < e) ? E1[j + 8]  : 0u;
        uint m2 = (j + 16 < e) ? E1[j + 16] : 0u;
        uint m3 = (j + 24 < e) ? E1[j + 24] : 0u;
        uint4 w0 = *reinterpret_cast<const uint4*>(g1b + (size_t)(m0 & 0xffffu) * 40 + off);
        uint4 w1 = *reinterpret_cast<const uint4*>(g1b + (size_t)(m1 & 0xffffu) * 40 + off);
        uint4 w2 = *reinterpret_cast<const uint4*>(g1b + (size_t)(m2 & 0xffffu) * 40 + off);
        uint4 w3 = *reinterpret_cast<const uint4*>(g1b + (size_t)(m3 & 0xffffu) * 40 + off);
        fma8(a1, w0, bf2f((ushort)(m0 >> 16)));
        fma8(a1, w1, bf2f((ushort)(m1 >> 16)));
        fma8(a1, w2, bf2f((ushort)(m2 >> 16)));
        fma8(a1, w3, bf2f((ushort)(m3 >> 16)));
      }
    }
    {
      int s = rp2[r], e = rp2[r + 1];
      for (int j0 = s; j0 < e; j0 += 32) {
        int j = j0 + sub;
        uint m0 = (j      < e) ? E2[j]      : 0u;
        uint m1 = (j + 8  < e) ? E2[j + 8]  : 0u;
        uint m2 = (j + 16 < e) ? E2[j + 16] : 0u;
        uint m3 = (j + 24 < e) ? E2[j + 24] : 0u;
        uint4 w0 = *reinterpret_cast<const uint4*>(g2b + (size_t)(m0 & 0xffffu) * 40 + off);
        uint4 w1 = *reinterpret_cast<const uint4*>(g2b + (size_t)(m1 & 0xffffu) * 40 + off);
        uint4 w2 = *reinterpret_cast<const uint4*>(g2b + (size_t)(m2 & 0xffffu) * 40 + off);
        uint4 w3 = *reinterpret_cast<const uint4*>(g2b + (size_t)(m3 & 0xffffu) * 40 + off);
        fma8(a2, w0, bf2f((ushort)(m0 >> 16)));
        fma8(a2, w1, bf2f((ushort)(m1 >> 16)));
        fma8(a2, w2, bf2f((ushort)(m2 >> 16)));
        fma8(a2, w3, bf2f((ushort)(m3 >> 16)));
      }
    }
#pragma unroll
    for (int mask = 8; mask <= 32; mask <<= 1) {
#pragma unroll
      for (int t = 0; t < 8; ++t) {
        a1[t] += __shfl_xor(a1[t], mask);
        a2[t] += __shfl_xor(a2[t], mask);
      }
    }
    if (lane < 5) {
      float* p = out + (size_t)r * 40 + lane * 8;
      float4 o0 = *reinterpret_cast<const float4*>(p);
      float4 o1 = *reinterpret_cast<const float4*>(p + 4);
      o0.x += a1[0] + a2[0]; o0.y += a1[1] + a2[1];
      o0.z += a1[2] + a2[2]; o0.w += a1[3] + a2[3];
      o1.x += a1[4] + a2[4]; o1.y += a1[5] + a2[5];
      o1.z += a1[6] + a2[6]; o1.w += a1[7] + a2[7];
      *reinterpret_cast<float4*>(p)     = o0;
      *reinterpret_cast<float4*>(p + 4) = o1;
    }
  }
}

// ---------------------------------------------------------------------------
extern "C" void kernel_launch(void* const* d_in, const int* in_sizes, int n_in,
                              void* d_out, int out_size, void* d_ws, size_t ws_size,
                              hipStream_t stream) {
  const float* x     = (const float*)d_in[0];
  const int*   a1r   = (const int*)d_in[1];
  const int*   a1c   = (const int*)d_in[2];
  const float* a1v   = (const float*)d_in[3];
  const int*   a2r   = (const int*)d_in[4];
  const int*   a2c   = (const int*)d_in[5];
  const float* a2v   = (const float*)d_in[6];
  const float* We    = (const float*)d_in[7];
  const float* be    = (const float*)d_in[8];
  const float* gamma = (const float*)d_in[9];
  const float* beta  = (const float*)d_in[10];
  const float* mean  = (const float*)d_in[11];
  const float* var   = (const float*)d_in[12];
  const float* Wf    = (const float*)d_in[13];
  const float* bf    = (const float*)d_in[14];
  float* out = (float*)d_out;

  const int N  = in_sizes[0] / 512;
  const int E1 = in_sizes[1];
  const int E2 = in_sizes[4];
  const int nbins = (N + 511) >> 9;   // requires N <= 65536

  char* p = (char*)d_ws;
  auto alloc = [&](size_t bytes) {
    char* q = p; p += (bytes + 255) & ~(size_t)255; return q;
  };
  ushort* hb   = (ushort*)alloc((size_t)N * 64 * 2);
  ushort* h1b  = (ushort*)alloc((size_t)N * 128 * 2);
  ushort* g1b  = (ushort*)alloc((size_t)N * 40 * 2);
  ushort* g2b  = (ushort*)alloc((size_t)N * 40 * 2);
  int*    rp1  = (int*)   alloc(((size_t)N + 1) * 4);
  int*    rp2  = (int*)   alloc(((size_t)N + 1) * 4);
  uint*   E1s  = (uint*)  alloc((size_t)E1 * 4);
  uint*   E2s  = (uint*)  alloc((size_t)E2 * 4);
  int2*   S1   = (int2*)  alloc((size_t)E1 * 8);
  int2*   S2   = (int2*)  alloc((size_t)E2 * 8);
  int*    gbin1  = (int*) alloc(MAXBINS * 4);
  int*    gbin2  = (int*) alloc(MAXBINS * 4);
  int*    gbase1 = (int*) alloc(MAXBINS * 4);
  int*    gbase2 = (int*) alloc(MAXBINS * 4);
  int*    gcur1  = (int*) alloc(MAXBINS * 4);
  int*    gcur2  = (int*) alloc(MAXBINS * 4);

  hipMemsetAsync(gbin1, 0, (size_t)2 * MAXBINS * 4 + 256, stream);

  // embed via MFMA (independent of CSR build)
  embed_mfma<<<(N + 127) / 128, 256, 0, stream>>>(x, We, be, hb, N);

  // binned CSR build
  bin_hist<<<256, 256, 0, stream>>>(a1r, gbin1, E1, nbins);
  bin_hist<<<256, 256, 0, stream>>>(a2r, gbin2, E2, nbins);
  bin_scan<<<1, 64, 0, stream>>>(gbin1, gbase1, gcur1, gbin2, gbase2, gcur2, nbins);
  bin_scatter<<<256, 256, 0, stream>>>(a1r, a1c, a1v, E1, gcur1, S1, nbins);
  bin_scatter<<<256, 256, 0, stream>>>(a2r, a2c, a2v, E2, gcur2, S2, nbins);
  csr_finalize<<<2 * nbins, 256, 0, stream>>>(
      S1, gbase1, rp1, E1s, E1, S2, gbase2, rp2, E2s, E2, N, nbins);

  // conv1 (gather, MLP=4) + fused BN -> bf16 h1b
  const int NW = 2048 * 4;
  conv1_gather<<<2048, 256, 0, stream>>>(
      hb, rp1, E1s, rp2, E2s, gamma, beta, mean, var, h1b, N, NW);

  // MFMA dense tail: out base + g1b/g2b in one pass
  dense_tail_mfma<<<(N + 127) / 128, 256, 0, stream>>>(
      hb, h1b, Wf, bf, out, g1b, g2b, N);

  // out += A1@g1 + A2@g2 (MLP=4, bf16 gather)
  final_add_kernel<<<2048, 256, 0, stream>>>(
      g1b, g2b, rp1, E1s, rp2, E2s, out, N, NW);
}

// Round 9
// 303.620 us; speedup vs baseline: 25.4322x; 1.0652x over previous
//
#include <hip/hip_runtime.h>

#define BN_EPS 1e-5f
#define MAXBINS 128   // bins of 512 rows; requires N <= 65536 (col packs in 16 bits)

typedef __attribute__((ext_vector_type(8))) short bf16x8;
typedef __attribute__((ext_vector_type(4))) float f32x4;

__device__ __forceinline__ ushort f2bf(float f) {
  uint u = __float_as_uint(f);
  u += 0x7fffu + ((u >> 16) & 1u);
  return (ushort)(u >> 16);
}
__device__ __forceinline__ float bf2f(ushort u) {
  return __uint_as_float((uint)u << 16);
}
__device__ __forceinline__ uint pack2bf(float a, float b) {
  return (uint)f2bf(a) | ((uint)f2bf(b) << 16);
}
// acc[0..7] += v * bf16x8(wv)
__device__ __forceinline__ void fma8(float acc[8], uint4 wv, float v) {
  acc[0] += v * __uint_as_float(wv.x << 16);
  acc[1] += v * __uint_as_float(wv.x & 0xffff0000u);
  acc[2] += v * __uint_as_float(wv.y << 16);
  acc[3] += v * __uint_as_float(wv.y & 0xffff0000u);
  acc[4] += v * __uint_as_float(wv.z << 16);
  acc[5] += v * __uint_as_float(wv.z & 0xffff0000u);
  acc[6] += v * __uint_as_float(wv.w << 16);
  acc[7] += v * __uint_as_float(wv.w & 0xffff0000u);
}

// ---------------------------------------------------------------------------
// One-time weight transpose to bf16 (L2-resident broadcast tables):
//   Wet[col][k] : col<64,  k<512  = We^T
//   Wtg[col][k] : col<128, k<192  = [Wf[0:192] | Wf[192:320](k>=64) |
//                                    Wf[320:448](k>=64) | 0-pad]^T
// ---------------------------------------------------------------------------
__global__ __launch_bounds__(256) void prep_weights(
    const float* __restrict__ We, const float* __restrict__ Wf,
    ushort* __restrict__ Wet, ushort* __restrict__ Wtg) {
  int i = blockIdx.x * 256 + threadIdx.x;
  if (i < 32768) {
    int col = i >> 9, k = i & 511;     // consecutive k -> coalesced writes
    Wet[(size_t)col * 512 + k] = f2bf(We[(size_t)k * 64 + col]);
  } else if (i < 32768 + 24576) {
    int j = i - 32768;
    int col = j / 192, k = j % 192;
    float v = 0.f;
    if (col < 40)       v = Wf[(size_t)k * 40 + col];
    else if (col < 80)  { if (k >= 64) v = Wf[(size_t)(128 + k) * 40 + (col - 40)]; }
    else if (col < 120) { if (k >= 64) v = Wf[(size_t)(256 + k) * 40 + (col - 80)]; }
    Wtg[(size_t)col * 192 + k] = f2bf(v);
  }
}

// ---------------------------------------------------------------------------
// Embed via MFMA, no LDS: hb = bf16( relu(x @ We + b) )  [N,512]@[512,64]
// 4 waves x 32 rows = 128 rows/block. A from global x (in-reg f32->bf16),
// B-fragments straight from Wet (L2-hot). No barriers.
// ---------------------------------------------------------------------------
__global__ __launch_bounds__(256) void embed_mfma(
    const float* __restrict__ x, const ushort* __restrict__ Wet,
    const float* __restrict__ b, ushort* __restrict__ hb, int N) {
  const int tid  = threadIdx.x;
  const int wv   = tid >> 6;
  const int lane = tid & 63;
  const int m16  = lane & 15;
  const int kg   = lane >> 4;
  const int row0 = blockIdx.x * 128 + wv * 32;

  f32x4 acc[2][4];
#pragma unroll
  for (int i = 0; i < 2; ++i)
#pragma unroll
    for (int t = 0; t < 4; ++t) acc[i][t] = (f32x4){0.f, 0.f, 0.f, 0.f};

#pragma unroll 4
  for (int ks = 0; ks < 16; ++ks) {
    const int kk = ks * 32 + kg * 8;
    bf16x8 afr[2];
#pragma unroll
    for (int i = 0; i < 2; ++i) {
      int grow = row0 + i * 16 + m16;
      grow = (grow < N) ? grow : (N - 1);
      const float* ap = x + (size_t)grow * 512 + kk;
      float4 lo = *reinterpret_cast<const float4*>(ap);
      float4 hi = *reinterpret_cast<const float4*>(ap + 4);
      uint4 pk;
      pk.x = pack2bf(lo.x, lo.y); pk.y = pack2bf(lo.z, lo.w);
      pk.z = pack2bf(hi.x, hi.y); pk.w = pack2bf(hi.z, hi.w);
      afr[i] = *reinterpret_cast<const bf16x8*>(&pk);
    }
#pragma unroll
    for (int t = 0; t < 4; ++t) {
      bf16x8 bfr = *reinterpret_cast<const bf16x8*>(
          Wet + (size_t)(t * 16 + m16) * 512 + kk);
      acc[0][t] = __builtin_amdgcn_mfma_f32_16x16x32_bf16(afr[0], bfr, acc[0][t], 0, 0, 0);
      acc[1][t] = __builtin_amdgcn_mfma_f32_16x16x32_bf16(afr[1], bfr, acc[1][t], 0, 0, 0);
    }
  }

#pragma unroll
  for (int i = 0; i < 2; ++i) {
    const int rbase = row0 + i * 16 + kg * 4;
#pragma unroll
    for (int t = 0; t < 4; ++t) {
      const int col = t * 16 + m16;
      const float bias = b[col];
#pragma unroll
      for (int reg = 0; reg < 4; ++reg) {
        int gr = rbase + reg;
        if (gr < N)
          hb[(size_t)gr * 64 + col] = f2bf(fmaxf(acc[i][t][reg] + bias, 0.f));
      }
    }
  }
}

// ---------------------------------------------------------------------------
// CSR build, two-level binned (bin = row>>9)
// ---------------------------------------------------------------------------
__global__ __launch_bounds__(256) void bin_hist(
    const int* __restrict__ rows, int* __restrict__ gbin, int E, int nbins) {
  __shared__ int lb[MAXBINS];
  const int tid = threadIdx.x;
  if (tid < nbins) lb[tid] = 0;
  __syncthreads();
  const int stride = gridDim.x * blockDim.x;
  for (int i = blockIdx.x * blockDim.x + tid; i < E; i += stride)
    atomicAdd(&lb[rows[i] >> 9], 1);
  __syncthreads();
  if (tid < nbins && lb[tid]) atomicAdd(&gbin[tid], lb[tid]);
}

__device__ __forceinline__ void scan_bins_dev(
    const int* gbin, int* gbase, int* gcur, int nbins, int lane) {
  int carry = 0;
  for (int ch = 0; ch * 64 < nbins; ++ch) {
    int idx = ch * 64 + lane;
    int v = (idx < nbins) ? gbin[idx] : 0;
    int inc = v;
#pragma unroll
    for (int off = 1; off < 64; off <<= 1) {
      int y = __shfl_up(inc, off);
      if (lane >= off) inc += y;
    }
    int ex = carry + inc - v;
    if (idx < nbins) { gbase[idx] = ex; gcur[idx] = ex; }
    carry += __shfl(inc, 63);
  }
}

__global__ __launch_bounds__(64) void bin_scan(
    const int* __restrict__ gbin1, int* __restrict__ gbase1, int* __restrict__ gcur1,
    const int* __restrict__ gbin2, int* __restrict__ gbase2, int* __restrict__ gcur2,
    int nbins) {
  int lane = threadIdx.x;
  scan_bins_dev(gbin1, gbase1, gcur1, nbins, lane);
  scan_bins_dev(gbin2, gbase2, gcur2, nbins, lane);
}

// Staging record: int2( col | (row&511)<<16 , val_bits_f32 ).
__global__ __launch_bounds__(256) void bin_scatter(
    const int* __restrict__ rows, const int* __restrict__ cols,
    const float* __restrict__ vals, int E, int* __restrict__ gcur,
    int2* __restrict__ S, int nbins) {
  __shared__ int lcnt[MAXBINS];
  __shared__ int lcur[MAXBINS];
  const int tid = threadIdx.x;
  for (int e0 = blockIdx.x * 2048; e0 < E; e0 += gridDim.x * 2048) {
    int i0 = e0 + tid * 8;
    int r[8], c[8], vb[8];
    if (i0 + 8 <= E) {
      int4 a = *reinterpret_cast<const int4*>(rows + i0);
      int4 b = *reinterpret_cast<const int4*>(rows + i0 + 4);
      r[0]=a.x; r[1]=a.y; r[2]=a.z; r[3]=a.w; r[4]=b.x; r[5]=b.y; r[6]=b.z; r[7]=b.w;
      a = *reinterpret_cast<const int4*>(cols + i0);
      b = *reinterpret_cast<const int4*>(cols + i0 + 4);
      c[0]=a.x; c[1]=a.y; c[2]=a.z; c[3]=a.w; c[4]=b.x; c[5]=b.y; c[6]=b.z; c[7]=b.w;
      a = *reinterpret_cast<const int4*>(vals + i0);
      b = *reinterpret_cast<const int4*>(vals + i0 + 4);
      vb[0]=a.x; vb[1]=a.y; vb[2]=a.z; vb[3]=a.w; vb[4]=b.x; vb[5]=b.y; vb[6]=b.z; vb[7]=b.w;
    } else {
#pragma unroll
      for (int t = 0; t < 8; ++t) {
        int i = i0 + t;
        bool ok = i < E;
        r[t]  = ok ? rows[i] : -1;
        c[t]  = ok ? cols[i] : 0;
        vb[t] = ok ? __float_as_int(vals[i]) : 0;
      }
    }
    if (tid < nbins) lcnt[tid] = 0;
    __syncthreads();
#pragma unroll
    for (int t = 0; t < 8; ++t)
      if (r[t] >= 0) atomicAdd(&lcnt[r[t] >> 9], 1);
    __syncthreads();
    if (tid < nbins) {
      int n = lcnt[tid];
      lcur[tid] = n ? atomicAdd(&gcur[tid], n) : 0;
    }
    __syncthreads();
#pragma unroll
    for (int t = 0; t < 8; ++t) {
      if (r[t] >= 0) {
        int pos = atomicAdd(&lcur[r[t] >> 9], 1);
        S[pos] = make_int2(c[t] | ((r[t] & 511) << 16), vb[t]);
      }
    }
    __syncthreads();
  }
}

// One block per (graph, bin). Final edge record: uint( col | bf16(val)<<16 ).
__global__ __launch_bounds__(256) void csr_finalize(
    const int2* __restrict__ S1, const int* __restrict__ gbase1,
    int* __restrict__ rp1, uint* __restrict__ Eo1, int Etot1,
    const int2* __restrict__ S2, const int* __restrict__ gbase2,
    int* __restrict__ rp2, uint* __restrict__ Eo2, int Etot2,
    int N, int nbins) {
  __shared__ int cnt[512];
  __shared__ int cur[512];
  const int tid = threadIdx.x;
  const int b = blockIdx.x % nbins;
  const int g = blockIdx.x / nbins;
  const int2* S     = g ? S2 : S1;
  const int* gbase  = g ? gbase2 : gbase1;
  int* rp           = g ? rp2 : rp1;
  uint* Eo          = g ? Eo2 : Eo1;
  const int Etot    = g ? Etot2 : Etot1;

  const int base = gbase[b];
  const int end  = (b + 1 < nbins) ? gbase[b + 1] : Etot;
  const int r0   = b << 9;
  const int nrows = min(512, N - r0);

  for (int l = tid; l < 512; l += 256) cnt[l] = 0;
  __syncthreads();
  for (int j = base + tid; j < end; j += 256)
    atomicAdd(&cnt[S[j].x >> 16], 1);
  __syncthreads();
  if (tid < 64) {
    int carry = 0;
#pragma unroll
    for (int ch = 0; ch < 8; ++ch) {
      int v = cnt[ch * 64 + tid];
      int inc = v;
#pragma unroll
      for (int off = 1; off < 64; off <<= 1) {
        int y = __shfl_up(inc, off);
        if (tid >= off) inc += y;
      }
      inc += carry;
      cnt[ch * 64 + tid] = inc;
      carry = __shfl(inc, 63);
    }
  }
  __syncthreads();
  for (int l = tid; l < 512; l += 256)
    cur[l] = base + ((l > 0) ? cnt[l - 1] : 0);
  for (int l = tid; l < nrows; l += 256)
    rp[r0 + l + 1] = base + cnt[l];
  if (b == 0 && tid == 0) rp[0] = 0;
  __syncthreads();
  for (int j = base + tid; j < end; j += 256) {
    int2 m = S[j];
    int pos = atomicAdd(&cur[m.x >> 16], 1);
    Eo[pos] = (uint)(m.x & 0xffff) | ((uint)f2bf(__int_as_float(m.y)) << 16);
  }
}

// ---------------------------------------------------------------------------
// Conv1 gather + fused BN. One wave per row (grid-stride), 32-edge chunks,
// MLP=4 (4 independent masked meta loads + 4 independent gathers).
// ---------------------------------------------------------------------------
__global__ __launch_bounds__(256) void conv1_gather(
    const ushort* __restrict__ hb,
    const int* __restrict__ rp1, const uint* __restrict__ E1,
    const int* __restrict__ rp2, const uint* __restrict__ E2,
    const float* __restrict__ gamma, const float* __restrict__ beta,
    const float* __restrict__ mean, const float* __restrict__ var,
    ushort* __restrict__ h1b, int N, int nwaves) {
  const int wid  = (blockIdx.x * blockDim.x + threadIdx.x) >> 6;
  const int lane = threadIdx.x & 63;
  const int sub  = lane >> 3;
  const int q    = lane & 7;

  float sc1[8], sh1[8], sc2[8], sh2[8];
#pragma unroll
  for (int t4 = 0; t4 < 2; ++t4) {
    int f1 = q * 8 + t4 * 4;
    float4 gm = *reinterpret_cast<const float4*>(gamma + f1);
    float4 vr = *reinterpret_cast<const float4*>(var + f1);
    float4 mn = *reinterpret_cast<const float4*>(mean + f1);
    float4 bt = *reinterpret_cast<const float4*>(beta + f1);
    float s0 = gm.x * rsqrtf(vr.x + BN_EPS), s1 = gm.y * rsqrtf(vr.y + BN_EPS);
    float s2 = gm.z * rsqrtf(vr.z + BN_EPS), s3 = gm.w * rsqrtf(vr.w + BN_EPS);
    sc1[t4 * 4 + 0] = s0; sh1[t4 * 4 + 0] = bt.x - mn.x * s0;
    sc1[t4 * 4 + 1] = s1; sh1[t4 * 4 + 1] = bt.y - mn.y * s1;
    sc1[t4 * 4 + 2] = s2; sh1[t4 * 4 + 2] = bt.z - mn.z * s2;
    sc1[t4 * 4 + 3] = s3; sh1[t4 * 4 + 3] = bt.w - mn.w * s3;
    int f2 = 64 + f1;
    gm = *reinterpret_cast<const float4*>(gamma + f2);
    vr = *reinterpret_cast<const float4*>(var + f2);
    mn = *reinterpret_cast<const float4*>(mean + f2);
    bt = *reinterpret_cast<const float4*>(beta + f2);
    s0 = gm.x * rsqrtf(vr.x + BN_EPS); s1 = gm.y * rsqrtf(vr.y + BN_EPS);
    s2 = gm.z * rsqrtf(vr.z + BN_EPS); s3 = gm.w * rsqrtf(vr.w + BN_EPS);
    sc2[t4 * 4 + 0] = s0; sh2[t4 * 4 + 0] = bt.x - mn.x * s0;
    sc2[t4 * 4 + 1] = s1; sh2[t4 * 4 + 1] = bt.y - mn.y * s1;
    sc2[t4 * 4 + 2] = s2; sh2[t4 * 4 + 2] = bt.z - mn.z * s2;
    sc2[t4 * 4 + 3] = s3; sh2[t4 * 4 + 3] = bt.w - mn.w * s3;
  }

  for (int r = wid; r < N; r += nwaves) {
    float acc1[8] = {0, 0, 0, 0, 0, 0, 0, 0};
    float acc2[8] = {0, 0, 0, 0, 0, 0, 0, 0};
    {
      int s = rp1[r], e = rp1[r + 1];
      for (int j0 = s; j0 < e; j0 += 32) {
        int j = j0 + sub;
        uint m0 = (j      < e) ? E1[j]      : 0u;
        uint m1 = (j + 8  < e) ? E1[j + 8]  : 0u;
        uint m2 = (j + 16 < e) ? E1[j + 16] : 0u;
        uint m3 = (j + 24 < e) ? E1[j + 24] : 0u;
        uint4 w0 = *reinterpret_cast<const uint4*>(hb + (size_t)(m0 & 0xffffu) * 64 + q * 8);
        uint4 w1 = *reinterpret_cast<const uint4*>(hb + (size_t)(m1 & 0xffffu) * 64 + q * 8);
        uint4 w2 = *reinterpret_cast<const uint4*>(hb + (size_t)(m2 & 0xffffu) * 64 + q * 8);
        uint4 w3 = *reinterpret_cast<const uint4*>(hb + (size_t)(m3 & 0xffffu) * 64 + q * 8);
        fma8(acc1, w0, bf2f((ushort)(m0 >> 16)));
        fma8(acc1, w1, bf2f((ushort)(m1 >> 16)));
        fma8(acc1, w2, bf2f((ushort)(m2 >> 16)));
        fma8(acc1, w3, bf2f((ushort)(m3 >> 16)));
      }
    }
    {
      int s = rp2[r], e = rp2[r + 1];
      for (int j0 = s; j0 < e; j0 += 32) {
        int j = j0 + sub;
        uint m0 = (j      < e) ? E2[j]      : 0u;
        uint m1 = (j + 8  < e) ? E2[j + 8]  : 0u;
        uint m2 = (j + 16 < e) ? E2[j + 16] : 0u;
        uint m3 = (j + 24 < e) ? E2[j + 24] : 0u;
        uint4 w0 = *reinterpret_cast<const uint4*>(hb + (size_t)(m0 & 0xffffu) * 64 + q * 8);
        uint4 w1 = *reinterpret_cast<const uint4*>(hb + (size_t)(m1 & 0xffffu) * 64 + q * 8);
        uint4 w2 = *reinterpret_cast<const uint4*>(hb + (size_t)(m2 & 0xffffu) * 64 + q * 8);
        uint4 w3 = *reinterpret_cast<const uint4*>(hb + (size_t)(m3 & 0xffffu) * 64 + q * 8);
        fma8(acc2, w0, bf2f((ushort)(m0 >> 16)));
        fma8(acc2, w1, bf2f((ushort)(m1 >> 16)));
        fma8(acc2, w2, bf2f((ushort)(m2 >> 16)));
        fma8(acc2, w3, bf2f((ushort)(m3 >> 16)));
      }
    }
#pragma unroll
    for (int mask = 8; mask <= 32; mask <<= 1) {
#pragma unroll
      for (int t = 0; t < 8; ++t) {
        acc1[t] += __shfl_xor(acc1[t], mask);
        acc2[t] += __shfl_xor(acc2[t], mask);
      }
    }
    if (lane < 8) {
      uint4 p1, p2;
      p1.x = pack2bf(acc1[0] * sc1[0] + sh1[0], acc1[1] * sc1[1] + sh1[1]);
      p1.y = pack2bf(acc1[2] * sc1[2] + sh1[2], acc1[3] * sc1[3] + sh1[3]);
      p1.z = pack2bf(acc1[4] * sc1[4] + sh1[4], acc1[5] * sc1[5] + sh1[5]);
      p1.w = pack2bf(acc1[6] * sc1[6] + sh1[6], acc1[7] * sc1[7] + sh1[7]);
      p2.x = pack2bf(acc2[0] * sc2[0] + sh2[0], acc2[1] * sc2[1] + sh2[1]);
      p2.y = pack2bf(acc2[2] * sc2[2] + sh2[2], acc2[3] * sc2[3] + sh2[3]);
      p2.z = pack2bf(acc2[4] * sc2[4] + sh2[4], acc2[5] * sc2[5] + sh2[5]);
      p2.w = pack2bf(acc2[6] * sc2[6] + sh2[6], acc2[7] * sc2[7] + sh2[7]);
      ushort* dst = h1b + (size_t)r * 128 + q * 8;
      *reinterpret_cast<uint4*>(dst)      = p1;
      *reinterpret_cast<uint4*>(dst + 64) = p2;
    }
  }
}

// ---------------------------------------------------------------------------
// MFMA dense tail, no LDS: A = [hb | h1b] (N x 192 bf16), B from Wtg (L2).
//   cols 0:40 -> out (f32,+bias); 40:80 -> g1b; 80:120 -> g2b (bf16)
// ---------------------------------------------------------------------------
__global__ __launch_bounds__(256) void dense_tail_mfma(
    const ushort* __restrict__ hb, const ushort* __restrict__ h1b,
    const ushort* __restrict__ Wtg, const float* __restrict__ bfin,
    float* __restrict__ out, ushort* __restrict__ g1b, ushort* __restrict__ g2b,
    int N) {
  const int tid  = threadIdx.x;
  const int wv   = tid >> 6;
  const int lane = tid & 63;
  const int m16  = lane & 15;
  const int kg   = lane >> 4;
  const int row0 = blockIdx.x * 128;

  f32x4 acc[2][8];
#pragma unroll
  for (int i = 0; i < 2; ++i)
#pragma unroll
    for (int t = 0; t < 8; ++t) acc[i][t] = (f32x4){0.f, 0.f, 0.f, 0.f};

#pragma unroll
  for (int ks = 0; ks < 6; ++ks) {
    const int kk = ks * 32 + kg * 8;
    bf16x8 afr[2];
#pragma unroll
    for (int i = 0; i < 2; ++i) {
      int grow = row0 + wv * 32 + i * 16 + m16;
      grow = (grow < N) ? grow : (N - 1);
      const ushort* ap = (kk < 64) ? hb + (size_t)grow * 64 + kk
                                   : h1b + (size_t)grow * 128 + (kk - 64);
      afr[i] = *reinterpret_cast<const bf16x8*>(ap);
    }
#pragma unroll
    for (int t = 0; t < 8; ++t) {
      bf16x8 bfr = *reinterpret_cast<const bf16x8*>(
          Wtg + (size_t)(t * 16 + m16) * 192 + kk);
      acc[0][t] = __builtin_amdgcn_mfma_f32_16x16x32_bf16(afr[0], bfr, acc[0][t], 0, 0, 0);
      acc[1][t] = __builtin_amdgcn_mfma_f32_16x16x32_bf16(afr[1], bfr, acc[1][t], 0, 0, 0);
    }
  }

#pragma unroll
  for (int i = 0; i < 2; ++i) {
    const int rbase = row0 + wv * 32 + i * 16 + kg * 4;
#pragma unroll
    for (int t = 0; t < 8; ++t) {
      const int col = t * 16 + m16;
      if (col >= 120) continue;
      const float bias = (col < 40) ? bfin[col] : 0.f;
#pragma unroll
      for (int reg = 0; reg < 4; ++reg) {
        int gr = rbase + reg;
        if (gr < N) {
          float v = acc[i][t][reg];
          if (col < 40)       out[(size_t)gr * 40 + col] = v + bias;
          else if (col < 80)  g1b[(size_t)gr * 40 + (col - 40)] = f2bf(v);
          else                g2b[(size_t)gr * 40 + (col - 80)] = f2bf(v);
        }
      }
    }
  }
}

// ---------------------------------------------------------------------------
// Final add: out[r,:] += sum_{adj1} v*g1b[c,:] + sum_{adj2} v*g2b[c,:]
// 32-edge chunks, MLP=4, 8-lane subgroups; lanes q<5 carry real data.
// ---------------------------------------------------------------------------
__global__ __launch_bounds__(256) void final_add_kernel(
    const ushort* __restrict__ g1b, const ushort* __restrict__ g2b,
    const int* __restrict__ rp1, const uint* __restrict__ E1,
    const int* __restrict__ rp2, const uint* __restrict__ E2,
    float* __restrict__ out, int N, int nwaves) {
  const int wid  = (blockIdx.x * blockDim.x + threadIdx.x) >> 6;
  const int lane = threadIdx.x & 63;
  const int sub  = lane >> 3;
  const int q    = lane & 7;
  const int off  = (q < 5) ? q * 8 : 0;

  for (int r = wid; r < N; r += nwaves) {
    float a1[8] = {0, 0, 0, 0, 0, 0, 0, 0};
    float a2[8] = {0, 0, 0, 0, 0, 0, 0, 0};
    {
      int s = rp1[r], e = rp1[r + 1];
      for (int j0 = s; j0 < e; j0 += 32) {
        int j = j0 + sub;
        uint m0 = (j      < e) ? E1[j]      : 0u;
        uint m1 = (j + 8  < e) ? E1[j + 8]  : 0u;
        uint m2 = (j + 16 < e) ? E1[j + 16] : 0u;
        uint m3 = (j + 24 < e) ? E1[j + 24] : 0u;
        uint4 w0 = *reinterpret_cast<const uint4*>(g1b + (size_t)(m0 & 0xffffu) * 40 + off);
        uint4 w1 = *reinterpret_cast<const uint4*>(g1b + (size_t)(m1 & 0xffffu) * 40 + off);
        uint4 w2 = *reinterpret_cast<const uint4*>(g1b + (size_t)(m2 & 0xffffu) * 40 + off);
        uint4 w3 = *reinterpret_cast<const uint4*>(g1b + (size_t)(m3 & 0xffffu) * 40 + off);
        fma8(a1, w0, bf2f((ushort)(m0 >> 16)));
        fma8(a1, w1, bf2f((ushort)(m1 >> 16)));
        fma8(a1, w2, bf2f((ushort)(m2 >> 16)));
        fma8(a1, w3, bf2f((ushort)(m3 >> 16)));
      }
    }
    {
      int s = rp2[r], e = rp2[r + 1];
      for (int j0 = s; j0 < e; j0 += 32) {
        int j = j0 + sub;
        uint m0 = (j      < e) ? E2[j]      : 0u;
        uint m1 = (j + 8  < e) ? E2[j + 8]  : 0u;
        uint m2 = (j + 16 < e) ? E2[j + 16] : 0u;
        uint m3 = (j + 24 < e) ? E2[j + 24] : 0u;
        uint4 w0 = *reinterpret_cast<const uint4*>(g2b + (size_t)(m0 & 0xffffu) * 40 + off);
        uint4 w1 = *reinterpret_cast<const uint4*>(g2b + (size_t)(m1 & 0xffffu) * 40 + off);
        uint4 w2 = *reinterpret_cast<const uint4*>(g2b + (size_t)(m2 & 0xffffu) * 40 + off);
        uint4 w3 = *reinterpret_cast<const uint4*>(g2b + (size_t)(m3 & 0xffffu) * 40 + off);
        fma8(a2, w0, bf2f((ushort)(m0 >> 16)));
        fma8(a2, w1, bf2f((ushort)(m1 >> 16)));
        fma8(a2, w2, bf2f((ushort)(m2 >> 16)));
        fma8(a2, w3, bf2f((ushort)(m3 >> 16)));
      }
    }
#pragma unroll
    for (int mask = 8; mask <= 32; mask <<= 1) {
#pragma unroll
      for (int t = 0; t < 8; ++t) {
        a1[t] += __shfl_xor(a1[t], mask);
        a2[t] += __shfl_xor(a2[t], mask);
      }
    }
    if (lane < 5) {
      float* p = out + (size_t)r * 40 + lane * 8;
      float4 o0 = *reinterpret_cast<const float4*>(p);
      float4 o1 = *reinterpret_cast<const float4*>(p + 4);
      o0.x += a1[0] + a2[0]; o0.y += a1[1] + a2[1];
      o0.z += a1[2] + a2[2]; o0.w += a1[3] + a2[3];
      o1.x += a1[4] + a2[4]; o1.y += a1[5] + a2[5];
      o1.z += a1[6] + a2[6]; o1.w += a1[7] + a2[7];
      *reinterpret_cast<float4*>(p)     = o0;
      *reinterpret_cast<float4*>(p + 4) = o1;
    }
  }
}

// ---------------------------------------------------------------------------
extern "C" void kernel_launch(void* const* d_in, const int* in_sizes, int n_in,
                              void* d_out, int out_size, void* d_ws, size_t ws_size,
                              hipStream_t stream) {
  const float* x     = (const float*)d_in[0];
  const int*   a1r   = (const int*)d_in[1];
  const int*   a1c   = (const int*)d_in[2];
  const float* a1v   = (const float*)d_in[3];
  const int*   a2r   = (const int*)d_in[4];
  const int*   a2c   = (const int*)d_in[5];
  const float* a2v   = (const float*)d_in[6];
  const float* We    = (const float*)d_in[7];
  const float* be    = (const float*)d_in[8];
  const float* gamma = (const float*)d_in[9];
  const float* beta  = (const float*)d_in[10];
  const float* mean  = (const float*)d_in[11];
  const float* var   = (const float*)d_in[12];
  const float* Wf    = (const float*)d_in[13];
  const float* bf    = (const float*)d_in[14];
  float* out = (float*)d_out;

  const int N  = in_sizes[0] / 512;
  const int E1 = in_sizes[1];
  const int E2 = in_sizes[4];
  const int nbins = (N + 511) >> 9;   // requires N <= 65536

  char* p = (char*)d_ws;
  auto alloc = [&](size_t bytes) {
    char* q = p; p += (bytes + 255) & ~(size_t)255; return q;
  };
  ushort* hb   = (ushort*)alloc((size_t)N * 64 * 2);
  ushort* h1b  = (ushort*)alloc((size_t)N * 128 * 2);
  ushort* g1b  = (ushort*)alloc((size_t)N * 40 * 2);
  ushort* g2b  = (ushort*)alloc((size_t)N * 40 * 2);
  ushort* Wet  = (ushort*)alloc((size_t)64 * 512 * 2);
  ushort* Wtg  = (ushort*)alloc((size_t)128 * 192 * 2);
  int*    rp1  = (int*)   alloc(((size_t)N + 1) * 4);
  int*    rp2  = (int*)   alloc(((size_t)N + 1) * 4);
  uint*   E1s  = (uint*)  alloc((size_t)E1 * 4);
  uint*   E2s  = (uint*)  alloc((size_t)E2 * 4);
  int2*   S1   = (int2*)  alloc((size_t)E1 * 8);
  int2*   S2   = (int2*)  alloc((size_t)E2 * 8);
  int*    gbin1  = (int*) alloc(MAXBINS * 4);
  int*    gbin2  = (int*) alloc(MAXBINS * 4);
  int*    gbase1 = (int*) alloc(MAXBINS * 4);
  int*    gbase2 = (int*) alloc(MAXBINS * 4);
  int*    gcur1  = (int*) alloc(MAXBINS * 4);
  int*    gcur2  = (int*) alloc(MAXBINS * 4);

  hipMemsetAsync(gbin1, 0, (size_t)2 * MAXBINS * 4 + 256, stream);

  // one-time weight transpose (bf16)
  prep_weights<<<(32768 + 24576 + 255) / 256, 256, 0, stream>>>(We, Wf, Wet, Wtg);

  // embed via MFMA (no LDS; B from Wet)
  embed_mfma<<<(N + 127) / 128, 256, 0, stream>>>(x, Wet, be, hb, N);

  // binned CSR build
  bin_hist<<<256, 256, 0, stream>>>(a1r, gbin1, E1, nbins);
  bin_hist<<<256, 256, 0, stream>>>(a2r, gbin2, E2, nbins);
  bin_scan<<<1, 64, 0, stream>>>(gbin1, gbase1, gcur1, gbin2, gbase2, gcur2, nbins);
  bin_scatter<<<256, 256, 0, stream>>>(a1r, a1c, a1v, E1, gcur1, S1, nbins);
  bin_scatter<<<256, 256, 0, stream>>>(a2r, a2c, a2v, E2, gcur2, S2, nbins);
  csr_finalize<<<2 * nbins, 256, 0, stream>>>(
      S1, gbase1, rp1, E1s, E1, S2, gbase2, rp2, E2s, E2, N, nbins);

  // conv1 (gather, MLP=4) + fused BN -> bf16 h1b
  const int NW = 2048 * 4;
  conv1_gather<<<2048, 256, 0, stream>>>(
      hb, rp1, E1s, rp2, E2s, gamma, beta, mean, var, h1b, N, NW);

  // MFMA dense tail (no LDS; B from Wtg): out base + g1b/g2b in one pass
  dense_tail_mfma<<<(N + 127) / 128, 256, 0, stream>>>(
      hb, h1b, Wtg, bf, out, g1b, g2b, N);

  // out += A1@g1 + A2@g2 (MLP=4, bf16 gather)
  final_add_kernel<<<2048, 256, 0, stream>>>(
      g1b, g2b, rp1, E1s, rp2, E2s, out, N, NW);
}